// Round 1
// baseline (1720.897 us; speedup 1.0000x reference)
//
#include <hip/hip_runtime.h>
#include <cmath>

#define BB 4
#define CC 128
#define HH 64
#define WW 64
#define SP 4096   // H*W
#define NG 32     // groups
#define TT 32     // attention uv-tile width

__device__ __forceinline__ float silu_f(float v) {
    return v / (1.f + __expf(-v));
}

// ---------------- GroupNorm + SiLU ----------------
// grid: B*NG blocks, 256 threads. Each block: one (b, group) = 4 ch x 4096 = 16384 contiguous floats.
__global__ __launch_bounds__(256) void gn_silu_kernel(
    const float* __restrict__ in, const float* __restrict__ scale,
    const float* __restrict__ bias, float* __restrict__ out)
{
    const int bg = blockIdx.x;           // b*NG + g
    const int g = bg & (NG - 1);
    const float* p = in + (size_t)bg * 16384;
    float* o = out + (size_t)bg * 16384;

    float s = 0.f, s2 = 0.f;
    for (int i = threadIdx.x; i < 16384; i += 256) {
        float v = p[i];
        s += v; s2 += v * v;
    }
    #pragma unroll
    for (int off = 32; off >= 1; off >>= 1) {
        s  += __shfl_down(s,  off, 64);
        s2 += __shfl_down(s2, off, 64);
    }
    __shared__ float rs[4], rs2[4];
    __shared__ float mean_s, inv_s;
    const int wid = threadIdx.x >> 6;
    if ((threadIdx.x & 63) == 0) { rs[wid] = s; rs2[wid] = s2; }
    __syncthreads();
    if (threadIdx.x == 0) {
        float S = rs[0] + rs[1] + rs[2] + rs[3];
        float S2 = rs2[0] + rs2[1] + rs2[2] + rs2[3];
        float m = S * (1.f / 16384.f);
        float var = S2 * (1.f / 16384.f) - m * m;
        mean_s = m;
        inv_s = rsqrtf(var + 1e-5f);
    }
    __syncthreads();
    const float m = mean_s, inv = inv_s;
    for (int i = threadIdx.x; i < 16384; i += 256) {
        int c = (g << 2) + (i >> 12);
        float v = (p[i] - m) * inv * scale[c] + bias[c];
        o[i] = silu_f(v);
    }
}

// ---------------- 3x3 conv (pad 1), optional residual add ----------------
// grid: (yblk=16, cog=16, b=4), block 256 = 64(x) x 4(y). Each thread: 8 co accumulators.
__global__ __launch_bounds__(256) void conv3x3_kernel(
    const float* __restrict__ in, const float* __restrict__ wgt,
    const float* __restrict__ bias, const float* __restrict__ resid,
    float* __restrict__ out)
{
    const int x = threadIdx.x & 63;
    const int yl = threadIdx.x >> 6;
    const int y = blockIdx.x * 4 + yl;
    const int cog = blockIdx.y;     // co base = cog*8
    const int b = blockIdx.z;

    __shared__ float wl[128 * 9 * 8];   // [(ci*9+k)][j], 36 KB
    for (int i = threadIdx.x; i < 9216; i += 256) {
        int j = i & 7;
        int rest = i >> 3;          // ci*9 + k
        int ci = rest / 9;
        int k = rest - ci * 9;
        wl[i] = wgt[((size_t)(cog * 8 + j) * 128 + ci) * 9 + k];
    }
    __syncthreads();

    float acc[8];
    #pragma unroll
    for (int j = 0; j < 8; ++j) acc[j] = bias[cog * 8 + j];

    const float* inb = in + (size_t)b * CC * SP;
    for (int ci = 0; ci < 128; ++ci) {
        const float* inc = inb + ci * SP;
        const float* wc = wl + ci * 72;
        #pragma unroll
        for (int ky = 0; ky < 3; ++ky) {
            int ys = y + ky - 1;
            if (ys < 0 || ys > 63) continue;   // wave-uniform (y uniform per wave)
            #pragma unroll
            for (int kx = 0; kx < 3; ++kx) {
                int xs = x + kx - 1;
                float v = (xs >= 0 && xs <= 63) ? inc[ys * 64 + xs] : 0.f;
                const float4* wk4 = (const float4*)(wc + (ky * 3 + kx) * 8);
                float4 wa = wk4[0], wb = wk4[1];
                acc[0] += v * wa.x; acc[1] += v * wa.y;
                acc[2] += v * wa.z; acc[3] += v * wa.w;
                acc[4] += v * wb.x; acc[5] += v * wb.y;
                acc[6] += v * wb.z; acc[7] += v * wb.w;
            }
        }
    }
    #pragma unroll
    for (int j = 0; j < 8; ++j) {
        size_t o = ((size_t)(b * CC + cog * 8 + j)) * SP + y * 64 + x;
        float r = resid ? resid[o] : 0.f;
        out[o] = acc[j] + r;
    }
}

// ---------------- time-embedding MLP: temb[b][co] = silu(t[b]) @ mlp_w[co]^T + mlp_b ----------------
__global__ __launch_bounds__(128) void temb_kernel(
    const float* __restrict__ t, const float* __restrict__ w,
    const float* __restrict__ bias, float* __restrict__ temb)
{
    const int b = blockIdx.x;
    __shared__ float st[512];
    for (int i = threadIdx.x; i < 512; i += 128) st[i] = silu_f(t[b * 512 + i]);
    __syncthreads();
    const int co = threadIdx.x;
    float acc = bias[co];
    const float* wr = w + (size_t)co * 512;
    for (int k = 0; k < 512; ++k) acc += st[k] * wr[k];
    temb[b * 128 + co] = acc;
}

// ---------------- 1x1 conv: cmat[b][co][p] = sum_ci cond[b][ci][p]*w[co][ci] + b[co] ----------------
// grid: (pblk=16, cog=16, b=4), block 256
__global__ __launch_bounds__(256) void conv1x1_kernel(
    const float* __restrict__ in, const float* __restrict__ wgt,
    const float* __restrict__ bias, float* __restrict__ out)
{
    const int p = blockIdx.x * 256 + threadIdx.x;
    const int cog = blockIdx.y, b = blockIdx.z;
    __shared__ float wl[128 * 8];
    for (int i = threadIdx.x; i < 1024; i += 256) {
        int j = i & 7, ci = i >> 3;
        wl[i] = wgt[(size_t)(cog * 8 + j) * 128 + ci];
    }
    __syncthreads();
    float acc[8];
    #pragma unroll
    for (int j = 0; j < 8; ++j) acc[j] = bias[cog * 8 + j];
    const float* inb = in + (size_t)b * CC * SP + p;
    for (int ci = 0; ci < 128; ++ci) {
        float v = inb[ci * SP];
        const float4* wk4 = (const float4*)(wl + ci * 8);
        float4 wa = wk4[0], wb = wk4[1];
        acc[0] += v * wa.x; acc[1] += v * wa.y;
        acc[2] += v * wa.z; acc[3] += v * wa.w;
        acc[4] += v * wb.x; acc[5] += v * wb.y;
        acc[6] += v * wb.z; acc[7] += v * wb.w;
    }
    #pragma unroll
    for (int j = 0; j < 8; ++j)
        out[((size_t)(b * CC + cog * 8 + j)) * SP + p] = acc[j];
}

// ---------------- fused cross-attention per (b, w) ----------------
// h2 = h1 + temb + attn + emb[aim].  Softmax over h (fully resident: 64).
__global__ __launch_bounds__(256) void attn_kernel(
    const float* __restrict__ h1, const float* __restrict__ temb,
    const float* __restrict__ cm, const int* __restrict__ aim,
    const float* __restrict__ emb, float* __restrict__ h2)
{
    const int w = blockIdx.x;
    const int b = blockIdx.y;
    const int tid = threadIdx.x;

    __shared__ float hs[CC * HH];        // [c][h]      32 KB
    __shared__ float ct[TT * 129];       // [t][ci]     16.5 KB (stride 129: conflict-free)
    __shared__ float Ps[TT * 65];        // [t][h]      8.3 KB  (stride 65)

    for (int i = tid; i < CC * HH; i += 256) {
        int c = i >> 6, h = i & 63;
        hs[i] = h1[((size_t)(b * CC + c)) * SP + h * WW + w] + temb[b * CC + c];
    }

    float acc[32];
    #pragma unroll
    for (int i = 0; i < 32; ++i) acc[i] = 0.f;

    const int t2 = tid & 31;             // phase-2: my uv column
    const int hb = tid >> 5;             // phase-2: my h-block (8 rows)
    const int c0 = (tid & 31) << 2;      // phase-3: c base (4 channels)
    const int h0 = (tid >> 5) << 3;      // phase-3: h base (8 rows)
    const float scl = 0.088388347648318447f;  // 1/sqrt(128)

    for (int tile = 0; tile < SP / TT; ++tile) {
        const int uv0 = tile * TT;
        __syncthreads();                 // protect ct/Ps from previous phase 3
        // phase 1: stage c tile
        for (int i = tid; i < CC * TT; i += 256) {
            int t = i & (TT - 1);
            int ci = i >> 5;
            ct[t * 129 + ci] = cm[((size_t)(b * CC + ci)) * SP + uv0 + t];
        }
        __syncthreads();
        // phase 2: S[t2][h0..h0+7] = scale * sum_ci hs[ci][h]*ct[t2][ci]
        {
            float sacc[8];
            #pragma unroll
            for (int k = 0; k < 8; ++k) sacc[k] = 0.f;
            const float* ctt = ct + t2 * 129;
            const int hh0 = hb * 8;
            for (int ci = 0; ci < CC; ++ci) {
                float cv = ctt[ci];
                const float* hp = hs + ci * 64 + hh0;
                #pragma unroll
                for (int k = 0; k < 8; ++k) sacc[k] += cv * hp[k];
            }
            float* ps = Ps + t2 * 65 + hh0;
            #pragma unroll
            for (int k = 0; k < 8; ++k) ps[k] = sacc[k] * scl;
        }
        __syncthreads();
        // softmax over h for each uv column (row of Ps)
        if (tid < TT) {
            float* row = Ps + tid * 65;
            float mx = -1e30f;
            for (int h = 0; h < HH; ++h) mx = fmaxf(mx, row[h]);
            float l = 0.f;
            for (int h = 0; h < HH; ++h) { float e = __expf(row[h] - mx); l += e; row[h] = e; }
            float rl = 1.f / l;
            for (int h = 0; h < HH; ++h) row[h] *= rl;
        }
        __syncthreads();
        // phase 3: acc[c0+j][h0+k] += sum_t P[t][h]*ct[t][c]
        for (int t = 0; t < TT; ++t) {
            const float* ctr = ct + t * 129 + c0;
            float v0 = ctr[0], v1 = ctr[1], v2 = ctr[2], v3 = ctr[3];
            const float* pr = Ps + t * 65 + h0;
            #pragma unroll
            for (int k = 0; k < 8; ++k) {
                float pv = pr[k];
                acc[k * 4 + 0] += pv * v0;
                acc[k * 4 + 1] += pv * v1;
                acc[k * 4 + 2] += pv * v2;
                acc[k * 4 + 3] += pv * v3;
            }
        }
    }
    // epilogue: h2 = hs(=h1+temb) + attn + contrast_embed[aim]
    const int ab = aim[b];
    #pragma unroll
    for (int k = 0; k < 8; ++k) {
        int h = h0 + k;
        #pragma unroll
        for (int j = 0; j < 4; ++j) {
            int c = c0 + j;
            size_t o = ((size_t)(b * CC + c)) * SP + h * WW + w;
            h2[o] = hs[c * 64 + h] + acc[k * 4 + j] + emb[ab * CC + c];
        }
    }
}

extern "C" void kernel_launch(void* const* d_in, const int* in_sizes, int n_in,
                              void* d_out, int out_size, void* d_ws, size_t ws_size,
                              hipStream_t stream)
{
    const float* x     = (const float*)d_in[0];
    const float* t     = (const float*)d_in[1];
    const int*   aim   = (const int*)  d_in[2];
    const float* cond  = (const float*)d_in[3];
    const float* gn1s  = (const float*)d_in[4];
    const float* gn1b  = (const float*)d_in[5];
    const float* c1w   = (const float*)d_in[6];
    const float* c1b   = (const float*)d_in[7];
    const float* mlpw  = (const float*)d_in[8];
    const float* mlpb  = (const float*)d_in[9];
    const float* cw    = (const float*)d_in[10];
    const float* cb    = (const float*)d_in[11];
    const float* gn2s  = (const float*)d_in[12];
    const float* gn2b  = (const float*)d_in[13];
    const float* c2w   = (const float*)d_in[14];
    const float* c2b   = (const float*)d_in[15];
    const float* emb   = (const float*)d_in[16];
    float* out = (float*)d_out;
    float* ws = (float*)d_ws;

    float* a1   = ws;             // 2.1M floats (reused as a2 after attention)
    float* h1   = ws + 2097152;
    float* cmat = ws + 4194304;
    float* h2   = ws + 6291456;
    float* tembw = ws + 8388608;  // 512 floats

    gn_silu_kernel<<<dim3(BB * NG), dim3(256), 0, stream>>>(x, gn1s, gn1b, a1);
    conv3x3_kernel<<<dim3(16, 16, 4), dim3(256), 0, stream>>>(a1, c1w, c1b, nullptr, h1);
    temb_kernel<<<dim3(BB), dim3(128), 0, stream>>>(t, mlpw, mlpb, tembw);
    conv1x1_kernel<<<dim3(16, 16, 4), dim3(256), 0, stream>>>(cond, cw, cb, cmat);
    attn_kernel<<<dim3(WW, BB), dim3(256), 0, stream>>>(h1, tembw, cmat, aim, emb, h2);
    gn_silu_kernel<<<dim3(BB * NG), dim3(256), 0, stream>>>(h2, gn2s, gn2b, a1);
    conv3x3_kernel<<<dim3(16, 16, 4), dim3(256), 0, stream>>>(a1, c2w, c2b, x, out);
}

// Round 3
// 651.059 us; speedup vs baseline: 2.6432x; 2.6432x over previous
//
#include <hip/hip_runtime.h>
#include <cmath>

#define BB 4
#define CC 128
#define HH 64
#define WW 64
#define SP 4096   // H*W
#define NG 32     // groups
#define TT 64     // attention uv-tile width

typedef __bf16 bf16x8 __attribute__((ext_vector_type(8)));
typedef float  f32x4  __attribute__((ext_vector_type(4)));

__device__ __forceinline__ float silu_f(float v) {
    return v / (1.f + __expf(-v));
}

// ---------------- GroupNorm + SiLU ----------------
__global__ __launch_bounds__(256) void gn_silu_kernel(
    const float* __restrict__ in, const float* __restrict__ scale,
    const float* __restrict__ bias, float* __restrict__ out)
{
    const int bg = blockIdx.x;
    const int g = bg & (NG - 1);
    const float* p = in + (size_t)bg * 16384;
    float* o = out + (size_t)bg * 16384;

    float s = 0.f, s2 = 0.f;
    for (int i = threadIdx.x; i < 16384; i += 256) {
        float v = p[i];
        s += v; s2 += v * v;
    }
    #pragma unroll
    for (int off = 32; off >= 1; off >>= 1) {
        s  += __shfl_down(s,  off, 64);
        s2 += __shfl_down(s2, off, 64);
    }
    __shared__ float rs[4], rs2[4];
    __shared__ float mean_s, inv_s;
    const int wid = threadIdx.x >> 6;
    if ((threadIdx.x & 63) == 0) { rs[wid] = s; rs2[wid] = s2; }
    __syncthreads();
    if (threadIdx.x == 0) {
        float S = rs[0] + rs[1] + rs[2] + rs[3];
        float S2 = rs2[0] + rs2[1] + rs2[2] + rs2[3];
        float m = S * (1.f / 16384.f);
        float var = S2 * (1.f / 16384.f) - m * m;
        mean_s = m;
        inv_s = rsqrtf(var + 1e-5f);
    }
    __syncthreads();
    const float m = mean_s, inv = inv_s;
    for (int i = threadIdx.x; i < 16384; i += 256) {
        int c = (g << 2) + (i >> 12);
        float v = (p[i] - m) * inv * scale[c] + bias[c];
        o[i] = silu_f(v);
    }
}

// ---------------- 3x3 conv (pad 1), optional residual add ----------------
__global__ __launch_bounds__(256) void conv3x3_kernel(
    const float* __restrict__ in, const float* __restrict__ wgt,
    const float* __restrict__ bias, const float* __restrict__ resid,
    float* __restrict__ out)
{
    const int x = threadIdx.x & 63;
    const int yl = threadIdx.x >> 6;
    const int y = blockIdx.x * 4 + yl;
    const int cog = blockIdx.y;
    const int b = blockIdx.z;

    __shared__ float wl[128 * 9 * 8];
    for (int i = threadIdx.x; i < 9216; i += 256) {
        int j = i & 7;
        int rest = i >> 3;
        int ci = rest / 9;
        int k = rest - ci * 9;
        wl[i] = wgt[((size_t)(cog * 8 + j) * 128 + ci) * 9 + k];
    }
    __syncthreads();

    float acc[8];
    #pragma unroll
    for (int j = 0; j < 8; ++j) acc[j] = bias[cog * 8 + j];

    const float* inb = in + (size_t)b * CC * SP;
    for (int ci = 0; ci < 128; ++ci) {
        const float* inc = inb + ci * SP;
        const float* wc = wl + ci * 72;
        #pragma unroll
        for (int ky = 0; ky < 3; ++ky) {
            int ys = y + ky - 1;
            if (ys < 0 || ys > 63) continue;
            #pragma unroll
            for (int kx = 0; kx < 3; ++kx) {
                int xs = x + kx - 1;
                float v = (xs >= 0 && xs <= 63) ? inc[ys * 64 + xs] : 0.f;
                const float4* wk4 = (const float4*)(wc + (ky * 3 + kx) * 8);
                float4 wa = wk4[0], wb = wk4[1];
                acc[0] += v * wa.x; acc[1] += v * wa.y;
                acc[2] += v * wa.z; acc[3] += v * wa.w;
                acc[4] += v * wb.x; acc[5] += v * wb.y;
                acc[6] += v * wb.z; acc[7] += v * wb.w;
            }
        }
    }
    #pragma unroll
    for (int j = 0; j < 8; ++j) {
        size_t o = ((size_t)(b * CC + cog * 8 + j)) * SP + y * 64 + x;
        float r = resid ? resid[o] : 0.f;
        out[o] = acc[j] + r;
    }
}

// ---------------- time-embedding MLP ----------------
__global__ __launch_bounds__(128) void temb_kernel(
    const float* __restrict__ t, const float* __restrict__ w,
    const float* __restrict__ bias, float* __restrict__ temb)
{
    const int b = blockIdx.x;
    __shared__ float st[512];
    for (int i = threadIdx.x; i < 512; i += 128) st[i] = silu_f(t[b * 512 + i]);
    __syncthreads();
    const int co = threadIdx.x;
    float acc = bias[co];
    const float* wr = w + (size_t)co * 512;
    for (int k = 0; k < 512; ++k) acc += st[k] * wr[k];
    temb[b * 128 + co] = acc;
}

// ---------------- 1x1 conv -> TWO bf16 layouts ----------------
// cmT[b][p][c] (c-contiguous)  and  cm2[b][c][p] (p-contiguous)
__global__ __launch_bounds__(256) void conv1x1_kernel(
    const float* __restrict__ in, const float* __restrict__ wgt,
    const float* __restrict__ bias, __bf16* __restrict__ cmT,
    __bf16* __restrict__ cm2)
{
    const int p = blockIdx.x * 256 + threadIdx.x;
    const int cog = blockIdx.y, b = blockIdx.z;
    __shared__ float wl[128 * 8];
    for (int i = threadIdx.x; i < 1024; i += 256) {
        int j = i & 7, ci = i >> 3;
        wl[i] = wgt[(size_t)(cog * 8 + j) * 128 + ci];
    }
    __syncthreads();
    float acc[8];
    #pragma unroll
    for (int j = 0; j < 8; ++j) acc[j] = bias[cog * 8 + j];
    const float* inb = in + (size_t)b * CC * SP + p;
    for (int ci = 0; ci < 128; ++ci) {
        float v = inb[ci * SP];
        const float4* wk4 = (const float4*)(wl + ci * 8);
        float4 wa = wk4[0], wb = wk4[1];
        acc[0] += v * wa.x; acc[1] += v * wa.y;
        acc[2] += v * wa.z; acc[3] += v * wa.w;
        acc[4] += v * wb.x; acc[5] += v * wb.y;
        acc[6] += v * wb.z; acc[7] += v * wb.w;
    }
    bf16x8 v8;
    #pragma unroll
    for (int j = 0; j < 8; ++j) v8[j] = (__bf16)acc[j];
    *(bf16x8*)&cmT[((size_t)(b * SP + p)) * 128 + cog * 8] = v8;
    #pragma unroll
    for (int j = 0; j < 8; ++j)
        cm2[((size_t)(b * CC + cog * 8 + j)) * SP + p] = v8[j];
}

// ---------------- fused cross-attention per (b, w), bf16 MFMA ----------------
#define HST 136   // hsT row stride (bf16)
#define CTT 136   // ctT row stride (bf16)
#define CT2 72    // ct2 row stride (bf16)
#define PSS 65    // Ps row stride (fp32)
#define PBS 72    // Pb row stride (bf16)

__global__ __launch_bounds__(256) void attn_kernel(
    const float* __restrict__ h1, const float* __restrict__ temb,
    const __bf16* __restrict__ cmT, const __bf16* __restrict__ cm2,
    const int* __restrict__ aim, const float* __restrict__ emb,
    float* __restrict__ h2)
{
    const int w = blockIdx.x;
    const int b = blockIdx.y;
    const int tid = threadIdx.x;
    const int l = tid & 63;         // lane
    const int wv = tid >> 6;        // wave id = h-block
    const int l15 = l & 15;
    const int l4 = l >> 4;          // quad

    __shared__ __bf16 hsT[HH * HST];    // [h][c]
    __shared__ __bf16 ctT[TT * CTT];    // [t][c]
    __shared__ __bf16 ct2[CC * CT2];    // [c][t]
    __shared__ float  Ps[HH * PSS];     // [h][t]
    __shared__ __bf16 Pb[HH * PBS];     // [h][t]
    __shared__ float  Mx[TT], Ri[TT];

    const float scl = 0.088388347648318447f;  // 1/sqrt(128)

    // stage hsT = bf16(scl * (h1[:, :, w] + temb))  [h][c]  — exhaustive
    for (int i = tid; i < CC * HH; i += 256) {
        int c = i >> 6, h = i & 63;
        float v = h1[((size_t)(b * CC + c)) * SP + h * WW + w] + temb[b * CC + c];
        hsT[h * HST + c] = (__bf16)(v * scl);
    }
    __syncthreads();

    // hoist matmul1 A-fragments (hsT rows for this wave's h-block)
    const int myh = 16 * wv + l15;
    bf16x8 afrag[4];
    #pragma unroll
    for (int ks = 0; ks < 4; ++ks)
        afrag[ks] = *(const bf16x8*)&hsT[myh * HST + ks * 32 + l4 * 8];

    f32x4 acc2[8];
    #pragma unroll
    for (int nt = 0; nt < 8; ++nt) acc2[nt] = (f32x4){0.f, 0.f, 0.f, 0.f};

    const __bf16* cmTb = cmT + (size_t)b * SP * 128;
    const __bf16* cm2b = cm2 + (size_t)b * CC * SP;

    for (int tile = 0; tile < SP / TT; ++tile) {
        const int uv0 = tile * TT;
        __syncthreads();   // previous tile's reads done

        // stage ctT [t][c] from cmT (16B chunks)
        #pragma unroll
        for (int it = 0; it < 4; ++it) {
            int q = it * 256 + tid;          // 1024 chunks
            int t = q >> 4, cc = q & 15;
            bf16x8 v = *(const bf16x8*)&cmTb[((size_t)(uv0 + t)) * 128 + cc * 8];
            *(bf16x8*)&ctT[t * CTT + cc * 8] = v;
        }
        // stage ct2 [c][t] from cm2
        #pragma unroll
        for (int it = 0; it < 4; ++it) {
            int q = it * 256 + tid;
            int c = q >> 3, tc = q & 7;
            bf16x8 v = *(const bf16x8*)&cm2b[((size_t)c) * SP + uv0 + tc * 8];
            *(bf16x8*)&ct2[c * CT2 + tc * 8] = v;
        }
        __syncthreads();

        // matmul1: S[h][t] for this wave's 16 h rows; write to Ps
        #pragma unroll
        for (int nt = 0; nt < 4; ++nt) {
            const int tb = nt * 16;
            f32x4 acc = (f32x4){0.f, 0.f, 0.f, 0.f};
            #pragma unroll
            for (int ks = 0; ks < 4; ++ks) {
                bf16x8 bfr = *(const bf16x8*)&ctT[(tb + l15) * CTT + ks * 32 + l4 * 8];
                acc = __builtin_amdgcn_mfma_f32_16x16x32_bf16(afrag[ks], bfr, acc, 0, 0, 0);
            }
            #pragma unroll
            for (int r = 0; r < 4; ++r)
                Ps[(16 * wv + l4 * 4 + r) * PSS + tb + l15] = acc[r];
        }
        __syncthreads();

        // softmax phase 1: per-column (t) max & sum over h
        {
            int t = tid >> 2, q = tid & 3;
            float mx = -1e30f;
            float vals[16];
            #pragma unroll
            for (int i = 0; i < 16; ++i) {
                vals[i] = Ps[(16 * q + i) * PSS + t];
                mx = fmaxf(mx, vals[i]);
            }
            mx = fmaxf(mx, __shfl_xor(mx, 1, 64));
            mx = fmaxf(mx, __shfl_xor(mx, 2, 64));
            float sm = 0.f;
            #pragma unroll
            for (int i = 0; i < 16; ++i) sm += __expf(vals[i] - mx);
            sm += __shfl_xor(sm, 1, 64);
            sm += __shfl_xor(sm, 2, 64);
            if (q == 0) { Mx[t] = mx; Ri[t] = 1.f / sm; }
        }
        __syncthreads();

        // softmax phase 2: Pb[h][t] = bf16(exp(Ps-Mx)*Ri)
        {
            int h = tid & 63, seg = tid >> 6;
            #pragma unroll
            for (int i = 0; i < 16; ++i) {
                int t = seg * 16 + i;
                float e = __expf(Ps[h * PSS + t] - Mx[t]) * Ri[t];
                Pb[h * PBS + t] = (__bf16)e;
            }
        }
        __syncthreads();

        // matmul2: O[h][c] += P[h][t] * ct2[c][t]
        bf16x8 pfr[2];
        #pragma unroll
        for (int ks = 0; ks < 2; ++ks)
            pfr[ks] = *(const bf16x8*)&Pb[myh * PBS + ks * 32 + l4 * 8];
        #pragma unroll
        for (int nt = 0; nt < 8; ++nt) {
            #pragma unroll
            for (int ks = 0; ks < 2; ++ks) {
                bf16x8 bfr = *(const bf16x8*)&ct2[(nt * 16 + l15) * CT2 + ks * 32 + l4 * 8];
                acc2[nt] = __builtin_amdgcn_mfma_f32_16x16x32_bf16(pfr[ks], bfr, acc2[nt], 0, 0, 0);
            }
        }
    }

    // epilogue: h2 = h1 + temb + attn + emb[aim]
    const int ab = aim[b];
    #pragma unroll
    for (int nt = 0; nt < 8; ++nt) {
        int c = nt * 16 + l15;
        float tv = temb[b * CC + c];
        float ev = emb[ab * CC + c];
        #pragma unroll
        for (int r = 0; r < 4; ++r) {
            int h = 16 * wv + l4 * 4 + r;
            size_t o = ((size_t)(b * CC + c)) * SP + h * WW + w;
            h2[o] = h1[o] + tv + acc2[nt][r] + ev;
        }
    }
}

extern "C" void kernel_launch(void* const* d_in, const int* in_sizes, int n_in,
                              void* d_out, int out_size, void* d_ws, size_t ws_size,
                              hipStream_t stream)
{
    const float* x     = (const float*)d_in[0];
    const float* t     = (const float*)d_in[1];
    const int*   aim   = (const int*)  d_in[2];
    const float* cond  = (const float*)d_in[3];
    const float* gn1s  = (const float*)d_in[4];
    const float* gn1b  = (const float*)d_in[5];
    const float* c1w   = (const float*)d_in[6];
    const float* c1b   = (const float*)d_in[7];
    const float* mlpw  = (const float*)d_in[8];
    const float* mlpb  = (const float*)d_in[9];
    const float* cw    = (const float*)d_in[10];
    const float* cb    = (const float*)d_in[11];
    const float* gn2s  = (const float*)d_in[12];
    const float* gn2b  = (const float*)d_in[13];
    const float* c2w   = (const float*)d_in[14];
    const float* c2b   = (const float*)d_in[15];
    const float* emb   = (const float*)d_in[16];
    float* out = (float*)d_out;
    float* ws = (float*)d_ws;

    float*  a1   = ws;                       // 2.1M floats
    float*  h1   = ws + 2097152;
    float*  h2   = ws + 4194304;
    __bf16* cmT  = (__bf16*)(ws + 6291456);  // 4*4096*128 bf16 = 1M floats
    __bf16* cm2  = (__bf16*)(ws + 7340032);
    float*  tembw = ws + 8388608;            // 512 floats

    gn_silu_kernel<<<dim3(BB * NG), dim3(256), 0, stream>>>(x, gn1s, gn1b, a1);
    conv3x3_kernel<<<dim3(16, 16, 4), dim3(256), 0, stream>>>(a1, c1w, c1b, nullptr, h1);
    temb_kernel<<<dim3(BB), dim3(128), 0, stream>>>(t, mlpw, mlpb, tembw);
    conv1x1_kernel<<<dim3(16, 16, 4), dim3(256), 0, stream>>>(cond, cw, cb, cmT, cm2);
    attn_kernel<<<dim3(WW, BB), dim3(256), 0, stream>>>(h1, tembw, cmT, cm2, aim, emb, h2);
    gn_silu_kernel<<<dim3(BB * NG), dim3(256), 0, stream>>>(h2, gn2s, gn2b, a1);
    conv3x3_kernel<<<dim3(16, 16, 4), dim3(256), 0, stream>>>(a1, c2w, c2b, x, out);
}

// Round 4
// 365.714 us; speedup vs baseline: 4.7056x; 1.7802x over previous
//
#include <hip/hip_runtime.h>
#include <cmath>

#define BB 4
#define CC 128
#define HH 64
#define WW 64
#define SP 4096   // H*W
#define NG 32     // groups
#define TT 64     // attention uv-tile width

typedef __bf16 bf16x8 __attribute__((ext_vector_type(8)));
typedef float  f32x4  __attribute__((ext_vector_type(4)));

__device__ __forceinline__ float silu_f(float v) {
    return v / (1.f + __expf(-v));
}

// ---------------- GN stats (channels-first input): stats[b*32+g] = (mean, inv) ----------------
__global__ __launch_bounds__(256) void gn_stats_kernel(
    const float* __restrict__ in, float* __restrict__ stats)
{
    const int bg = blockIdx.x;
    const float* p = in + (size_t)bg * 16384;
    float s = 0.f, s2 = 0.f;
    for (int i = threadIdx.x; i < 16384; i += 256) {
        float v = p[i];
        s += v; s2 += v * v;
    }
    #pragma unroll
    for (int off = 32; off >= 1; off >>= 1) {
        s  += __shfl_down(s,  off, 64);
        s2 += __shfl_down(s2, off, 64);
    }
    __shared__ float rs[4], rs2[4];
    const int wid = threadIdx.x >> 6;
    if ((threadIdx.x & 63) == 0) { rs[wid] = s; rs2[wid] = s2; }
    __syncthreads();
    if (threadIdx.x == 0) {
        float S = rs[0] + rs[1] + rs[2] + rs[3];
        float S2 = rs2[0] + rs2[1] + rs2[2] + rs2[3];
        float m = S * (1.f / 16384.f);
        float var = S2 * (1.f / 16384.f) - m * m;
        stats[bg * 2] = m;
        stats[bg * 2 + 1] = rsqrtf(var + 1e-5f);
    }
}

// ---------------- GN apply + SiLU + transpose to channels-last bf16 ----------------
// grid (32 ptiles, 4 b). in [b][c][p] fp32 -> outT [b][p][c] bf16, p-tile = 128
__global__ __launch_bounds__(256) void gn_apply_cl_kernel(
    const float* __restrict__ in, const float* __restrict__ stats,
    const float* __restrict__ scale, const float* __restrict__ bias,
    __bf16* __restrict__ outT)
{
    const int p0 = blockIdx.x * 128;
    const int b = blockIdx.y;
    const int tid = threadIdx.x;
    __shared__ __bf16 T[128 * 136];   // [p local][c]

    for (int it = 0; it < 16; ++it) {
        int q = it * 256 + tid;            // 4096 float4 tasks
        int c = q >> 5, p4 = q & 31;
        float4 v = *(const float4*)&in[((size_t)(b * CC + c)) * SP + p0 + p4 * 4];
        int g = c >> 2;
        float m = stats[(b * NG + g) * 2], inv = stats[(b * NG + g) * 2 + 1];
        float sc = scale[c], bi = bias[c];
        float r0 = silu_f((v.x - m) * inv * sc + bi);
        float r1 = silu_f((v.y - m) * inv * sc + bi);
        float r2 = silu_f((v.z - m) * inv * sc + bi);
        float r3 = silu_f((v.w - m) * inv * sc + bi);
        T[(p4 * 4 + 0) * 136 + c] = (__bf16)r0;
        T[(p4 * 4 + 1) * 136 + c] = (__bf16)r1;
        T[(p4 * 4 + 2) * 136 + c] = (__bf16)r2;
        T[(p4 * 4 + 3) * 136 + c] = (__bf16)r3;
    }
    __syncthreads();
    for (int it = 0; it < 8; ++it) {
        int q = it * 256 + tid;            // 2048 16B chunks
        int pr = q >> 4, cc = q & 15;
        *(bf16x8*)&outT[((size_t)(b * SP + p0 + pr)) * CC + cc * 8] =
            *(const bf16x8*)&T[pr * 136 + cc * 8];
    }
}

// ---------------- GN2 stats from channels-last fp32 ----------------
__global__ __launch_bounds__(256) void gn_stats_cl_kernel(
    const float* __restrict__ inT, float* __restrict__ stats)
{
    const int bg = blockIdx.x;
    const int b = bg >> 5, g = bg & 31;
    float s = 0.f, s2 = 0.f;
    for (int it = 0; it < 16; ++it) {
        int p = it * 256 + threadIdx.x;
        float4 v = *(const float4*)&inT[((size_t)(b * SP + p)) * CC + g * 4];
        s += v.x + v.y + v.z + v.w;
        s2 += v.x * v.x + v.y * v.y + v.z * v.z + v.w * v.w;
    }
    #pragma unroll
    for (int off = 32; off >= 1; off >>= 1) {
        s  += __shfl_down(s,  off, 64);
        s2 += __shfl_down(s2, off, 64);
    }
    __shared__ float rs[4], rs2[4];
    const int wid = threadIdx.x >> 6;
    if ((threadIdx.x & 63) == 0) { rs[wid] = s; rs2[wid] = s2; }
    __syncthreads();
    if (threadIdx.x == 0) {
        float S = rs[0] + rs[1] + rs[2] + rs[3];
        float S2 = rs2[0] + rs2[1] + rs2[2] + rs2[3];
        float m = S * (1.f / 16384.f);
        float var = S2 * (1.f / 16384.f) - m * m;
        stats[bg * 2] = m;
        stats[bg * 2 + 1] = rsqrtf(var + 1e-5f);
    }
}

// ---------------- GN2 apply + SiLU, channels-last fp32 -> channels-last bf16 ----------------
// grid 2048 x 256 thr, one float4 each
__global__ __launch_bounds__(256) void gn_apply2_cl_kernel(
    const float* __restrict__ inT, const float* __restrict__ stats,
    const float* __restrict__ scale, const float* __restrict__ bias,
    __bf16* __restrict__ outT)
{
    int idx = blockIdx.x * 256 + threadIdx.x;   // float4 index
    int b = idx >> 17;                           // 131072 float4 per batch
    int g = idx & 31;                            // c chunk = group
    int c0 = g * 4;
    float4 v = *(const float4*)&inT[(size_t)idx * 4];
    float m = stats[(b * NG + g) * 2], inv = stats[(b * NG + g) * 2 + 1];
    __bf16 o[4];
    o[0] = (__bf16)silu_f((v.x - m) * inv * scale[c0 + 0] + bias[c0 + 0]);
    o[1] = (__bf16)silu_f((v.y - m) * inv * scale[c0 + 1] + bias[c0 + 1]);
    o[2] = (__bf16)silu_f((v.z - m) * inv * scale[c0 + 2] + bias[c0 + 2]);
    o[3] = (__bf16)silu_f((v.w - m) * inv * scale[c0 + 3] + bias[c0 + 3]);
    *(float2*)&outT[(size_t)idx * 4] = *(float2*)o;
}

// ---------------- weight transpose: W[co][ci][3][3] fp32 -> Wt[tap][co][ci] bf16 ----------------
__global__ __launch_bounds__(256) void wt_kernel(
    const float* __restrict__ w1, const float* __restrict__ w2,
    __bf16* __restrict__ wt)   // [2][9][128][128]
{
    const int blk = blockIdx.x;        // 0..17
    const int wsel = blk / 9, tap = blk % 9;
    const float* src = wsel ? w2 : w1;
    __bf16* dst = wt + (size_t)wsel * 9 * 16384 + (size_t)tap * 16384;
    for (int it = 0; it < 64; ++it) {
        int q = it * 256 + threadIdx.x;   // q = co*128+ci
        dst[q] = (__bf16)src[(size_t)q * 9 + tap];
    }
}

// ---------------- time-embedding MLP ----------------
__global__ __launch_bounds__(128) void temb_kernel(
    const float* __restrict__ t, const float* __restrict__ w,
    const float* __restrict__ bias, float* __restrict__ temb)
{
    const int b = blockIdx.x;
    __shared__ float st[512];
    for (int i = threadIdx.x; i < 512; i += 128) st[i] = silu_f(t[b * 512 + i]);
    __syncthreads();
    const int co = threadIdx.x;
    float acc = bias[co];
    const float* wr = w + (size_t)co * 512;
    for (int k = 0; k < 512; ++k) acc += st[k] * wr[k];
    temb[b * 128 + co] = acc;
}

// ---------------- 3x3 conv via per-tap MFMA GEMM ----------------
// inT [b][p][ci] bf16 (p = y*64+x), Wt [tap][co][ci] bf16.
// Block: (pb = y row, b). C[co 0..127][p row of 64]. 4 waves: wave wv does m-blocks {2wv,2wv+1}.
template<bool FUSE_TEMB, bool OUT_CF>
__global__ __launch_bounds__(256) void conv_mfma_kernel(
    const __bf16* __restrict__ inT, const __bf16* __restrict__ wt,
    const float* __restrict__ bias, const float* __restrict__ temb,
    const float* __restrict__ resid, __bf16* __restrict__ outT,
    float* __restrict__ outF)
{
    const int pb = blockIdx.x;    // y row
    const int b = blockIdx.y;
    const int p0 = pb * 64;
    const int tid = threadIdx.x;
    const int l = tid & 63, wv = tid >> 6;
    const int l15 = l & 15, l4 = l >> 4;

    __shared__ __bf16 wl[128 * 136];    // [co][ci] for one tap
    __shared__ __bf16 Otr[64 * 136];    // conv1 transpose buffer [p local][co]

    f32x4 acc[2][4];
    #pragma unroll
    for (int mb = 0; mb < 2; ++mb)
        #pragma unroll
        for (int nb = 0; nb < 4; ++nb) acc[mb][nb] = (f32x4){0.f, 0.f, 0.f, 0.f};

    const __bf16* inTb = inT + (size_t)b * SP * CC;

    for (int tap = 0; tap < 9; ++tap) {
        const int dy = tap / 3 - 1, dx = tap % 3 - 1;
        __syncthreads();
        // stage weight tile
        #pragma unroll
        for (int it = 0; it < 8; ++it) {
            int q = it * 256 + tid;          // 2048 chunks
            int co = q >> 4, cc = q & 15;
            *(bf16x8*)&wl[co * 136 + cc * 8] =
                *(const bf16x8*)&wt[((size_t)tap * 128 + co) * 128 + cc * 8];
        }
        __syncthreads();
        const int yy = pb + dy;
        const bool yok = ((unsigned)yy) < 64u;
        #pragma unroll
        for (int ks = 0; ks < 4; ++ks) {
            bf16x8 bfr[4];
            #pragma unroll
            for (int nb = 0; nb < 4; ++nb) {
                int x = nb * 16 + l15;
                int xx = x + dx;
                bool ok = yok && (((unsigned)xx) < 64u);
                bf16x8 v;
                if (ok) {
                    v = *(const bf16x8*)&inTb[((size_t)(yy * 64 + xx)) * CC + ks * 32 + l4 * 8];
                } else {
                    #pragma unroll
                    for (int j = 0; j < 8; ++j) v[j] = (__bf16)0.f;
                }
                bfr[nb] = v;
            }
            #pragma unroll
            for (int mb = 0; mb < 2; ++mb) {
                int co = (wv * 2 + mb) * 16 + l15;
                bf16x8 afr = *(const bf16x8*)&wl[co * 136 + ks * 32 + l4 * 8];
                #pragma unroll
                for (int nb = 0; nb < 4; ++nb)
                    acc[mb][nb] = __builtin_amdgcn_mfma_f32_16x16x32_bf16(afr, bfr[nb], acc[mb][nb], 0, 0, 0);
            }
        }
    }

    // epilogue. D layout: row(co part) = l4*4+r, col(p part) = l15.
    if (OUT_CF) {
        #pragma unroll
        for (int mb = 0; mb < 2; ++mb) {
            #pragma unroll
            for (int r = 0; r < 4; ++r) {
                int co = (wv * 2 + mb) * 16 + l4 * 4 + r;
                float bv = bias[co];
                #pragma unroll
                for (int nb = 0; nb < 4; ++nb) {
                    int p = p0 + nb * 16 + l15;
                    size_t o = ((size_t)(b * CC + co)) * SP + p;
                    outF[o] = acc[mb][nb][r] + bv + resid[o];
                }
            }
        }
    } else {
        #pragma unroll
        for (int mb = 0; mb < 2; ++mb) {
            #pragma unroll
            for (int r = 0; r < 4; ++r) {
                int co = (wv * 2 + mb) * 16 + l4 * 4 + r;
                float bv = bias[co] + (FUSE_TEMB ? temb[b * CC + co] : 0.f);
                #pragma unroll
                for (int nb = 0; nb < 4; ++nb) {
                    int pl = nb * 16 + l15;
                    Otr[pl * 136 + co] = (__bf16)(acc[mb][nb][r] + bv);
                }
            }
        }
        __syncthreads();
        #pragma unroll
        for (int it = 0; it < 4; ++it) {
            int q = it * 256 + tid;           // 1024 16B chunks
            int pr = q >> 4, cc = q & 15;
            *(bf16x8*)&outT[((size_t)(b * SP + p0 + pr)) * CC + cc * 8] =
                *(const bf16x8*)&Otr[pr * 136 + cc * 8];
        }
    }
}

// ---------------- 1x1 conv -> cmT [b][p][co] bf16 (x 1/sqrt(128)) + cm2 [b][co][p] bf16 ----------------
__global__ __launch_bounds__(256) void conv1x1_kernel(
    const float* __restrict__ in, const float* __restrict__ wgt,
    const float* __restrict__ bias, __bf16* __restrict__ cmT,
    __bf16* __restrict__ cm2)
{
    const int p0 = blockIdx.x * 256;
    const int p = p0 + threadIdx.x;
    const int cog = blockIdx.y, b = blockIdx.z;
    __shared__ float wl[128 * 8];
    __shared__ __bf16 tr[8][272];
    for (int i = threadIdx.x; i < 1024; i += 256) {
        int j = i & 7, ci = i >> 3;
        wl[i] = wgt[(size_t)(cog * 8 + j) * 128 + ci];
    }
    __syncthreads();
    float acc[8];
    #pragma unroll
    for (int j = 0; j < 8; ++j) acc[j] = bias[cog * 8 + j];
    const float* inb = in + (size_t)b * CC * SP + p;
    for (int ci = 0; ci < 128; ++ci) {
        float v = inb[ci * SP];
        const float4* wk4 = (const float4*)(wl + ci * 8);
        float4 wa = wk4[0], wb = wk4[1];
        acc[0] += v * wa.x; acc[1] += v * wa.y;
        acc[2] += v * wa.z; acc[3] += v * wa.w;
        acc[4] += v * wb.x; acc[5] += v * wb.y;
        acc[6] += v * wb.z; acc[7] += v * wb.w;
    }
    const float scl = 0.088388347648318447f;  // 1/sqrt(128)
    bf16x8 v8s;
    #pragma unroll
    for (int j = 0; j < 8; ++j) {
        v8s[j] = (__bf16)(acc[j] * scl);
        tr[j][threadIdx.x] = (__bf16)acc[j];
    }
    *(bf16x8*)&cmT[((size_t)(b * SP + p)) * CC + cog * 8] = v8s;
    __syncthreads();
    {
        int j = threadIdx.x >> 5, t32 = threadIdx.x & 31;
        *(bf16x8*)&cm2[((size_t)(b * CC + cog * 8 + j)) * SP + p0 + t32 * 8] =
            *(const bf16x8*)&tr[j][t32 * 8];
    }
}

// ---------------- fused cross-attention per (b, w), bf16 MFMA, channels-last I/O ----------------
#define HST 136   // hsT row stride (bf16)
#define CTT 136   // ctT row stride (bf16)
#define CT2 72    // ct2 row stride (bf16)
#define PSS 65    // Ps row stride (fp32)
#define PBS 72    // Pb row stride (bf16)
#define OTS 136   // Otr row stride (fp32)

__global__ __launch_bounds__(256) void attn_kernel(
    const __bf16* __restrict__ h1T, const __bf16* __restrict__ cmT,
    const __bf16* __restrict__ cm2, const int* __restrict__ aim,
    const float* __restrict__ emb, float* __restrict__ h2T)
{
    const int w = blockIdx.x;
    const int b = blockIdx.y;
    const int tid = threadIdx.x;
    const int l = tid & 63;
    const int wv = tid >> 6;
    const int l15 = l & 15;
    const int l4 = l >> 4;

    __shared__ __bf16 hsT[HH * HST];    // [h][c]  (h1+temb, unscaled)
    __shared__ __bf16 ctT[TT * CTT];    // [t][c]  (pre-scaled by 1/sqrt(128))
    __shared__ __bf16 ct2[CC * CT2];    // [c][t]
    __shared__ float  Ps[HH * PSS];     // [h][t]
    __shared__ __bf16 Pb[HH * PBS];     // [h][t]
    __shared__ float  Mx[TT], Ri[TT];
    __shared__ float  Otr[HH * OTS];    // [h][c] epilogue transpose
    __shared__ float  embs[CC];

    const __bf16* h1Tb = h1T + (size_t)b * SP * CC;

    // stage hsT [h][c] — coalesced 16B chunks
    #pragma unroll
    for (int it = 0; it < 4; ++it) {
        int q = it * 256 + tid;          // 1024 chunks
        int h = q >> 4, cc = q & 15;
        *(bf16x8*)&hsT[h * HST + cc * 8] =
            *(const bf16x8*)&h1Tb[((size_t)(h * WW + w)) * CC + cc * 8];
    }
    if (tid < CC) embs[tid] = emb[aim[b] * CC + tid];
    __syncthreads();

    const int myh = 16 * wv + l15;
    bf16x8 afrag[4];
    #pragma unroll
    for (int ks = 0; ks < 4; ++ks)
        afrag[ks] = *(const bf16x8*)&hsT[myh * HST + ks * 32 + l4 * 8];

    f32x4 acc2[8];
    #pragma unroll
    for (int nt = 0; nt < 8; ++nt) acc2[nt] = (f32x4){0.f, 0.f, 0.f, 0.f};

    const __bf16* cmTb = cmT + (size_t)b * SP * CC;
    const __bf16* cm2b = cm2 + (size_t)b * CC * SP;

    for (int tile = 0; tile < SP / TT; ++tile) {
        const int uv0 = tile * TT;
        __syncthreads();

        #pragma unroll
        for (int it = 0; it < 4; ++it) {
            int q = it * 256 + tid;
            int t = q >> 4, cc = q & 15;
            *(bf16x8*)&ctT[t * CTT + cc * 8] =
                *(const bf16x8*)&cmTb[((size_t)(uv0 + t)) * CC + cc * 8];
        }
        #pragma unroll
        for (int it = 0; it < 4; ++it) {
            int q = it * 256 + tid;
            int c = q >> 3, tc = q & 7;
            *(bf16x8*)&ct2[c * CT2 + tc * 8] =
                *(const bf16x8*)&cm2b[((size_t)c) * SP + uv0 + tc * 8];
        }
        __syncthreads();

        // matmul1: S[h][t]
        #pragma unroll
        for (int nt = 0; nt < 4; ++nt) {
            const int tb = nt * 16;
            f32x4 acc = (f32x4){0.f, 0.f, 0.f, 0.f};
            #pragma unroll
            for (int ks = 0; ks < 4; ++ks) {
                bf16x8 bfr = *(const bf16x8*)&ctT[(tb + l15) * CTT + ks * 32 + l4 * 8];
                acc = __builtin_amdgcn_mfma_f32_16x16x32_bf16(afrag[ks], bfr, acc, 0, 0, 0);
            }
            #pragma unroll
            for (int r = 0; r < 4; ++r)
                Ps[(16 * wv + l4 * 4 + r) * PSS + tb + l15] = acc[r];
        }
        __syncthreads();

        // softmax phase 1
        {
            int t = tid >> 2, q = tid & 3;
            float mx = -1e30f;
            float vals[16];
            #pragma unroll
            for (int i = 0; i < 16; ++i) {
                vals[i] = Ps[(16 * q + i) * PSS + t];
                mx = fmaxf(mx, vals[i]);
            }
            mx = fmaxf(mx, __shfl_xor(mx, 1, 64));
            mx = fmaxf(mx, __shfl_xor(mx, 2, 64));
            float sm = 0.f;
            #pragma unroll
            for (int i = 0; i < 16; ++i) sm += __expf(vals[i] - mx);
            sm += __shfl_xor(sm, 1, 64);
            sm += __shfl_xor(sm, 2, 64);
            if (q == 0) { Mx[t] = mx; Ri[t] = 1.f / sm; }
        }
        __syncthreads();

        // softmax phase 2
        {
            int h = tid & 63, seg = tid >> 6;
            #pragma unroll
            for (int i = 0; i < 16; ++i) {
                int t = seg * 16 + i;
                float e = __expf(Ps[h * PSS + t] - Mx[t]) * Ri[t];
                Pb[h * PBS + t] = (__bf16)e;
            }
        }
        __syncthreads();

        // matmul2
        bf16x8 pfr[2];
        #pragma unroll
        for (int ks = 0; ks < 2; ++ks)
            pfr[ks] = *(const bf16x8*)&Pb[myh * PBS + ks * 32 + l4 * 8];
        #pragma unroll
        for (int nt = 0; nt < 8; ++nt) {
            #pragma unroll
            for (int ks = 0; ks < 2; ++ks) {
                bf16x8 bfr = *(const bf16x8*)&ct2[(nt * 16 + l15) * CT2 + ks * 32 + l4 * 8];
                acc2[nt] = __builtin_amdgcn_mfma_f32_16x16x32_bf16(pfr[ks], bfr, acc2[nt], 0, 0, 0);
            }
        }
    }

    // epilogue: Otr[h][c] = attn contribution, then coalesced h2T = hsT + Otr + emb
    #pragma unroll
    for (int nt = 0; nt < 8; ++nt) {
        #pragma unroll
        for (int r = 0; r < 4; ++r) {
            int h = 16 * wv + l4 * 4 + r;
            int c = nt * 16 + l15;
            Otr[h * OTS + c] = acc2[nt][r];
        }
    }
    __syncthreads();
    float* h2Tb = h2T + (size_t)b * SP * CC;
    #pragma unroll
    for (int it = 0; it < 8; ++it) {
        int j = it * 256 + tid;          // 2048 float4 tasks
        int h = j >> 5, c4 = j & 31;
        int c = c4 * 4;
        float4 o4 = *(const float4*)&Otr[h * OTS + c];
        o4.x += (float)hsT[h * HST + c + 0] + embs[c + 0];
        o4.y += (float)hsT[h * HST + c + 1] + embs[c + 1];
        o4.z += (float)hsT[h * HST + c + 2] + embs[c + 2];
        o4.w += (float)hsT[h * HST + c + 3] + embs[c + 3];
        *(float4*)&h2Tb[((size_t)(h * WW + w)) * CC + c] = o4;
    }
}

extern "C" void kernel_launch(void* const* d_in, const int* in_sizes, int n_in,
                              void* d_out, int out_size, void* d_ws, size_t ws_size,
                              hipStream_t stream)
{
    const float* x     = (const float*)d_in[0];
    const float* t     = (const float*)d_in[1];
    const int*   aim   = (const int*)  d_in[2];
    const float* cond  = (const float*)d_in[3];
    const float* gn1s  = (const float*)d_in[4];
    const float* gn1b  = (const float*)d_in[5];
    const float* c1w   = (const float*)d_in[6];
    const float* c1b   = (const float*)d_in[7];
    const float* mlpw  = (const float*)d_in[8];
    const float* mlpb  = (const float*)d_in[9];
    const float* cw    = (const float*)d_in[10];
    const float* cb    = (const float*)d_in[11];
    const float* gn2s  = (const float*)d_in[12];
    const float* gn2b  = (const float*)d_in[13];
    const float* c2w   = (const float*)d_in[14];
    const float* c2b   = (const float*)d_in[15];
    const float* emb   = (const float*)d_in[16];
    float* out = (float*)d_out;
    float* ws = (float*)d_ws;

    __bf16* aT    = (__bf16*)ws;                  // 2M bf16 = 1,048,576 fl (a1T, reused as a2T)
    __bf16* h1T   = (__bf16*)(ws + 1048576);      // 2M bf16
    float*  h2T   = ws + 2097152;                 // 2,097,152 fl
    __bf16* cmT   = (__bf16*)(ws + 4194304);      // 2M bf16
    __bf16* cm2   = (__bf16*)(ws + 5242880);      // 2M bf16
    __bf16* wt    = (__bf16*)(ws + 6291456);      // 2*9*16384 bf16 = 147,456 fl
    float*  tembw = ws + 6438912;                 // 512 fl
    float*  st1   = ws + 6439424;                 // 256 fl
    float*  st2   = ws + 6439680;                 // 256 fl

    gn_stats_kernel<<<dim3(BB * NG), dim3(256), 0, stream>>>(x, st1);
    gn_apply_cl_kernel<<<dim3(32, BB), dim3(256), 0, stream>>>(x, st1, gn1s, gn1b, aT);
    wt_kernel<<<dim3(18), dim3(256), 0, stream>>>(c1w, c2w, wt);
    temb_kernel<<<dim3(BB), dim3(128), 0, stream>>>(t, mlpw, mlpb, tembw);
    conv1x1_kernel<<<dim3(16, 16, BB), dim3(256), 0, stream>>>(cond, cw, cb, cmT, cm2);
    conv_mfma_kernel<true, false><<<dim3(64, BB), dim3(256), 0, stream>>>(
        aT, wt, c1b, tembw, nullptr, h1T, nullptr);
    attn_kernel<<<dim3(WW, BB), dim3(256), 0, stream>>>(h1T, cmT, cm2, aim, emb, h2T);
    gn_stats_cl_kernel<<<dim3(BB * NG), dim3(256), 0, stream>>>(h2T, st2);
    gn_apply2_cl_kernel<<<dim3(2048), dim3(256), 0, stream>>>(h2T, st2, gn2s, gn2b, aT);
    conv_mfma_kernel<false, true><<<dim3(64, BB), dim3(256), 0, stream>>>(
        aT, wt + (size_t)9 * 16384, c2b, nullptr, x, nullptr, out);
}

// Round 5
// 332.816 us; speedup vs baseline: 5.1707x; 1.0988x over previous
//
#include <hip/hip_runtime.h>
#include <cmath>

#define BB 4
#define CC 128
#define HH 64
#define WW 64
#define SP 4096   // H*W
#define NG 32     // groups
#define TT 64     // attention uv-tile width

typedef __bf16 bf16x8 __attribute__((ext_vector_type(8)));
typedef __bf16 bf16x4 __attribute__((ext_vector_type(4)));
typedef float  f32x4  __attribute__((ext_vector_type(4)));

__device__ __forceinline__ float silu_f(float v) {
    return v / (1.f + __expf(-v));
}

// ---------------- GN1 stats (channels-first fp32 input) ----------------
__global__ __launch_bounds__(256) void gn_stats_kernel(
    const float* __restrict__ in, float* __restrict__ stats)
{
    const int bg = blockIdx.x;
    const float* p = in + (size_t)bg * 16384;
    float s = 0.f, s2 = 0.f;
    for (int i = threadIdx.x; i < 16384; i += 256) {
        float v = p[i];
        s += v; s2 += v * v;
    }
    #pragma unroll
    for (int off = 32; off >= 1; off >>= 1) {
        s  += __shfl_down(s,  off, 64);
        s2 += __shfl_down(s2, off, 64);
    }
    __shared__ float rs[4], rs2[4];
    const int wid = threadIdx.x >> 6;
    if ((threadIdx.x & 63) == 0) { rs[wid] = s; rs2[wid] = s2; }
    __syncthreads();
    if (threadIdx.x == 0) {
        float S = rs[0] + rs[1] + rs[2] + rs[3];
        float S2 = rs2[0] + rs2[1] + rs2[2] + rs2[3];
        float m = S * (1.f / 16384.f);
        float var = S2 * (1.f / 16384.f) - m * m;
        stats[bg * 2] = m;
        stats[bg * 2 + 1] = rsqrtf(var + 1e-5f);
    }
}

// ---------------- GN1 apply + SiLU + transpose to channels-last bf16 ----------------
__global__ __launch_bounds__(256) void gn_apply_cl_kernel(
    const float* __restrict__ in, const float* __restrict__ stats,
    const float* __restrict__ scale, const float* __restrict__ bias,
    __bf16* __restrict__ outT)
{
    const int p0 = blockIdx.x * 128;
    const int b = blockIdx.y;
    const int tid = threadIdx.x;
    __shared__ __bf16 T[128 * 136];   // [p local][c]

    for (int it = 0; it < 16; ++it) {
        int q = it * 256 + tid;            // 4096 float4 tasks
        int c = q >> 5, p4 = q & 31;
        float4 v = *(const float4*)&in[((size_t)(b * CC + c)) * SP + p0 + p4 * 4];
        int g = c >> 2;
        float m = stats[(b * NG + g) * 2], inv = stats[(b * NG + g) * 2 + 1];
        float sc = scale[c], bi = bias[c];
        T[(p4 * 4 + 0) * 136 + c] = (__bf16)silu_f((v.x - m) * inv * sc + bi);
        T[(p4 * 4 + 1) * 136 + c] = (__bf16)silu_f((v.y - m) * inv * sc + bi);
        T[(p4 * 4 + 2) * 136 + c] = (__bf16)silu_f((v.z - m) * inv * sc + bi);
        T[(p4 * 4 + 3) * 136 + c] = (__bf16)silu_f((v.w - m) * inv * sc + bi);
    }
    __syncthreads();
    for (int it = 0; it < 8; ++it) {
        int q = it * 256 + tid;            // 2048 16B chunks
        int pr = q >> 4, cc = q & 15;
        *(bf16x8*)&outT[((size_t)(b * SP + p0 + pr)) * CC + cc * 8] =
            *(const bf16x8*)&T[pr * 136 + cc * 8];
    }
}

// ---------------- GN2 stats from channels-last bf16 ----------------
__global__ __launch_bounds__(256) void gn_stats_cl_kernel(
    const __bf16* __restrict__ inT, float* __restrict__ stats)
{
    const int bg = blockIdx.x;
    const int b = bg >> 5, g = bg & 31;
    float s = 0.f, s2 = 0.f;
    for (int it = 0; it < 16; ++it) {
        int p = it * 256 + threadIdx.x;
        bf16x4 v = *(const bf16x4*)&inT[((size_t)(b * SP + p)) * CC + g * 4];
        #pragma unroll
        for (int j = 0; j < 4; ++j) {
            float f = (float)v[j];
            s += f; s2 += f * f;
        }
    }
    #pragma unroll
    for (int off = 32; off >= 1; off >>= 1) {
        s  += __shfl_down(s,  off, 64);
        s2 += __shfl_down(s2, off, 64);
    }
    __shared__ float rs[4], rs2[4];
    const int wid = threadIdx.x >> 6;
    if ((threadIdx.x & 63) == 0) { rs[wid] = s; rs2[wid] = s2; }
    __syncthreads();
    if (threadIdx.x == 0) {
        float S = rs[0] + rs[1] + rs[2] + rs[3];
        float S2 = rs2[0] + rs2[1] + rs2[2] + rs2[3];
        float m = S * (1.f / 16384.f);
        float var = S2 * (1.f / 16384.f) - m * m;
        stats[bg * 2] = m;
        stats[bg * 2 + 1] = rsqrtf(var + 1e-5f);
    }
}

// ---------------- GN2 apply + SiLU, channels-last bf16 -> channels-last bf16 ----------------
__global__ __launch_bounds__(256) void gn_apply2_cl_kernel(
    const __bf16* __restrict__ inT, const float* __restrict__ stats,
    const float* __restrict__ scale, const float* __restrict__ bias,
    __bf16* __restrict__ outT)
{
    int idx = blockIdx.x * 256 + threadIdx.x;   // 4-elem chunk index
    int b = idx >> 17;
    int g = idx & 31;
    int c0 = g * 4;
    bf16x4 v = *(const bf16x4*)&inT[(size_t)idx * 4];
    float m = stats[(b * NG + g) * 2], inv = stats[(b * NG + g) * 2 + 1];
    bf16x4 o;
    #pragma unroll
    for (int j = 0; j < 4; ++j)
        o[j] = (__bf16)silu_f(((float)v[j] - m) * inv * scale[c0 + j] + bias[c0 + j]);
    *(bf16x4*)&outT[(size_t)idx * 4] = o;
}

// ---------------- weight transpose: W[co][ci][3][3] fp32 -> Wt[tap][co][ci] bf16 ----------------
__global__ __launch_bounds__(256) void wt_kernel(
    const float* __restrict__ w1, const float* __restrict__ w2,
    __bf16* __restrict__ wt)   // [2][9][128][128]
{
    const int blk = blockIdx.x;        // 0..17
    const int wsel = blk / 9, tap = blk % 9;
    const float* src = wsel ? w2 : w1;
    __bf16* dst = wt + (size_t)wsel * 9 * 16384 + (size_t)tap * 16384;
    for (int it = 0; it < 64; ++it) {
        int q = it * 256 + threadIdx.x;   // q = co*128+ci
        dst[q] = (__bf16)src[(size_t)q * 9 + tap];
    }
}

// ---------------- time-embedding MLP ----------------
__global__ __launch_bounds__(128) void temb_kernel(
    const float* __restrict__ t, const float* __restrict__ w,
    const float* __restrict__ bias, float* __restrict__ temb)
{
    const int b = blockIdx.x;
    __shared__ float st[512];
    for (int i = threadIdx.x; i < 512; i += 128) st[i] = silu_f(t[b * 512 + i]);
    __syncthreads();
    const int co = threadIdx.x;
    float acc = bias[co];
    const float* wr = w + (size_t)co * 512;
    for (int k = 0; k < 512; ++k) acc += st[k] * wr[k];
    temb[b * 128 + co] = acc;
}

// ---------------- 3x3 conv via per-tap MFMA, weights from global (L2) ----------------
// grid (128, BB): y = pb>>1, x0 = (pb&1)*32. Wave wv: co base wv*32 (2 m-blocks).
template<bool FUSE_TEMB, bool OUT_CF>
__global__ __launch_bounds__(256) void conv_mfma_kernel(
    const __bf16* __restrict__ inT, const __bf16* __restrict__ wt,
    const float* __restrict__ bias, const float* __restrict__ temb,
    const float* __restrict__ resid, __bf16* __restrict__ outT,
    float* __restrict__ outF)
{
    const int pb = blockIdx.x;
    const int y = pb >> 1, x0 = (pb & 1) * 32;
    const int b = blockIdx.y;
    const int tid = threadIdx.x;
    const int l = tid & 63, wv = tid >> 6;
    const int l15 = l & 15, l4 = l >> 4;

    f32x4 acc[2][2];
    #pragma unroll
    for (int mb = 0; mb < 2; ++mb)
        #pragma unroll
        for (int nb = 0; nb < 2; ++nb) acc[mb][nb] = (f32x4){0.f, 0.f, 0.f, 0.f};

    const __bf16* inTb = inT + (size_t)b * SP * CC;

    for (int tap = 0; tap < 9; ++tap) {
        const int dy = tap / 3 - 1, dx = tap % 3 - 1;
        const int yy = y + dy;
        const bool yok = ((unsigned)yy) < 64u;
        #pragma unroll
        for (int ks = 0; ks < 4; ++ks) {
            bf16x8 bfr[2];
            #pragma unroll
            for (int nb = 0; nb < 2; ++nb) {
                int xx = x0 + nb * 16 + l15 + dx;
                bool ok = yok && (((unsigned)xx) < 64u);
                bf16x8 v;
                if (ok) {
                    v = *(const bf16x8*)&inTb[((size_t)(yy * 64 + xx)) * CC + ks * 32 + l4 * 8];
                } else {
                    #pragma unroll
                    for (int j = 0; j < 8; ++j) v[j] = (__bf16)0.f;
                }
                bfr[nb] = v;
            }
            #pragma unroll
            for (int mb = 0; mb < 2; ++mb) {
                int co = wv * 32 + mb * 16 + l15;
                bf16x8 afr = *(const bf16x8*)&wt[((size_t)tap * 128 + co) * 128 + ks * 32 + l4 * 8];
                #pragma unroll
                for (int nb = 0; nb < 2; ++nb)
                    acc[mb][nb] = __builtin_amdgcn_mfma_f32_16x16x32_bf16(afr, bfr[nb], acc[mb][nb], 0, 0, 0);
            }
        }
    }

    if (OUT_CF) {
        #pragma unroll
        for (int mb = 0; mb < 2; ++mb) {
            #pragma unroll
            for (int r = 0; r < 4; ++r) {
                int co = wv * 32 + mb * 16 + l4 * 4 + r;
                float bv = bias[co];
                #pragma unroll
                for (int nb = 0; nb < 2; ++nb) {
                    int p = y * 64 + x0 + nb * 16 + l15;
                    size_t o = ((size_t)(b * CC + co)) * SP + p;
                    outF[o] = acc[mb][nb][r] + bv + resid[o];
                }
            }
        }
    } else {
        __shared__ __bf16 Otr[32 * 136];   // [x local][co]
        #pragma unroll
        for (int mb = 0; mb < 2; ++mb) {
            #pragma unroll
            for (int r = 0; r < 4; ++r) {
                int co = wv * 32 + mb * 16 + l4 * 4 + r;
                float bv = bias[co] + (FUSE_TEMB ? temb[b * CC + co] : 0.f);
                #pragma unroll
                for (int nb = 0; nb < 2; ++nb) {
                    int xl = nb * 16 + l15;
                    Otr[xl * 136 + co] = (__bf16)(acc[mb][nb][r] + bv);
                }
            }
        }
        __syncthreads();
        #pragma unroll
        for (int it = 0; it < 2; ++it) {
            int q = it * 256 + tid;           // 512 16B chunks
            int xl = q >> 4, cc = q & 15;
            *(bf16x8*)&outT[((size_t)(b * SP + y * 64 + x0 + xl)) * CC + cc * 8] =
                *(const bf16x8*)&Otr[xl * 136 + cc * 8];
        }
    }
}

// ---------------- 1x1 conv -> cmT [b][p][co] bf16 (x 1/sqrt(128)) + cm2 [b][co][p] bf16 ----------------
__global__ __launch_bounds__(256) void conv1x1_kernel(
    const float* __restrict__ in, const float* __restrict__ wgt,
    const float* __restrict__ bias, __bf16* __restrict__ cmT,
    __bf16* __restrict__ cm2)
{
    const int p0 = blockIdx.x * 256;
    const int p = p0 + threadIdx.x;
    const int cog = blockIdx.y, b = blockIdx.z;
    __shared__ float wl[128 * 8];
    __shared__ __bf16 tr[8][272];
    for (int i = threadIdx.x; i < 1024; i += 256) {
        int j = i & 7, ci = i >> 3;
        wl[i] = wgt[(size_t)(cog * 8 + j) * 128 + ci];
    }
    __syncthreads();
    float acc[8];
    #pragma unroll
    for (int j = 0; j < 8; ++j) acc[j] = bias[cog * 8 + j];
    const float* inb = in + (size_t)b * CC * SP + p;
    for (int ci = 0; ci < 128; ++ci) {
        float v = inb[ci * SP];
        const float4* wk4 = (const float4*)(wl + ci * 8);
        float4 wa = wk4[0], wb = wk4[1];
        acc[0] += v * wa.x; acc[1] += v * wa.y;
        acc[2] += v * wa.z; acc[3] += v * wa.w;
        acc[4] += v * wb.x; acc[5] += v * wb.y;
        acc[6] += v * wb.z; acc[7] += v * wb.w;
    }
    const float scl = 0.088388347648318447f;  // 1/sqrt(128)
    bf16x8 v8s;
    #pragma unroll
    for (int j = 0; j < 8; ++j) {
        v8s[j] = (__bf16)(acc[j] * scl);
        tr[j][threadIdx.x] = (__bf16)acc[j];
    }
    *(bf16x8*)&cmT[((size_t)(b * SP + p)) * CC + cog * 8] = v8s;
    __syncthreads();
    {
        int j = threadIdx.x >> 5, t32 = threadIdx.x & 31;
        *(bf16x8*)&cm2[((size_t)(b * CC + cog * 8 + j)) * SP + p0 + t32 * 8] =
            *(const bf16x8*)&tr[j][t32 * 8];
    }
}

// ---------------- fused cross-attention per (b, w), 8 waves, even/odd tile halves ----------------
#define HST 136   // hsT row stride (bf16)
#define CTT 136   // ctT row stride (bf16)
#define CT2 72    // ct2 row stride (bf16)
#define PBS 72    // Pb row stride (bf16)

// LDS pool layout (bytes):
//   0      : ctT[2]  2 x 64*136*2  = 34816   (epilogue alias: Otr fp32 64*136*4 = 34816)
//   34816  : ct2[2]  2 x 128*72*2  = 36864
//   71680  : Pb[2]   2 x 64*72*2   = 18432
//   90112  : hsT     64*136*2      = 17408
//   107520 : embs    128*4         = 512
#define POOL_BYTES 108032

__global__ __launch_bounds__(512) void attn_kernel(
    const __bf16* __restrict__ h1T, const __bf16* __restrict__ cmT,
    const __bf16* __restrict__ cm2, const int* __restrict__ aim,
    const float* __restrict__ emb, __bf16* __restrict__ h2T)
{
    const int w = blockIdx.x;
    const int b = blockIdx.y;
    const int tid = threadIdx.x;
    const int wv8 = tid >> 6;       // 0..7
    const int hf = wv8 >> 2;        // tile-half (0=even tiles, 1=odd)
    const int wl = wv8 & 3;         // wave within half
    const int l = tid & 63, l15 = l & 15, l4 = l >> 4;

    __shared__ __align__(16) char pool[POOL_BYTES];
    __bf16* ctT  = (__bf16*)(pool + hf * 17408);            // [t][c], this half's
    __bf16* ct2  = (__bf16*)(pool + 34816 + hf * 18432);    // [c][t]
    __bf16* Pb   = (__bf16*)(pool + 71680 + hf * 9216);     // [h][t]
    __bf16* hsT  = (__bf16*)(pool + 90112);                 // [h][c], shared
    float*  embs = (float*)(pool + 107520);
    float*  Otr  = (float*)(pool);                          // epilogue alias

    const __bf16* h1Tb = h1T + (size_t)b * SP * CC;

    // stage hsT (all 512 threads)
    #pragma unroll
    for (int it = 0; it < 2; ++it) {
        int q = it * 512 + tid;          // 1024 chunks
        int h = q >> 4, cc = q & 15;
        *(bf16x8*)&hsT[h * HST + cc * 8] =
            *(const bf16x8*)&h1Tb[((size_t)(h * WW + w)) * CC + cc * 8];
    }
    if (tid < CC) embs[tid] = emb[aim[b] * CC + tid];
    __syncthreads();

    // hoist matmul1 B-frags (hsT rows, tile-invariant): B[n=h][k=c]
    bf16x8 hfr[4][4];
    #pragma unroll
    for (int nt = 0; nt < 4; ++nt)
        #pragma unroll
        for (int ks = 0; ks < 4; ++ks)
            hfr[nt][ks] = *(const bf16x8*)&hsT[(nt * 16 + l15) * HST + ks * 32 + l4 * 8];

    const int myh = 16 * wl + l15;     // matmul2 A rows

    f32x4 acc2[8];
    #pragma unroll
    for (int nt = 0; nt < 8; ++nt) acc2[nt] = (f32x4){0.f, 0.f, 0.f, 0.f};

    const __bf16* cmTb = cmT + (size_t)b * SP * CC;
    const __bf16* cm2b = cm2 + (size_t)b * CC * SP;
    const int gtid = tid & 255;

    for (int tp = 0; tp < 32; ++tp) {
        const int uv0 = (tp * 2 + hf) * TT;
        __syncthreads();
        // stage this half's ctT/ct2 (256 threads per half)
        #pragma unroll
        for (int it = 0; it < 4; ++it) {
            int q = it * 256 + gtid;          // 1024 chunks
            int t = q >> 4, cc = q & 15;
            *(bf16x8*)&ctT[t * CTT + cc * 8] =
                *(const bf16x8*)&cmTb[((size_t)(uv0 + t)) * CC + cc * 8];
        }
        #pragma unroll
        for (int it = 0; it < 4; ++it) {
            int q = it * 256 + gtid;
            int c = q >> 3, tc = q & 7;
            *(bf16x8*)&ct2[c * CT2 + tc * 8] =
                *(const bf16x8*)&cm2b[((size_t)c) * SP + uv0 + tc * 8];
        }
        __syncthreads();

        // matmul1 transposed: S^T[t][h], wave wl owns t rows [16wl, 16wl+16)
        bf16x8 afr[4];
        #pragma unroll
        for (int ks = 0; ks < 4; ++ks)
            afr[ks] = *(const bf16x8*)&ctT[(16 * wl + l15) * CTT + ks * 32 + l4 * 8];
        f32x4 s1[4];
        #pragma unroll
        for (int nt = 0; nt < 4; ++nt) {
            s1[nt] = (f32x4){0.f, 0.f, 0.f, 0.f};
            #pragma unroll
            for (int ks = 0; ks < 4; ++ks)
                s1[nt] = __builtin_amdgcn_mfma_f32_16x16x32_bf16(afr[ks], hfr[nt][ks], s1[nt], 0, 0, 0);
        }
        // in-register softmax over h (row t = 16wl + l4*4 + r; cols spread over l15 & nt)
        #pragma unroll
        for (int r = 0; r < 4; ++r) {
            float mx = fmaxf(fmaxf(s1[0][r], s1[1][r]), fmaxf(s1[2][r], s1[3][r]));
            mx = fmaxf(mx, __shfl_xor(mx, 1, 64));
            mx = fmaxf(mx, __shfl_xor(mx, 2, 64));
            mx = fmaxf(mx, __shfl_xor(mx, 4, 64));
            mx = fmaxf(mx, __shfl_xor(mx, 8, 64));
            float e0 = __expf(s1[0][r] - mx);
            float e1 = __expf(s1[1][r] - mx);
            float e2 = __expf(s1[2][r] - mx);
            float e3 = __expf(s1[3][r] - mx);
            float sm = e0 + e1 + e2 + e3;
            sm += __shfl_xor(sm, 1, 64);
            sm += __shfl_xor(sm, 2, 64);
            sm += __shfl_xor(sm, 4, 64);
            sm += __shfl_xor(sm, 8, 64);
            float ri = 1.f / sm;
            const int t = 16 * wl + l4 * 4 + r;
            Pb[(0 * 16 + l15) * PBS + t] = (__bf16)(e0 * ri);
            Pb[(1 * 16 + l15) * PBS + t] = (__bf16)(e1 * ri);
            Pb[(2 * 16 + l15) * PBS + t] = (__bf16)(e2 * ri);
            Pb[(3 * 16 + l15) * PBS + t] = (__bf16)(e3 * ri);
        }
        __syncthreads();

        // matmul2: O[h][c] += P[h][t] * ct2[c][t]
        bf16x8 pfr[2];
        #pragma unroll
        for (int ks = 0; ks < 2; ++ks)
            pfr[ks] = *(const bf16x8*)&Pb[myh * PBS + ks * 32 + l4 * 8];
        #pragma unroll
        for (int nt = 0; nt < 8; ++nt) {
            #pragma unroll
            for (int ks = 0; ks < 2; ++ks) {
                bf16x8 bfr = *(const bf16x8*)&ct2[(nt * 16 + l15) * CT2 + ks * 32 + l4 * 8];
                acc2[nt] = __builtin_amdgcn_mfma_f32_16x16x32_bf16(pfr[ks], bfr, acc2[nt], 0, 0, 0);
            }
        }
    }

    // epilogue: combine halves through fp32 Otr (aliases dead ctT region)
    __syncthreads();
    if (hf == 0) {
        #pragma unroll
        for (int nt = 0; nt < 8; ++nt)
            #pragma unroll
            for (int r = 0; r < 4; ++r)
                Otr[(16 * wl + l4 * 4 + r) * HST + nt * 16 + l15] = acc2[nt][r];
    }
    __syncthreads();
    if (hf == 1) {
        #pragma unroll
        for (int nt = 0; nt < 8; ++nt)
            #pragma unroll
            for (int r = 0; r < 4; ++r)
                Otr[(16 * wl + l4 * 4 + r) * HST + nt * 16 + l15] += acc2[nt][r];
    }
    __syncthreads();
    // h2 = hs + attn + emb, write channels-last bf16 coalesced
    __bf16* h2Tb = h2T + (size_t)b * SP * CC;
    #pragma unroll
    for (int it = 0; it < 2; ++it) {
        int q = it * 512 + tid;              // 1024 chunks
        int h = q >> 4, cc = q & 15;
        bf16x8 o;
        #pragma unroll
        for (int j = 0; j < 8; ++j) {
            int c = cc * 8 + j;
            o[j] = (__bf16)(Otr[h * HST + c] + (float)hsT[h * HST + c] + embs[c]);
        }
        *(bf16x8*)&h2Tb[((size_t)(h * WW + w)) * CC + cc * 8] = o;
    }
}

extern "C" void kernel_launch(void* const* d_in, const int* in_sizes, int n_in,
                              void* d_out, int out_size, void* d_ws, size_t ws_size,
                              hipStream_t stream)
{
    const float* x     = (const float*)d_in[0];
    const float* t     = (const float*)d_in[1];
    const int*   aim   = (const int*)  d_in[2];
    const float* cond  = (const float*)d_in[3];
    const float* gn1s  = (const float*)d_in[4];
    const float* gn1b  = (const float*)d_in[5];
    const float* c1w   = (const float*)d_in[6];
    const float* c1b   = (const float*)d_in[7];
    const float* mlpw  = (const float*)d_in[8];
    const float* mlpb  = (const float*)d_in[9];
    const float* cw    = (const float*)d_in[10];
    const float* cb    = (const float*)d_in[11];
    const float* gn2s  = (const float*)d_in[12];
    const float* gn2b  = (const float*)d_in[13];
    const float* c2w   = (const float*)d_in[14];
    const float* c2b   = (const float*)d_in[15];
    const float* emb   = (const float*)d_in[16];
    float* out = (float*)d_out;
    float* ws = (float*)d_ws;

    __bf16* aT    = (__bf16*)ws;                  // 2M bf16 (a1T, reused as a2T)
    __bf16* h1T   = (__bf16*)(ws + 1048576);
    __bf16* h2T   = (__bf16*)(ws + 2097152);
    __bf16* cmT   = (__bf16*)(ws + 3145728);
    __bf16* cm2   = (__bf16*)(ws + 4194304);
    __bf16* wt    = (__bf16*)(ws + 5242880);      // 2*9*16384 bf16
    float*  tembw = ws + 5390336;
    float*  st1   = ws + 5390848;
    float*  st2   = ws + 5391104;

    gn_stats_kernel<<<dim3(BB * NG), dim3(256), 0, stream>>>(x, st1);
    gn_apply_cl_kernel<<<dim3(32, BB), dim3(256), 0, stream>>>(x, st1, gn1s, gn1b, aT);
    wt_kernel<<<dim3(18), dim3(256), 0, stream>>>(c1w, c2w, wt);
    temb_kernel<<<dim3(BB), dim3(128), 0, stream>>>(t, mlpw, mlpb, tembw);
    conv1x1_kernel<<<dim3(16, 16, BB), dim3(256), 0, stream>>>(cond, cw, cb, cmT, cm2);
    conv_mfma_kernel<true, false><<<dim3(128, BB), dim3(256), 0, stream>>>(
        aT, wt, c1b, tembw, nullptr, h1T, nullptr);
    attn_kernel<<<dim3(WW, BB), dim3(512), 0, stream>>>(h1T, cmT, cm2, aim, emb, h2T);
    gn_stats_cl_kernel<<<dim3(BB * NG), dim3(256), 0, stream>>>(h2T, st2);
    gn_apply2_cl_kernel<<<dim3(2048), dim3(256), 0, stream>>>(h2T, st2, gn2s, gn2b, aT);
    conv_mfma_kernel<false, true><<<dim3(128, BB), dim3(256), 0, stream>>>(
        aT, wt + (size_t)9 * 16384, c2b, nullptr, x, nullptr, out);
}

// Round 6
// 320.684 us; speedup vs baseline: 5.3663x; 1.0378x over previous
//
#include <hip/hip_runtime.h>
#include <cmath>

#define BB 4
#define CC 128
#define HH 64
#define WW 64
#define SP 4096   // H*W
#define NG 32     // groups
#define TT 64     // attention uv-tile width

typedef __bf16 bf16x8 __attribute__((ext_vector_type(8)));
typedef __bf16 bf16x4 __attribute__((ext_vector_type(4)));
typedef float  f32x4  __attribute__((ext_vector_type(4)));

__device__ __forceinline__ float silu_f(float v) {
    return v / (1.f + __expf(-v));
}

// ---------------- GN1 stats (channels-first fp32 input) ----------------
__global__ __launch_bounds__(256) void gn_stats_kernel(
    const float* __restrict__ in, float* __restrict__ stats)
{
    const int bg = blockIdx.x;
    const float* p = in + (size_t)bg * 16384;
    float s = 0.f, s2 = 0.f;
    for (int i = threadIdx.x; i < 16384; i += 256) {
        float v = p[i];
        s += v; s2 += v * v;
    }
    #pragma unroll
    for (int off = 32; off >= 1; off >>= 1) {
        s  += __shfl_down(s,  off, 64);
        s2 += __shfl_down(s2, off, 64);
    }
    __shared__ float rs[4], rs2[4];
    const int wid = threadIdx.x >> 6;
    if ((threadIdx.x & 63) == 0) { rs[wid] = s; rs2[wid] = s2; }
    __syncthreads();
    if (threadIdx.x == 0) {
        float S = rs[0] + rs[1] + rs[2] + rs[3];
        float S2 = rs2[0] + rs2[1] + rs2[2] + rs2[3];
        float m = S * (1.f / 16384.f);
        float var = S2 * (1.f / 16384.f) - m * m;
        stats[bg * 2] = m;
        stats[bg * 2 + 1] = rsqrtf(var + 1e-5f);
    }
}

// ---------------- GN1 apply + SiLU + transpose to channels-last bf16 ----------------
__global__ __launch_bounds__(256) void gn_apply_cl_kernel(
    const float* __restrict__ in, const float* __restrict__ stats,
    const float* __restrict__ scale, const float* __restrict__ bias,
    __bf16* __restrict__ outT)
{
    const int p0 = blockIdx.x * 128;
    const int b = blockIdx.y;
    const int tid = threadIdx.x;
    __shared__ __bf16 T[128 * 136];   // [p local][c]

    for (int it = 0; it < 16; ++it) {
        int q = it * 256 + tid;            // 4096 float4 tasks
        int c = q >> 5, p4 = q & 31;
        float4 v = *(const float4*)&in[((size_t)(b * CC + c)) * SP + p0 + p4 * 4];
        int g = c >> 2;
        float m = stats[(b * NG + g) * 2], inv = stats[(b * NG + g) * 2 + 1];
        float sc = scale[c], bi = bias[c];
        T[(p4 * 4 + 0) * 136 + c] = (__bf16)silu_f((v.x - m) * inv * sc + bi);
        T[(p4 * 4 + 1) * 136 + c] = (__bf16)silu_f((v.y - m) * inv * sc + bi);
        T[(p4 * 4 + 2) * 136 + c] = (__bf16)silu_f((v.z - m) * inv * sc + bi);
        T[(p4 * 4 + 3) * 136 + c] = (__bf16)silu_f((v.w - m) * inv * sc + bi);
    }
    __syncthreads();
    for (int it = 0; it < 8; ++it) {
        int q = it * 256 + tid;            // 2048 16B chunks
        int pr = q >> 4, cc = q & 15;
        *(bf16x8*)&outT[((size_t)(b * SP + p0 + pr)) * CC + cc * 8] =
            *(const bf16x8*)&T[pr * 136 + cc * 8];
    }
}

// ---------------- weight transpose: W[co][ci][3][3] fp32 -> Wt[tap][co][ci] bf16 ----------------
__global__ __launch_bounds__(256) void wt_kernel(
    const float* __restrict__ w1, const float* __restrict__ w2,
    __bf16* __restrict__ wt)   // [2][9][128][128]
{
    const int blk = blockIdx.x;        // 0..17
    const int wsel = blk / 9, tap = blk % 9;
    const float* src = wsel ? w2 : w1;
    __bf16* dst = wt + (size_t)wsel * 9 * 16384 + (size_t)tap * 16384;
    for (int it = 0; it < 64; ++it) {
        int q = it * 256 + threadIdx.x;   // q = co*128+ci
        dst[q] = (__bf16)src[(size_t)q * 9 + tap];
    }
}

// ---------------- time-embedding MLP (coalesced, LDS-staged) ----------------
// grid 8 (cog): block computes co in [cog*16, cog*16+16) for all 4 b
__global__ __launch_bounds__(256) void temb_kernel(
    const float* __restrict__ t, const float* __restrict__ w,
    const float* __restrict__ bias, float* __restrict__ temb)
{
    const int cog = blockIdx.x;
    const int tid = threadIdx.x;
    __shared__ float st[4][512];
    __shared__ float wr[16][512];
    for (int it = 0; it < 8; ++it) {
        int q = it * 256 + tid;            // 2048
        st[q >> 9][q & 511] = silu_f(t[q]);
    }
    for (int it = 0; it < 8; ++it) {
        int q = it * 256 + tid;            // 2048 float4
        int row = q >> 7, col4 = q & 127;
        *(float4*)&wr[row][col4 * 4] =
            *(const float4*)&w[(size_t)(cog * 16 + row) * 512 + col4 * 4];
    }
    __syncthreads();
    const int col = tid >> 4, seg = tid & 15;
    float acc[4] = {0.f, 0.f, 0.f, 0.f};
    for (int k = seg * 32; k < seg * 32 + 32; ++k) {
        float wv = wr[col][k];
        acc[0] += st[0][k] * wv;
        acc[1] += st[1][k] * wv;
        acc[2] += st[2][k] * wv;
        acc[3] += st[3][k] * wv;
    }
    #pragma unroll
    for (int o = 1; o < 16; o <<= 1) {
        #pragma unroll
        for (int b4 = 0; b4 < 4; ++b4)
            acc[b4] += __shfl_xor(acc[b4], o, 64);
    }
    if (seg == 0) {
        float bv = bias[cog * 16 + col];
        #pragma unroll
        for (int b4 = 0; b4 < 4; ++b4)
            temb[b4 * 128 + cog * 16 + col] = acc[b4] + bv;
    }
}

// ---------------- 3x3 conv via per-tap MFMA, weights from global (L2) ----------------
template<bool FUSE_TEMB, bool OUT_CF>
__global__ __launch_bounds__(256) void conv_mfma_kernel(
    const __bf16* __restrict__ inT, const __bf16* __restrict__ wt,
    const float* __restrict__ bias, const float* __restrict__ temb,
    const float* __restrict__ resid, __bf16* __restrict__ outT,
    float* __restrict__ outF)
{
    const int pb = blockIdx.x;
    const int y = pb >> 1, x0 = (pb & 1) * 32;
    const int b = blockIdx.y;
    const int tid = threadIdx.x;
    const int l = tid & 63, wv = tid >> 6;
    const int l15 = l & 15, l4 = l >> 4;

    f32x4 acc[2][2];
    #pragma unroll
    for (int mb = 0; mb < 2; ++mb)
        #pragma unroll
        for (int nb = 0; nb < 2; ++nb) acc[mb][nb] = (f32x4){0.f, 0.f, 0.f, 0.f};

    const __bf16* inTb = inT + (size_t)b * SP * CC;

    for (int tap = 0; tap < 9; ++tap) {
        const int dy = tap / 3 - 1, dx = tap % 3 - 1;
        const int yy = y + dy;
        const bool yok = ((unsigned)yy) < 64u;
        #pragma unroll
        for (int ks = 0; ks < 4; ++ks) {
            bf16x8 bfr[2];
            #pragma unroll
            for (int nb = 0; nb < 2; ++nb) {
                int xx = x0 + nb * 16 + l15 + dx;
                bool ok = yok && (((unsigned)xx) < 64u);
                bf16x8 v;
                if (ok) {
                    v = *(const bf16x8*)&inTb[((size_t)(yy * 64 + xx)) * CC + ks * 32 + l4 * 8];
                } else {
                    #pragma unroll
                    for (int j = 0; j < 8; ++j) v[j] = (__bf16)0.f;
                }
                bfr[nb] = v;
            }
            #pragma unroll
            for (int mb = 0; mb < 2; ++mb) {
                int co = wv * 32 + mb * 16 + l15;
                bf16x8 afr = *(const bf16x8*)&wt[((size_t)tap * 128 + co) * 128 + ks * 32 + l4 * 8];
                #pragma unroll
                for (int nb = 0; nb < 2; ++nb)
                    acc[mb][nb] = __builtin_amdgcn_mfma_f32_16x16x32_bf16(afr, bfr[nb], acc[mb][nb], 0, 0, 0);
            }
        }
    }

    if (OUT_CF) {
        #pragma unroll
        for (int mb = 0; mb < 2; ++mb) {
            #pragma unroll
            for (int r = 0; r < 4; ++r) {
                int co = wv * 32 + mb * 16 + l4 * 4 + r;
                float bv = bias[co];
                #pragma unroll
                for (int nb = 0; nb < 2; ++nb) {
                    int p = y * 64 + x0 + nb * 16 + l15;
                    size_t o = ((size_t)(b * CC + co)) * SP + p;
                    outF[o] = acc[mb][nb][r] + bv + resid[o];
                }
            }
        }
    } else {
        __shared__ __bf16 Otr[32 * 136];   // [x local][co]
        #pragma unroll
        for (int mb = 0; mb < 2; ++mb) {
            #pragma unroll
            for (int r = 0; r < 4; ++r) {
                int co = wv * 32 + mb * 16 + l4 * 4 + r;
                float bv = bias[co] + (FUSE_TEMB ? temb[b * CC + co] : 0.f);
                #pragma unroll
                for (int nb = 0; nb < 2; ++nb) {
                    int xl = nb * 16 + l15;
                    Otr[xl * 136 + co] = (__bf16)(acc[mb][nb][r] + bv);
                }
            }
        }
        __syncthreads();
        #pragma unroll
        for (int it = 0; it < 2; ++it) {
            int q = it * 256 + tid;           // 512 16B chunks
            int xl = q >> 4, cc = q & 15;
            *(bf16x8*)&outT[((size_t)(b * SP + y * 64 + x0 + xl)) * CC + cc * 8] =
                *(const bf16x8*)&Otr[xl * 136 + cc * 8];
        }
    }
}

// ---------------- 1x1 conv -> cmT [b][p][co] bf16 (x 1/sqrt(128)) + cm2 [b][co][p] bf16 ----------------
__global__ __launch_bounds__(256) void conv1x1_kernel(
    const float* __restrict__ in, const float* __restrict__ wgt,
    const float* __restrict__ bias, __bf16* __restrict__ cmT,
    __bf16* __restrict__ cm2)
{
    const int p0 = blockIdx.x * 256;
    const int p = p0 + threadIdx.x;
    const int cog = blockIdx.y, b = blockIdx.z;
    __shared__ float wl[128 * 8];
    __shared__ __bf16 tr[8][272];
    for (int i = threadIdx.x; i < 1024; i += 256) {
        int j = i & 7, ci = i >> 3;
        wl[i] = wgt[(size_t)(cog * 8 + j) * 128 + ci];
    }
    __syncthreads();
    float acc[8];
    #pragma unroll
    for (int j = 0; j < 8; ++j) acc[j] = bias[cog * 8 + j];
    const float* inb = in + (size_t)b * CC * SP + p;
    for (int ci = 0; ci < 128; ++ci) {
        float v = inb[ci * SP];
        const float4* wk4 = (const float4*)(wl + ci * 8);
        float4 wa = wk4[0], wb = wk4[1];
        acc[0] += v * wa.x; acc[1] += v * wa.y;
        acc[2] += v * wa.z; acc[3] += v * wa.w;
        acc[4] += v * wb.x; acc[5] += v * wb.y;
        acc[6] += v * wb.z; acc[7] += v * wb.w;
    }
    const float scl = 0.088388347648318447f;  // 1/sqrt(128)
    bf16x8 v8s;
    #pragma unroll
    for (int j = 0; j < 8; ++j) {
        v8s[j] = (__bf16)(acc[j] * scl);
        tr[j][threadIdx.x] = (__bf16)acc[j];
    }
    *(bf16x8*)&cmT[((size_t)(b * SP + p)) * CC + cog * 8] = v8s;
    __syncthreads();
    {
        int j = threadIdx.x >> 5, t32 = threadIdx.x & 31;
        *(bf16x8*)&cm2[((size_t)(b * CC + cog * 8 + j)) * SP + p0 + t32 * 8] =
            *(const bf16x8*)&tr[j][t32 * 8];
    }
}

// ---------------- fused cross-attention: grid (w, b, s), 256 thr, 1 barrier/tile ----------------
#define HST 136   // hsT row stride (bf16)
#define CT2 72    // ct2 row stride (bf16)
#define PBS 72    // Pb row stride (bf16)

// LDS pool (bytes):
//   0     : ct2[2]  2 x 128*72*2 = 36864   (epilogue alias: Otr fp32 64*136*4 = 34816)
//   36864 : Pb[2]   2 x 64*72*2  = 18432
//   55296 : hsT     64*136*2     = 17408
#define POOL_BYTES 72704

__global__ __launch_bounds__(256) void attn_kernel(
    const __bf16* __restrict__ h1T, const __bf16* __restrict__ cmT,
    const __bf16* __restrict__ cm2, float* __restrict__ part0,
    float* __restrict__ part1)
{
    const int w = blockIdx.x;
    const int b = blockIdx.y;
    const int s = blockIdx.z;          // even/odd uv tiles
    const int tid = threadIdx.x;
    const int wl = tid >> 6;           // wave 0..3
    const int l = tid & 63, l15 = l & 15, l4 = l >> 4;

    __shared__ __align__(16) char pool[POOL_BYTES];
    __bf16* ct2p = (__bf16*)pool;                 // two buffers of 9216 bf16
    __bf16* Pbp  = (__bf16*)(pool + 36864);       // two buffers of 4608 bf16
    __bf16* hsT  = (__bf16*)(pool + 55296);
    float*  Otr  = (float*)pool;                  // epilogue alias

    const __bf16* h1Tb = h1T + (size_t)b * SP * CC;
    const __bf16* cmTb = cmT + (size_t)b * SP * CC;
    const __bf16* cm2b = cm2 + (size_t)b * CC * SP;

    // stage hsT [h][c] + first ct2 buffer (tile 0 of this half)
    #pragma unroll
    for (int it = 0; it < 4; ++it) {
        int q = it * 256 + tid;          // 1024 chunks
        int h = q >> 4, cc = q & 15;
        *(bf16x8*)&hsT[h * HST + cc * 8] =
            *(const bf16x8*)&h1Tb[((size_t)(h * WW + w)) * CC + cc * 8];
    }
    {
        const int uv0 = s * TT;
        #pragma unroll
        for (int it = 0; it < 4; ++it) {
            int q = it * 256 + tid;
            int c = q >> 3, tc = q & 7;
            *(bf16x8*)&ct2p[c * CT2 + tc * 8] =
                *(const bf16x8*)&cm2b[((size_t)c) * SP + uv0 + tc * 8];
        }
    }
    __syncthreads();

    // hoist matmul1 B-frags (hsT rows): B[n=h][k=c]
    bf16x8 hfr[4][4];
    #pragma unroll
    for (int nt = 0; nt < 4; ++nt)
        #pragma unroll
        for (int ks = 0; ks < 4; ++ks)
            hfr[nt][ks] = *(const bf16x8*)&hsT[(nt * 16 + l15) * HST + ks * 32 + l4 * 8];

    f32x4 acc2[8];
    #pragma unroll
    for (int nt = 0; nt < 8; ++nt) acc2[nt] = (f32x4){0.f, 0.f, 0.f, 0.f};

    // produce tile 0: mm1 (A from global cmT) + softmax + Pb[buf0]
    #define PRODUCE(TILEIDX, BUF)                                                        \
    {                                                                                    \
        const int uv0q = ((TILEIDX) * 2 + s) * TT;                                       \
        const __bf16* arow = cmTb + ((size_t)(uv0q + 16 * wl + l15)) * CC;               \
        bf16x8 afr[4];                                                                   \
        _Pragma("unroll")                                                                \
        for (int ks = 0; ks < 4; ++ks) afr[ks] = *(const bf16x8*)&arow[ks * 32 + l4 * 8];\
        f32x4 s1[4];                                                                     \
        _Pragma("unroll")                                                                \
        for (int nt = 0; nt < 4; ++nt) {                                                 \
            s1[nt] = (f32x4){0.f, 0.f, 0.f, 0.f};                                        \
            _Pragma("unroll")                                                            \
            for (int ks = 0; ks < 4; ++ks)                                               \
                s1[nt] = __builtin_amdgcn_mfma_f32_16x16x32_bf16(afr[ks], hfr[nt][ks], s1[nt], 0, 0, 0); \
        }                                                                                \
        _Pragma("unroll")                                                                \
        for (int r = 0; r < 4; ++r) {                                                    \
            float mx = fmaxf(fmaxf(s1[0][r], s1[1][r]), fmaxf(s1[2][r], s1[3][r]));      \
            mx = fmaxf(mx, __shfl_xor(mx, 1, 64));                                       \
            mx = fmaxf(mx, __shfl_xor(mx, 2, 64));                                       \
            mx = fmaxf(mx, __shfl_xor(mx, 4, 64));                                       \
            mx = fmaxf(mx, __shfl_xor(mx, 8, 64));                                       \
            float e0 = __expf(s1[0][r] - mx);                                            \
            float e1 = __expf(s1[1][r] - mx);                                            \
            float e2 = __expf(s1[2][r] - mx);                                            \
            float e3 = __expf(s1[3][r] - mx);                                            \
            float sm = e0 + e1 + e2 + e3;                                                \
            sm += __shfl_xor(sm, 1, 64);                                                 \
            sm += __shfl_xor(sm, 2, 64);                                                 \
            sm += __shfl_xor(sm, 4, 64);                                                 \
            sm += __shfl_xor(sm, 8, 64);                                                 \
            float ri = 1.f / sm;                                                         \
            s1[0][r] = e0 * ri; s1[1][r] = e1 * ri;                                      \
            s1[2][r] = e2 * ri; s1[3][r] = e3 * ri;                                      \
        }                                                                                \
        __bf16* PbW = Pbp + (BUF) * 4608;                                                \
        _Pragma("unroll")                                                                \
        for (int nt = 0; nt < 4; ++nt) {                                                 \
            bf16x4 pk;                                                                   \
            pk[0] = (__bf16)s1[nt][0]; pk[1] = (__bf16)s1[nt][1];                        \
            pk[2] = (__bf16)s1[nt][2]; pk[3] = (__bf16)s1[nt][3];                        \
            *(bf16x4*)&PbW[(nt * 16 + l15) * PBS + 16 * wl + l4 * 4] = pk;               \
        }                                                                                \
    }

    PRODUCE(0, 0)

    const int myh = 16 * wl + l15;
    for (int i = 0; i < 32; ++i) {
        const int cur = i & 1;
        __syncthreads();
        // consume tile i: O[h][c] += P[h][t] * ct2[c][t]
        {
            const __bf16* PbR = Pbp + cur * 4608;
            const __bf16* ctR = ct2p + cur * 9216;
            bf16x8 pfr[2];
            #pragma unroll
            for (int ks = 0; ks < 2; ++ks)
                pfr[ks] = *(const bf16x8*)&PbR[myh * PBS + ks * 32 + l4 * 8];
            #pragma unroll
            for (int nt = 0; nt < 8; ++nt) {
                #pragma unroll
                for (int ks = 0; ks < 2; ++ks) {
                    bf16x8 bfr = *(const bf16x8*)&ctR[(nt * 16 + l15) * CT2 + ks * 32 + l4 * 8];
                    acc2[nt] = __builtin_amdgcn_mfma_f32_16x16x32_bf16(pfr[ks], bfr, acc2[nt], 0, 0, 0);
                }
            }
        }
        if (i < 31) {
            // stage ct2 for tile i+1 into the other buffer
            const int uv0n = ((i + 1) * 2 + s) * TT;
            __bf16* ctW = ct2p + (1 - cur) * 9216;
            #pragma unroll
            for (int it = 0; it < 4; ++it) {
                int q = it * 256 + tid;
                int c = q >> 3, tc = q & 7;
                *(bf16x8*)&ctW[c * CT2 + tc * 8] =
                    *(const bf16x8*)&cm2b[((size_t)c) * SP + uv0n + tc * 8];
            }
            PRODUCE(i + 1, 1 - cur)
        }
    }

    // epilogue: write fp32 partial attn contribution
    __syncthreads();
    #pragma unroll
    for (int nt = 0; nt < 8; ++nt)
        #pragma unroll
        for (int r = 0; r < 4; ++r)
            Otr[(16 * wl + l4 * 4 + r) * HST + nt * 16 + l15] = acc2[nt][r];
    __syncthreads();
    float* pO = (s == 0) ? part0 : part1;
    #pragma unroll
    for (int it = 0; it < 8; ++it) {
        int q = it * 256 + tid;              // 2048 float4 tasks
        int h = q >> 5, c4 = q & 31;
        float4 o4 = *(const float4*)&Otr[h * HST + c4 * 4];
        *(float4*)&pO[((size_t)(b * SP + h * WW + w)) * CC + c4 * 4] = o4;
    }
    #undef PRODUCE
}

// ---------------- GN2 stats partials: h2 = h1T + p0 + p1 + emb, coalesced ----------------
__global__ __launch_bounds__(256) void gn2_stats_kernel(
    const __bf16* __restrict__ h1T, const float* __restrict__ p0,
    const float* __restrict__ p1, const int* __restrict__ aim,
    const float* __restrict__ emb, float* __restrict__ pstat)
{
    const int pb = blockIdx.x, b = blockIdx.y;
    const int tid = threadIdx.x;
    const int c4 = tid & 31;
    const float4 ev = *(const float4*)&emb[aim[b] * CC + c4 * 4];
    float s = 0.f, s2 = 0.f;
    for (int it = 0; it < 16; ++it) {
        int prow = it * 8 + (tid >> 5);
        size_t base = ((size_t)(b * SP + pb * 128 + prow)) * CC + c4 * 4;
        float4 a = *(const float4*)&p0[base];
        float4 bb = *(const float4*)&p1[base];
        bf16x4 hv = *(const bf16x4*)&h1T[base];
        float v0 = a.x + bb.x + (float)hv[0] + ev.x;
        float v1 = a.y + bb.y + (float)hv[1] + ev.y;
        float v2 = a.z + bb.z + (float)hv[2] + ev.z;
        float v3 = a.w + bb.w + (float)hv[3] + ev.w;
        s += v0 + v1 + v2 + v3;
        s2 += v0 * v0 + v1 * v1 + v2 * v2 + v3 * v3;
    }
    s  += __shfl_down(s,  32, 64);
    s2 += __shfl_down(s2, 32, 64);
    __shared__ float ls[4][32][2];
    const int wv = tid >> 6, ll = tid & 63;
    if (ll < 32) { ls[wv][ll][0] = s; ls[wv][ll][1] = s2; }
    __syncthreads();
    if (tid < 32) {
        float S = ls[0][tid][0] + ls[1][tid][0] + ls[2][tid][0] + ls[3][tid][0];
        float S2 = ls[0][tid][1] + ls[1][tid][1] + ls[2][tid][1] + ls[3][tid][1];
        int g = tid;
        pstat[(((size_t)b * NG + g) * 32 + pb) * 2]     = S;
        pstat[(((size_t)b * NG + g) * 32 + pb) * 2 + 1] = S2;
    }
}

__global__ __launch_bounds__(128) void gn2_finalize_kernel(
    const float* __restrict__ pstat, float* __restrict__ st2)
{
    const int i = threadIdx.x;   // b*NG+g
    float S = 0.f, S2 = 0.f;
    for (int k = 0; k < 32; ++k) {
        S  += pstat[((size_t)i * 32 + k) * 2];
        S2 += pstat[((size_t)i * 32 + k) * 2 + 1];
    }
    float m = S * (1.f / 16384.f);
    float var = S2 * (1.f / 16384.f) - m * m;
    st2[i * 2] = m;
    st2[i * 2 + 1] = rsqrtf(var + 1e-5f);
}

// ---------------- GN2 apply + SiLU: reconstruct h2, normalize -> aT bf16 ----------------
__global__ __launch_bounds__(256) void gn2_apply_kernel(
    const __bf16* __restrict__ h1T, const float* __restrict__ p0,
    const float* __restrict__ p1, const int* __restrict__ aim,
    const float* __restrict__ emb, const float* __restrict__ st2,
    const float* __restrict__ scale, const float* __restrict__ bias,
    __bf16* __restrict__ outT)
{
    const int pb = blockIdx.x, b = blockIdx.y;
    const int tid = threadIdx.x;
    const int c4 = tid & 31;
    const int g = c4;
    const float4 ev = *(const float4*)&emb[aim[b] * CC + c4 * 4];
    const float4 sc = *(const float4*)&scale[c4 * 4];
    const float4 bi = *(const float4*)&bias[c4 * 4];
    const float m = st2[(b * NG + g) * 2], inv = st2[(b * NG + g) * 2 + 1];
    for (int it = 0; it < 16; ++it) {
        int prow = it * 8 + (tid >> 5);
        size_t base = ((size_t)(b * SP + pb * 128 + prow)) * CC + c4 * 4;
        float4 a = *(const float4*)&p0[base];
        float4 bb = *(const float4*)&p1[base];
        bf16x4 hv = *(const bf16x4*)&h1T[base];
        bf16x4 o;
        o[0] = (__bf16)silu_f((a.x + bb.x + (float)hv[0] + ev.x - m) * inv * sc.x + bi.x);
        o[1] = (__bf16)silu_f((a.y + bb.y + (float)hv[1] + ev.y - m) * inv * sc.y + bi.y);
        o[2] = (__bf16)silu_f((a.z + bb.z + (float)hv[2] + ev.z - m) * inv * sc.z + bi.z);
        o[3] = (__bf16)silu_f((a.w + bb.w + (float)hv[3] + ev.w - m) * inv * sc.w + bi.w);
        *(bf16x4*)&outT[base] = o;
    }
}

extern "C" void kernel_launch(void* const* d_in, const int* in_sizes, int n_in,
                              void* d_out, int out_size, void* d_ws, size_t ws_size,
                              hipStream_t stream)
{
    const float* x     = (const float*)d_in[0];
    const float* t     = (const float*)d_in[1];
    const int*   aim   = (const int*)  d_in[2];
    const float* cond  = (const float*)d_in[3];
    const float* gn1s  = (const float*)d_in[4];
    const float* gn1b  = (const float*)d_in[5];
    const float* c1w   = (const float*)d_in[6];
    const float* c1b   = (const float*)d_in[7];
    const float* mlpw  = (const float*)d_in[8];
    const float* mlpb  = (const float*)d_in[9];
    const float* cw    = (const float*)d_in[10];
    const float* cb    = (const float*)d_in[11];
    const float* gn2s  = (const float*)d_in[12];
    const float* gn2b  = (const float*)d_in[13];
    const float* c2w   = (const float*)d_in[14];
    const float* c2b   = (const float*)d_in[15];
    const float* emb   = (const float*)d_in[16];
    float* out = (float*)d_out;
    float* ws = (float*)d_ws;

    __bf16* aT    = (__bf16*)ws;                  // 2,097,152 bf16
    __bf16* h1T   = (__bf16*)(ws + 1048576);
    __bf16* cmT   = (__bf16*)(ws + 2097152);
    __bf16* cm2   = (__bf16*)(ws + 3145728);
    float*  p0    = ws + 4194304;                 // 2,097,152 fp32
    float*  p1    = ws + 6291456;
    __bf16* wt    = (__bf16*)(ws + 8388608);      // 294,912 bf16
    float*  tembw = ws + 8536064;
    float*  st1   = ws + 8536576;
    float*  st2   = ws + 8536832;
    float*  pstat = ws + 8537088;                 // 8192 fp32

    gn_stats_kernel<<<dim3(BB * NG), dim3(256), 0, stream>>>(x, st1);
    gn_apply_cl_kernel<<<dim3(32, BB), dim3(256), 0, stream>>>(x, st1, gn1s, gn1b, aT);
    wt_kernel<<<dim3(18), dim3(256), 0, stream>>>(c1w, c2w, wt);
    temb_kernel<<<dim3(8), dim3(256), 0, stream>>>(t, mlpw, mlpb, tembw);
    conv1x1_kernel<<<dim3(16, 16, BB), dim3(256), 0, stream>>>(cond, cw, cb, cmT, cm2);
    conv_mfma_kernel<true, false><<<dim3(128, BB), dim3(256), 0, stream>>>(
        aT, wt, c1b, tembw, nullptr, h1T, nullptr);
    attn_kernel<<<dim3(WW, BB, 2), dim3(256), 0, stream>>>(h1T, cmT, cm2, p0, p1);
    gn2_stats_kernel<<<dim3(32, BB), dim3(256), 0, stream>>>(h1T, p0, p1, aim, emb, pstat);
    gn2_finalize_kernel<<<dim3(1), dim3(128), 0, stream>>>(pstat, st2);
    gn2_apply_kernel<<<dim3(32, BB), dim3(256), 0, stream>>>(
        h1T, p0, p1, aim, emb, st2, gn2s, gn2b, aT);
    conv_mfma_kernel<false, true><<<dim3(128, BB), dim3(256), 0, stream>>>(
        aT, wt + (size_t)9 * 16384, c2b, nullptr, x, nullptr, out);
}

// Round 8
// 304.182 us; speedup vs baseline: 5.6575x; 1.0542x over previous
//
#include <hip/hip_runtime.h>
#include <cmath>

#define BB 4
#define CC 128
#define HH 64
#define WW 64
#define SP 4096   // H*W
#define NG 32     // groups
#define TT 64     // attention uv-tile width

typedef __bf16 bf16x8 __attribute__((ext_vector_type(8)));
typedef __bf16 bf16x4 __attribute__((ext_vector_type(4)));
typedef float  f32x4  __attribute__((ext_vector_type(4)));

__device__ __forceinline__ float silu_f(float v) {
    return v / (1.f + __expf(-v));
}

// ---------------- GN1 stats (channels-first fp32 input) ----------------
__global__ __launch_bounds__(256) void gn_stats_kernel(
    const float* __restrict__ in, float* __restrict__ stats)
{
    const int bg = blockIdx.x;
    const float* p = in + (size_t)bg * 16384;
    float s = 0.f, s2 = 0.f;
    for (int i = threadIdx.x; i < 16384; i += 256) {
        float v = p[i];
        s += v; s2 += v * v;
    }
    #pragma unroll
    for (int off = 32; off >= 1; off >>= 1) {
        s  += __shfl_down(s,  off, 64);
        s2 += __shfl_down(s2, off, 64);
    }
    __shared__ float rs[4], rs2[4];
    const int wid = threadIdx.x >> 6;
    if ((threadIdx.x & 63) == 0) { rs[wid] = s; rs2[wid] = s2; }
    __syncthreads();
    if (threadIdx.x == 0) {
        float S = rs[0] + rs[1] + rs[2] + rs[3];
        float S2 = rs2[0] + rs2[1] + rs2[2] + rs2[3];
        float m = S * (1.f / 16384.f);
        float var = S2 * (1.f / 16384.f) - m * m;
        stats[bg * 2] = m;
        stats[bg * 2 + 1] = rsqrtf(var + 1e-5f);
    }
}

// ---------------- GN1 apply + SiLU + transpose to channels-last bf16 ----------------
__global__ __launch_bounds__(256) void gn_apply_cl_kernel(
    const float* __restrict__ in, const float* __restrict__ stats,
    const float* __restrict__ scale, const float* __restrict__ bias,
    __bf16* __restrict__ outT)
{
    const int p0 = blockIdx.x * 128;
    const int b = blockIdx.y;
    const int tid = threadIdx.x;
    __shared__ __bf16 T[128 * 136];   // [p local][c]

    for (int it = 0; it < 16; ++it) {
        int q = it * 256 + tid;            // 4096 float4 tasks
        int c = q >> 5, p4 = q & 31;
        float4 v = *(const float4*)&in[((size_t)(b * CC + c)) * SP + p0 + p4 * 4];
        int g = c >> 2;
        float m = stats[(b * NG + g) * 2], inv = stats[(b * NG + g) * 2 + 1];
        float sc = scale[c], bi = bias[c];
        T[(p4 * 4 + 0) * 136 + c] = (__bf16)silu_f((v.x - m) * inv * sc + bi);
        T[(p4 * 4 + 1) * 136 + c] = (__bf16)silu_f((v.y - m) * inv * sc + bi);
        T[(p4 * 4 + 2) * 136 + c] = (__bf16)silu_f((v.z - m) * inv * sc + bi);
        T[(p4 * 4 + 3) * 136 + c] = (__bf16)silu_f((v.w - m) * inv * sc + bi);
    }
    __syncthreads();
    for (int it = 0; it < 8; ++it) {
        int q = it * 256 + tid;            // 2048 16B chunks
        int pr = q >> 4, cc = q & 15;
        *(bf16x8*)&outT[((size_t)(b * SP + p0 + pr)) * CC + cc * 8] =
            *(const bf16x8*)&T[pr * 136 + cc * 8];
    }
}

// ---------------- weight transpose: W[co][ci][3][3] fp32 -> Wt[tap][co][ci] bf16 ----------------
__global__ __launch_bounds__(256) void wt_kernel(
    const float* __restrict__ w1, const float* __restrict__ w2,
    __bf16* __restrict__ wt)   // [2][9][128][128]
{
    const int blk = blockIdx.x;        // 0..17
    const int wsel = blk / 9, tap = blk % 9;
    const float* src = wsel ? w2 : w1;
    __bf16* dst = wt + (size_t)wsel * 9 * 16384 + (size_t)tap * 16384;
    for (int it = 0; it < 64; ++it) {
        int q = it * 256 + threadIdx.x;   // q = co*128+ci
        dst[q] = (__bf16)src[(size_t)q * 9 + tap];
    }
}

// ---------------- time-embedding MLP ----------------
__global__ __launch_bounds__(256) void temb_kernel(
    const float* __restrict__ t, const float* __restrict__ w,
    const float* __restrict__ bias, float* __restrict__ temb)
{
    const int cog = blockIdx.x;
    const int tid = threadIdx.x;
    __shared__ float st[4][512];
    __shared__ float wr[16][512];
    for (int it = 0; it < 8; ++it) {
        int q = it * 256 + tid;            // 2048
        st[q >> 9][q & 511] = silu_f(t[q]);
    }
    for (int it = 0; it < 8; ++it) {
        int q = it * 256 + tid;            // 2048 float4
        int row = q >> 7, col4 = q & 127;
        *(float4*)&wr[row][col4 * 4] =
            *(const float4*)&w[(size_t)(cog * 16 + row) * 512 + col4 * 4];
    }
    __syncthreads();
    const int col = tid >> 4, seg = tid & 15;
    float acc[4] = {0.f, 0.f, 0.f, 0.f};
    for (int k = seg * 32; k < seg * 32 + 32; ++k) {
        float wv = wr[col][k];
        acc[0] += st[0][k] * wv;
        acc[1] += st[1][k] * wv;
        acc[2] += st[2][k] * wv;
        acc[3] += st[3][k] * wv;
    }
    #pragma unroll
    for (int o = 1; o < 16; o <<= 1) {
        #pragma unroll
        for (int b4 = 0; b4 < 4; ++b4)
            acc[b4] += __shfl_xor(acc[b4], o, 64);
    }
    if (seg == 0) {
        float bv = bias[cog * 16 + col];
        #pragma unroll
        for (int b4 = 0; b4 < 4; ++b4)
            temb[b4 * 128 + cog * 16 + col] = acc[b4] + bv;
    }
}

// ---------------- 3x3 conv v3: LDS input tile + reg-double-buffered weights ----------------
template<bool FUSE_TEMB, bool OUT_CF>
__global__ __launch_bounds__(256) void conv_mfma_kernel(
    const __bf16* __restrict__ inT, const __bf16* __restrict__ wt,
    const float* __restrict__ bias, const float* __restrict__ temb,
    const float* __restrict__ resid, __bf16* __restrict__ outT,
    float* __restrict__ outF)
{
    const int y   = blockIdx.x >> 1;
    const int coh = blockIdx.x & 1;
    const int b   = blockIdx.y;
    const int tid = threadIdx.x;
    const int l = tid & 63, wv = tid >> 6;
    const int l15 = l & 15, l4 = l >> 4;
    const int mB = (wv & 1) * 32;         // wave co base (block-local)
    const int xh = (wv >> 1) * 32;        // wave x base

    __shared__ __bf16 inS[3 * 66 * 136];  // [row 3][xs 66][c], xs = x+1 (halo)
    __shared__ __bf16 Otr[64 * 72];       // epilogue transpose (CL path)

    // stage 3 input rows with zero halo
    const __bf16* inTb = inT + (size_t)b * SP * CC;
    for (int q = tid; q < 3 * 66 * 16; q += 256) {
        int cc = q & 15;
        int xs = (q >> 4) % 66;
        int r  = (q >> 4) / 66;
        int yy = y + r - 1;
        int xg = xs - 1;
        bf16x8 v;
        if (((unsigned)yy < 64u) && ((unsigned)xg < 64u)) {
            v = *(const bf16x8*)&inTb[((size_t)(yy * 64 + xg)) * CC + cc * 8];
        } else {
            #pragma unroll
            for (int j = 0; j < 8; ++j) v[j] = (__bf16)0.f;
        }
        *(bf16x8*)&inS[(r * 66 + xs) * 136 + cc * 8] = v;
    }
    __syncthreads();

    f32x4 acc[2][2];
    #pragma unroll
    for (int mb = 0; mb < 2; ++mb)
        #pragma unroll
        for (int nb = 0; nb < 2; ++nb) acc[mb][nb] = (f32x4){0.f, 0.f, 0.f, 0.f};

    // weight lane pointers (A-frag: lane l15 = co row, quad l4 over k-chunk)
    const __bf16* wp0 = wt + (size_t)(coh * 64 + mB + l15) * 128 + l4 * 8;
    const __bf16* wp1 = wt + (size_t)(coh * 64 + mB + 16 + l15) * 128 + l4 * 8;

    bf16x8 wb[2][2][4];   // [buf][mb][ks]
    #pragma unroll
    for (int ks = 0; ks < 4; ++ks) {
        wb[0][0][ks] = *(const bf16x8*)(wp0 + ks * 32);
        wb[0][1][ks] = *(const bf16x8*)(wp1 + ks * 32);
    }

    #pragma unroll
    for (int tap = 0; tap < 9; ++tap) {
        const int cur = tap & 1, nxt = cur ^ 1;
        if (tap < 8) {
            #pragma unroll
            for (int ks = 0; ks < 4; ++ks) {
                wb[nxt][0][ks] = *(const bf16x8*)(wp0 + (tap + 1) * 16384 + ks * 32);
                wb[nxt][1][ks] = *(const bf16x8*)(wp1 + (tap + 1) * 16384 + ks * 32);
            }
        }
        // input row/col for this tap (xs = x + 1 + dx = x + tap%3)
        const __bf16* rb = &inS[((tap / 3) * 66 + xh + (tap % 3)) * 136];
        #pragma unroll
        for (int ks = 0; ks < 4; ++ks) {
            bf16x8 b0 = *(const bf16x8*)&rb[(l15) * 136 + ks * 32 + l4 * 8];
            bf16x8 b1 = *(const bf16x8*)&rb[(16 + l15) * 136 + ks * 32 + l4 * 8];
            acc[0][0] = __builtin_amdgcn_mfma_f32_16x16x32_bf16(wb[cur][0][ks], b0, acc[0][0], 0, 0, 0);
            acc[1][0] = __builtin_amdgcn_mfma_f32_16x16x32_bf16(wb[cur][1][ks], b0, acc[1][0], 0, 0, 0);
            acc[0][1] = __builtin_amdgcn_mfma_f32_16x16x32_bf16(wb[cur][0][ks], b1, acc[0][1], 0, 0, 0);
            acc[1][1] = __builtin_amdgcn_mfma_f32_16x16x32_bf16(wb[cur][1][ks], b1, acc[1][1], 0, 0, 0);
        }
    }

    if (OUT_CF) {
        // channels-first fp32 + residual
        #pragma unroll
        for (int mb = 0; mb < 2; ++mb) {
            #pragma unroll
            for (int r = 0; r < 4; ++r) {
                int co = coh * 64 + mB + mb * 16 + l4 * 4 + r;
                float bv = bias[co];
                #pragma unroll
                for (int nb = 0; nb < 2; ++nb) {
                    int p = y * 64 + xh + nb * 16 + l15;
                    size_t o = ((size_t)(b * CC + co)) * SP + p;
                    outF[o] = acc[mb][nb][r] + bv + resid[o];
                }
            }
        }
    } else {
        // channels-last bf16 via LDS transpose
        #pragma unroll
        for (int mb = 0; mb < 2; ++mb) {
            #pragma unroll
            for (int r = 0; r < 4; ++r) {
                int col = mB + mb * 16 + l4 * 4 + r;      // block-local co
                int cog = coh * 64 + col;
                float bv = bias[cog] + (FUSE_TEMB ? temb[b * CC + cog] : 0.f);
                #pragma unroll
                for (int nb = 0; nb < 2; ++nb) {
                    int xl = xh + nb * 16 + l15;
                    Otr[xl * 72 + col] = (__bf16)(acc[mb][nb][r] + bv);
                }
            }
        }
        __syncthreads();
        #pragma unroll
        for (int it = 0; it < 2; ++it) {
            int q = it * 256 + tid;           // 512 16B chunks
            int xl = q >> 3, cc = q & 7;
            *(bf16x8*)&outT[((size_t)(b * SP + y * 64 + xl)) * CC + coh * 64 + cc * 8] =
                *(const bf16x8*)&Otr[xl * 72 + cc * 8];
        }
    }
}

// ---------------- 1x1 conv -> cmT [b][p][co] bf16 (x 1/sqrt(128)) + cm2 [b][co][p] bf16 ----------------
__global__ __launch_bounds__(256) void conv1x1_kernel(
    const float* __restrict__ in, const float* __restrict__ wgt,
    const float* __restrict__ bias, __bf16* __restrict__ cmT,
    __bf16* __restrict__ cm2)
{
    const int p0 = blockIdx.x * 256;
    const int p = p0 + threadIdx.x;
    const int cog = blockIdx.y, b = blockIdx.z;
    __shared__ float wl[128 * 8];
    __shared__ __bf16 tr[8][272];
    for (int i = threadIdx.x; i < 1024; i += 256) {
        int j = i & 7, ci = i >> 3;
        wl[i] = wgt[(size_t)(cog * 8 + j) * 128 + ci];
    }
    __syncthreads();
    float acc[8];
    #pragma unroll
    for (int j = 0; j < 8; ++j) acc[j] = bias[cog * 8 + j];
    const float* inb = in + (size_t)b * CC * SP + p;
    for (int ci = 0; ci < 128; ++ci) {
        float v = inb[ci * SP];
        const float4* wk4 = (const float4*)(wl + ci * 8);
        float4 wa = wk4[0], wb = wk4[1];
        acc[0] += v * wa.x; acc[1] += v * wa.y;
        acc[2] += v * wa.z; acc[3] += v * wa.w;
        acc[4] += v * wb.x; acc[5] += v * wb.y;
        acc[6] += v * wb.z; acc[7] += v * wb.w;
    }
    const float scl = 0.088388347648318447f;  // 1/sqrt(128)
    bf16x8 v8s;
    #pragma unroll
    for (int j = 0; j < 8; ++j) {
        v8s[j] = (__bf16)(acc[j] * scl);
        tr[j][threadIdx.x] = (__bf16)acc[j];
    }
    *(bf16x8*)&cmT[((size_t)(b * SP + p)) * CC + cog * 8] = v8s;
    __syncthreads();
    {
        int j = threadIdx.x >> 5, t32 = threadIdx.x & 31;
        *(bf16x8*)&cm2[((size_t)(b * CC + cog * 8 + j)) * SP + p0 + t32 * 8] =
            *(const bf16x8*)&tr[j][t32 * 8];
    }
}

// ---------------- fused cross-attention v3: global-operand MFMAs, Pb-only LDS ----------------
#define PBS 72    // Pb row stride (bf16)

__global__ __launch_bounds__(256) void attn_kernel(
    const __bf16* __restrict__ h1T, const __bf16* __restrict__ cmT,
    const __bf16* __restrict__ cm2, __bf16* __restrict__ part0,
    __bf16* __restrict__ part1)
{
    const int w = blockIdx.x;
    const int b = blockIdx.y;
    const int s = blockIdx.z;          // even/odd uv tiles
    const int tid = threadIdx.x;
    const int wl = tid >> 6;           // wave 0..3
    const int l = tid & 63, l15 = l & 15, l4 = l >> 4;
    const int hB = (wl & 1) * 32;      // mm2: wave h base
    const int cB = (wl >> 1) * 64;     // mm2: wave c base

    __shared__ __align__(16) __bf16 Pb[2 * 64 * PBS];   // ping-pong [h][t]
    __bf16* Otr = Pb;                                    // epilogue alias [h][c] stride 136

    const __bf16* h1Tb = h1T + (size_t)b * SP * CC;
    const __bf16* cmTb = cmT + (size_t)b * SP * CC;
    const __bf16* cm2b = cm2 + (size_t)b * CC * SP;

    // hoist mm1 B-frags from global: B[n=h][k=c]
    bf16x8 hfr[4][4];
    #pragma unroll
    for (int nt = 0; nt < 4; ++nt)
        #pragma unroll
        for (int ks = 0; ks < 4; ++ks)
            hfr[nt][ks] = *(const bf16x8*)&h1Tb[((size_t)((nt * 16 + l15) * WW + w)) * CC + ks * 32 + l4 * 8];

    f32x4 acc2[2][4];   // [mb over h][nt over c]
    #pragma unroll
    for (int mb = 0; mb < 2; ++mb)
        #pragma unroll
        for (int nt = 0; nt < 4; ++nt) acc2[mb][nt] = (f32x4){0.f, 0.f, 0.f, 0.f};

    bf16x8 bfr[2][4][2];  // [buf][nt over c][ks2 over t]

    // prologue: load tile 0 operands, produce Pb[0]
    {
        const int uv0 = s * TT;
        #pragma unroll
        for (int nt = 0; nt < 4; ++nt)
            #pragma unroll
            for (int ks = 0; ks < 2; ++ks)
                bfr[0][nt][ks] = *(const bf16x8*)&cm2b[(size_t)(cB + nt * 16 + l15) * SP + uv0 + ks * 32 + l4 * 8];
        const __bf16* arow = cmTb + (size_t)(uv0 + 16 * wl + l15) * CC;
        bf16x8 afr[4];
        #pragma unroll
        for (int ks = 0; ks < 4; ++ks) afr[ks] = *(const bf16x8*)&arow[ks * 32 + l4 * 8];
        f32x4 s1[4];
        #pragma unroll
        for (int nt = 0; nt < 4; ++nt) {
            s1[nt] = (f32x4){0.f, 0.f, 0.f, 0.f};
            #pragma unroll
            for (int ks = 0; ks < 4; ++ks)
                s1[nt] = __builtin_amdgcn_mfma_f32_16x16x32_bf16(afr[ks], hfr[nt][ks], s1[nt], 0, 0, 0);
        }
        #pragma unroll
        for (int r = 0; r < 4; ++r) {
            float e0 = __expf(s1[0][r]), e1 = __expf(s1[1][r]);
            float e2 = __expf(s1[2][r]), e3 = __expf(s1[3][r]);
            float sm = e0 + e1 + e2 + e3;
            sm += __shfl_xor(sm, 1, 64);
            sm += __shfl_xor(sm, 2, 64);
            sm += __shfl_xor(sm, 4, 64);
            sm += __shfl_xor(sm, 8, 64);
            float ri = 1.f / sm;
            s1[0][r] = e0 * ri; s1[1][r] = e1 * ri;
            s1[2][r] = e2 * ri; s1[3][r] = e3 * ri;
        }
        #pragma unroll
        for (int nt = 0; nt < 4; ++nt) {
            bf16x4 pk;
            pk[0] = (__bf16)s1[nt][0]; pk[1] = (__bf16)s1[nt][1];
            pk[2] = (__bf16)s1[nt][2]; pk[3] = (__bf16)s1[nt][3];
            *(bf16x4*)&Pb[(nt * 16 + l15) * PBS + 16 * wl + l4 * 4] = pk;
        }
    }

    #pragma unroll 2
    for (int i = 0; i < 32; ++i) {
        const int cur = i & 1;
        __syncthreads();
        // prefetch tile i+1 operands (global) before consuming tile i
        bf16x8 afr[4];
        if (i < 31) {
            const int uv0n = ((i + 1) * 2 + s) * TT;
            #pragma unroll
            for (int nt = 0; nt < 4; ++nt)
                #pragma unroll
                for (int ks = 0; ks < 2; ++ks)
                    bfr[cur ^ 1][nt][ks] = *(const bf16x8*)&cm2b[(size_t)(cB + nt * 16 + l15) * SP + uv0n + ks * 32 + l4 * 8];
            const __bf16* arow = cmTb + (size_t)(uv0n + 16 * wl + l15) * CC;
            #pragma unroll
            for (int ks = 0; ks < 4; ++ks) afr[ks] = *(const bf16x8*)&arow[ks * 32 + l4 * 8];
        }
        // consume tile i: O[h][c] += P[h][t] * cm2[c][t]
        {
            const __bf16* PbR = Pb + cur * (64 * PBS);
            bf16x8 pfr[2][2];
            #pragma unroll
            for (int mb = 0; mb < 2; ++mb)
                #pragma unroll
                for (int ks = 0; ks < 2; ++ks)
                    pfr[mb][ks] = *(const bf16x8*)&PbR[(hB + mb * 16 + l15) * PBS + ks * 32 + l4 * 8];
            #pragma unroll
            for (int mb = 0; mb < 2; ++mb)
                #pragma unroll
                for (int nt = 0; nt < 4; ++nt)
                    #pragma unroll
                    for (int ks = 0; ks < 2; ++ks)
                        acc2[mb][nt] = __builtin_amdgcn_mfma_f32_16x16x32_bf16(
                            pfr[mb][ks], bfr[cur][nt][ks], acc2[mb][nt], 0, 0, 0);
        }
        // produce tile i+1
        if (i < 31) {
            f32x4 s1[4];
            #pragma unroll
            for (int nt = 0; nt < 4; ++nt) {
                s1[nt] = (f32x4){0.f, 0.f, 0.f, 0.f};
                #pragma unroll
                for (int ks = 0; ks < 4; ++ks)
                    s1[nt] = __builtin_amdgcn_mfma_f32_16x16x32_bf16(afr[ks], hfr[nt][ks], s1[nt], 0, 0, 0);
            }
            #pragma unroll
            for (int r = 0; r < 4; ++r) {
                float e0 = __expf(s1[0][r]), e1 = __expf(s1[1][r]);
                float e2 = __expf(s1[2][r]), e3 = __expf(s1[3][r]);
                float sm = e0 + e1 + e2 + e3;
                sm += __shfl_xor(sm, 1, 64);
                sm += __shfl_xor(sm, 2, 64);
                sm += __shfl_xor(sm, 4, 64);
                sm += __shfl_xor(sm, 8, 64);
                float ri = 1.f / sm;
                s1[0][r] = e0 * ri; s1[1][r] = e1 * ri;
                s1[2][r] = e2 * ri; s1[3][r] = e3 * ri;
            }
            __bf16* PbW = Pb + (cur ^ 1) * (64 * PBS);
            #pragma unroll
            for (int nt = 0; nt < 4; ++nt) {
                bf16x4 pk;
                pk[0] = (__bf16)s1[nt][0]; pk[1] = (__bf16)s1[nt][1];
                pk[2] = (__bf16)s1[nt][2]; pk[3] = (__bf16)s1[nt][3];
                *(bf16x4*)&PbW[(nt * 16 + l15) * PBS + 16 * wl + l4 * 4] = pk;
            }
        }
    }

    // epilogue: transpose via LDS (alias over Pb), write bf16 partial
    __syncthreads();
    #pragma unroll
    for (int mb = 0; mb < 2; ++mb)
        #pragma unroll
        for (int nt = 0; nt < 4; ++nt)
            #pragma unroll
            for (int r = 0; r < 4; ++r)
                Otr[(hB + mb * 16 + l4 * 4 + r) * 136 + cB + nt * 16 + l15] =
                    (__bf16)acc2[mb][nt][r];
    __syncthreads();
    __bf16* pO = (s == 0) ? part0 : part1;
    #pragma unroll
    for (int it = 0; it < 4; ++it) {
        int q = it * 256 + tid;              // 1024 16B chunks
        int h = q >> 4, cc = q & 15;
        *(bf16x8*)&pO[((size_t)(b * SP + h * WW + w)) * CC + cc * 8] =
            *(const bf16x8*)&Otr[h * 136 + cc * 8];
    }
}

// ---------------- GN2 stats partials: h2 = h1T + p0 + p1 + emb ----------------
__global__ __launch_bounds__(256) void gn2_stats_kernel(
    const __bf16* __restrict__ h1T, const __bf16* __restrict__ p0,
    const __bf16* __restrict__ p1, const int* __restrict__ aim,
    const float* __restrict__ emb, float* __restrict__ pstat)
{
    const int pb = blockIdx.x, b = blockIdx.y;   // pb over 64 blocks of 64 rows
    const int tid = threadIdx.x;
    const int c4 = tid & 31;
    const float4 ev = *(const float4*)&emb[aim[b] * CC + c4 * 4];
    float s = 0.f, s2 = 0.f;
    for (int it = 0; it < 8; ++it) {
        int prow = it * 8 + (tid >> 5);
        size_t base = ((size_t)(b * SP + pb * 64 + prow)) * CC + c4 * 4;
        bf16x4 a = *(const bf16x4*)&p0[base];
        bf16x4 bb = *(const bf16x4*)&p1[base];
        bf16x4 hv = *(const bf16x4*)&h1T[base];
        float v0 = (float)a[0] + (float)bb[0] + (float)hv[0] + ev.x;
        float v1 = (float)a[1] + (float)bb[1] + (float)hv[1] + ev.y;
        float v2 = (float)a[2] + (float)bb[2] + (float)hv[2] + ev.z;
        float v3 = (float)a[3] + (float)bb[3] + (float)hv[3] + ev.w;
        s += v0 + v1 + v2 + v3;
        s2 += v0 * v0 + v1 * v1 + v2 * v2 + v3 * v3;
    }
    s  += __shfl_down(s,  32, 64);
    s2 += __shfl_down(s2, 32, 64);
    __shared__ float ls[4][32][2];
    const int wv = tid >> 6, ll = tid & 63;
    if (ll < 32) { ls[wv][ll][0] = s; ls[wv][ll][1] = s2; }
    __syncthreads();
    if (tid < 32) {
        float S = ls[0][tid][0] + ls[1][tid][0] + ls[2][tid][0] + ls[3][tid][0];
        float S2 = ls[0][tid][1] + ls[1][tid][1] + ls[2][tid][1] + ls[3][tid][1];
        int g = tid;
        pstat[(((size_t)b * NG + g) * 64 + pb) * 2]     = S;
        pstat[(((size_t)b * NG + g) * 64 + pb) * 2 + 1] = S2;
    }
}

__global__ __launch_bounds__(128) void gn2_finalize_kernel(
    const float* __restrict__ pstat, float* __restrict__ st2)
{
    const int i = threadIdx.x;   // b*NG+g
    float S = 0.f, S2 = 0.f;
    for (int k = 0; k < 64; ++k) {
        S  += pstat[((size_t)i * 64 + k) * 2];
        S2 += pstat[((size_t)i * 64 + k) * 2 + 1];
    }
    float m = S * (1.f / 16384.f);
    float var = S2 * (1.f / 16384.f) - m * m;
    st2[i * 2] = m;
    st2[i * 2 + 1] = rsqrtf(var + 1e-5f);
}

// ---------------- GN2 apply + SiLU -> aT bf16 channels-last ----------------
__global__ __launch_bounds__(256) void gn2_apply_kernel(
    const __bf16* __restrict__ h1T, const __bf16* __restrict__ p0,
    const __bf16* __restrict__ p1, const int* __restrict__ aim,
    const float* __restrict__ emb, const float* __restrict__ st2,
    const float* __restrict__ scale, const float* __restrict__ bias,
    __bf16* __restrict__ outT)
{
    const int pb = blockIdx.x, b = blockIdx.y;
    const int tid = threadIdx.x;
    const int c4 = tid & 31;
    const int g = c4;
    const float4 ev = *(const float4*)&emb[aim[b] * CC + c4 * 4];
    const float4 sc = *(const float4*)&scale[c4 * 4];
    const float4 bi = *(const float4*)&bias[c4 * 4];
    const float m = st2[(b * NG + g) * 2], inv = st2[(b * NG + g) * 2 + 1];
    for (int it = 0; it < 8; ++it) {
        int prow = it * 8 + (tid >> 5);
        size_t base = ((size_t)(b * SP + pb * 64 + prow)) * CC + c4 * 4;
        bf16x4 a = *(const bf16x4*)&p0[base];
        bf16x4 bb = *(const bf16x4*)&p1[base];
        bf16x4 hv = *(const bf16x4*)&h1T[base];
        bf16x4 o;
        o[0] = (__bf16)silu_f(((float)a[0] + (float)bb[0] + (float)hv[0] + ev.x - m) * inv * sc.x + bi.x);
        o[1] = (__bf16)silu_f(((float)a[1] + (float)bb[1] + (float)hv[1] + ev.y - m) * inv * sc.y + bi.y);
        o[2] = (__bf16)silu_f(((float)a[2] + (float)bb[2] + (float)hv[2] + ev.z - m) * inv * sc.z + bi.z);
        o[3] = (__bf16)silu_f(((float)a[3] + (float)bb[3] + (float)hv[3] + ev.w - m) * inv * sc.w + bi.w);
        *(bf16x4*)&outT[base] = o;
    }
}

extern "C" void kernel_launch(void* const* d_in, const int* in_sizes, int n_in,
                              void* d_out, int out_size, void* d_ws, size_t ws_size,
                              hipStream_t stream)
{
    const float* x     = (const float*)d_in[0];
    const float* t     = (const float*)d_in[1];
    const int*   aim   = (const int*)  d_in[2];
    const float* cond  = (const float*)d_in[3];
    const float* gn1s  = (const float*)d_in[4];
    const float* gn1b  = (const float*)d_in[5];
    const float* c1w   = (const float*)d_in[6];
    const float* c1b   = (const float*)d_in[7];
    const float* mlpw  = (const float*)d_in[8];
    const float* mlpb  = (const float*)d_in[9];
    const float* cw    = (const float*)d_in[10];
    const float* cb    = (const float*)d_in[11];
    const float* gn2s  = (const float*)d_in[12];
    const float* gn2b  = (const float*)d_in[13];
    const float* c2w   = (const float*)d_in[14];
    const float* c2b   = (const float*)d_in[15];
    const float* emb   = (const float*)d_in[16];
    float* out = (float*)d_out;
    float* ws = (float*)d_ws;

    // float-offset workspace map (each bf16 tensor of 2,097,152 elems = 1,048,576 floats)
    __bf16* aT    = (__bf16*)ws;                  // [0, 1048576)
    __bf16* h1T   = (__bf16*)(ws + 1048576);      // [1048576, 2097152)
    __bf16* cmT   = (__bf16*)(ws + 2097152);      // [2097152, 3145728)
    __bf16* cm2   = (__bf16*)(ws + 3145728);      // [3145728, 4194304)
    __bf16* p0    = (__bf16*)(ws + 4194304);      // [4194304, 5242880)  bf16 partial
    __bf16* p1    = (__bf16*)(ws + 5242880);      // [5242880, 6291456)  bf16 partial
    __bf16* wt    = (__bf16*)(ws + 6291456);      // 294,912 bf16 = 147,456 fl
    float*  tembw = ws + 6438912;                 // 512
    float*  st1   = ws + 6439424;                 // 256
    float*  st2   = ws + 6439680;                 // 256
    float*  pstat = ws + 6439936;                 // 16384

    gn_stats_kernel<<<dim3(BB * NG), dim3(256), 0, stream>>>(x, st1);
    gn_apply_cl_kernel<<<dim3(32, BB), dim3(256), 0, stream>>>(x, st1, gn1s, gn1b, aT);
    wt_kernel<<<dim3(18), dim3(256), 0, stream>>>(c1w, c2w, wt);
    temb_kernel<<<dim3(8), dim3(256), 0, stream>>>(t, mlpw, mlpb, tembw);
    conv1x1_kernel<<<dim3(16, 16, BB), dim3(256), 0, stream>>>(cond, cw, cb, cmT, cm2);
    conv_mfma_kernel<true, false><<<dim3(128, BB), dim3(256), 0, stream>>>(
        aT, wt, c1b, tembw, nullptr, h1T, nullptr);
    attn_kernel<<<dim3(WW, BB, 2), dim3(256), 0, stream>>>(h1T, cmT, cm2, p0, p1);
    gn2_stats_kernel<<<dim3(64, BB), dim3(256), 0, stream>>>(h1T, p0, p1, aim, emb, pstat);
    gn2_finalize_kernel<<<dim3(1), dim3(128), 0, stream>>>(pstat, st2);
    gn2_apply_kernel<<<dim3(64, BB), dim3(256), 0, stream>>>(
        h1T, p0, p1, aim, emb, st2, gn2s, gn2b, aT);
    conv_mfma_kernel<false, true><<<dim3(128, BB), dim3(256), 0, stream>>>(
        aT, wt + (size_t)9 * 16384, c2b, nullptr, x, nullptr, out);
}

// Round 9
// 294.179 us; speedup vs baseline: 5.8498x; 1.0340x over previous
//
#include <hip/hip_runtime.h>
#include <cmath>

#define BB 4
#define CC 128
#define HH 64
#define WW 64
#define SP 4096   // H*W
#define NG 32     // groups
#define TT 64     // attention uv-tile width
#define NS 4      // attention uv split factor
#define PSZ ((size_t)BB * SP * CC)   // partial tensor elements

typedef __bf16 bf16x8 __attribute__((ext_vector_type(8)));
typedef __bf16 bf16x4 __attribute__((ext_vector_type(4)));
typedef float  f32x4  __attribute__((ext_vector_type(4)));

__device__ __forceinline__ float silu_f(float v) {
    return v / (1.f + __expf(-v));
}

// ---------------- GN1 fused stats+apply+SiLU -> channels-last bf16 ----------------
// block per (b,g): 4 ch x 4096 contiguous fp32, staged in LDS
__global__ __launch_bounds__(256) void gn1_fused_kernel(
    const float* __restrict__ in, const float* __restrict__ scale,
    const float* __restrict__ bias, __bf16* __restrict__ outT)
{
    const int bg = blockIdx.x;
    const int b = bg >> 5, g = bg & 31;
    const int tid = threadIdx.x;
    __shared__ float X[16384];
    __shared__ float rs[4], rs2[4];
    __shared__ float mean_s, inv_s;

    const float* p = in + (size_t)bg * 16384;
    float s = 0.f, s2 = 0.f;
    for (int it = 0; it < 16; ++it) {
        int q = it * 256 + tid;
        float4 v = *(const float4*)&p[q * 4];
        *(float4*)&X[q * 4] = v;
        s += v.x + v.y + v.z + v.w;
        s2 += v.x * v.x + v.y * v.y + v.z * v.z + v.w * v.w;
    }
    #pragma unroll
    for (int off = 32; off >= 1; off >>= 1) {
        s  += __shfl_down(s,  off, 64);
        s2 += __shfl_down(s2, off, 64);
    }
    const int wid = tid >> 6;
    if ((tid & 63) == 0) { rs[wid] = s; rs2[wid] = s2; }
    __syncthreads();
    if (tid == 0) {
        float S = rs[0] + rs[1] + rs[2] + rs[3];
        float S2 = rs2[0] + rs2[1] + rs2[2] + rs2[3];
        float m = S * (1.f / 16384.f);
        float var = S2 * (1.f / 16384.f) - m * m;
        mean_s = m;
        inv_s = rsqrtf(var + 1e-5f);
    }
    __syncthreads();
    const float m = mean_s, inv = inv_s;
    float sc[4], bi[4];
    #pragma unroll
    for (int j = 0; j < 4; ++j) { sc[j] = scale[g * 4 + j]; bi[j] = bias[g * 4 + j]; }
    for (int it = 0; it < 16; ++it) {
        int pp = it * 256 + tid;
        bf16x4 o;
        #pragma unroll
        for (int j = 0; j < 4; ++j)
            o[j] = (__bf16)silu_f((X[j * 4096 + pp] - m) * inv * sc[j] + bi[j]);
        *(bf16x4*)&outT[((size_t)(b * SP + pp)) * CC + g * 4] = o;
    }
}

// ---------------- weight transpose: W[co][ci][3][3] fp32 -> Wt[tap][co][ci] bf16 ----------------
__global__ __launch_bounds__(256) void wt_kernel(
    const float* __restrict__ w1, const float* __restrict__ w2,
    __bf16* __restrict__ wt)   // [2][9][128][128]
{
    const int blk = blockIdx.x;        // 0..17
    const int wsel = blk / 9, tap = blk % 9;
    const float* src = wsel ? w2 : w1;
    __bf16* dst = wt + (size_t)wsel * 9 * 16384 + (size_t)tap * 16384;
    for (int it = 0; it < 64; ++it) {
        int q = it * 256 + threadIdx.x;   // q = co*128+ci
        dst[q] = (__bf16)src[(size_t)q * 9 + tap];
    }
}

// ---------------- time-embedding MLP ----------------
__global__ __launch_bounds__(256) void temb_kernel(
    const float* __restrict__ t, const float* __restrict__ w,
    const float* __restrict__ bias, float* __restrict__ temb)
{
    const int cog = blockIdx.x;
    const int tid = threadIdx.x;
    __shared__ float st[4][512];
    __shared__ float wr[16][512];
    for (int it = 0; it < 8; ++it) {
        int q = it * 256 + tid;            // 2048
        st[q >> 9][q & 511] = silu_f(t[q]);
    }
    for (int it = 0; it < 8; ++it) {
        int q = it * 256 + tid;            // 2048 float4
        int row = q >> 7, col4 = q & 127;
        *(float4*)&wr[row][col4 * 4] =
            *(const float4*)&w[(size_t)(cog * 16 + row) * 512 + col4 * 4];
    }
    __syncthreads();
    const int col = tid >> 4, seg = tid & 15;
    float acc[4] = {0.f, 0.f, 0.f, 0.f};
    for (int k = seg * 32; k < seg * 32 + 32; ++k) {
        float wv = wr[col][k];
        acc[0] += st[0][k] * wv;
        acc[1] += st[1][k] * wv;
        acc[2] += st[2][k] * wv;
        acc[3] += st[3][k] * wv;
    }
    #pragma unroll
    for (int o = 1; o < 16; o <<= 1) {
        #pragma unroll
        for (int b4 = 0; b4 < 4; ++b4)
            acc[b4] += __shfl_xor(acc[b4], o, 64);
    }
    if (seg == 0) {
        float bv = bias[cog * 16 + col];
        #pragma unroll
        for (int b4 = 0; b4 < 4; ++b4)
            temb[b4 * 128 + cog * 16 + col] = acc[b4] + bv;
    }
}

// ---------------- 3x3 conv v3: LDS input tile + reg-double-buffered weights ----------------
template<bool FUSE_TEMB, bool OUT_CF>
__global__ __launch_bounds__(256) void conv_mfma_kernel(
    const __bf16* __restrict__ inT, const __bf16* __restrict__ wt,
    const float* __restrict__ bias, const float* __restrict__ temb,
    const float* __restrict__ resid, __bf16* __restrict__ outT,
    float* __restrict__ outF)
{
    const int y   = blockIdx.x >> 1;
    const int coh = blockIdx.x & 1;
    const int b   = blockIdx.y;
    const int tid = threadIdx.x;
    const int l = tid & 63, wv = tid >> 6;
    const int l15 = l & 15, l4 = l >> 4;
    const int mB = (wv & 1) * 32;         // wave co base (block-local)
    const int xh = (wv >> 1) * 32;        // wave x base

    __shared__ __bf16 inS[3 * 66 * 136];  // [row 3][xs 66][c], xs = x+1 (halo)
    __shared__ __bf16 Otr[64 * 72];       // epilogue transpose (CL path)

    // stage 3 input rows with zero halo
    const __bf16* inTb = inT + (size_t)b * SP * CC;
    for (int q = tid; q < 3 * 66 * 16; q += 256) {
        int cc = q & 15;
        int xs = (q >> 4) % 66;
        int r  = (q >> 4) / 66;
        int yy = y + r - 1;
        int xg = xs - 1;
        bf16x8 v;
        if (((unsigned)yy < 64u) && ((unsigned)xg < 64u)) {
            v = *(const bf16x8*)&inTb[((size_t)(yy * 64 + xg)) * CC + cc * 8];
        } else {
            #pragma unroll
            for (int j = 0; j < 8; ++j) v[j] = (__bf16)0.f;
        }
        *(bf16x8*)&inS[(r * 66 + xs) * 136 + cc * 8] = v;
    }
    __syncthreads();

    f32x4 acc[2][2];
    #pragma unroll
    for (int mb = 0; mb < 2; ++mb)
        #pragma unroll
        for (int nb = 0; nb < 2; ++nb) acc[mb][nb] = (f32x4){0.f, 0.f, 0.f, 0.f};

    const __bf16* wp0 = wt + (size_t)(coh * 64 + mB + l15) * 128 + l4 * 8;
    const __bf16* wp1 = wt + (size_t)(coh * 64 + mB + 16 + l15) * 128 + l4 * 8;

    bf16x8 wb[2][2][4];   // [buf][mb][ks]
    #pragma unroll
    for (int ks = 0; ks < 4; ++ks) {
        wb[0][0][ks] = *(const bf16x8*)(wp0 + ks * 32);
        wb[0][1][ks] = *(const bf16x8*)(wp1 + ks * 32);
    }

    #pragma unroll
    for (int tap = 0; tap < 9; ++tap) {
        const int cur = tap & 1, nxt = cur ^ 1;
        if (tap < 8) {
            #pragma unroll
            for (int ks = 0; ks < 4; ++ks) {
                wb[nxt][0][ks] = *(const bf16x8*)(wp0 + (tap + 1) * 16384 + ks * 32);
                wb[nxt][1][ks] = *(const bf16x8*)(wp1 + (tap + 1) * 16384 + ks * 32);
            }
        }
        const __bf16* rb = &inS[((tap / 3) * 66 + xh + (tap % 3)) * 136];
        #pragma unroll
        for (int ks = 0; ks < 4; ++ks) {
            bf16x8 b0 = *(const bf16x8*)&rb[(l15) * 136 + ks * 32 + l4 * 8];
            bf16x8 b1 = *(const bf16x8*)&rb[(16 + l15) * 136 + ks * 32 + l4 * 8];
            acc[0][0] = __builtin_amdgcn_mfma_f32_16x16x32_bf16(wb[cur][0][ks], b0, acc[0][0], 0, 0, 0);
            acc[1][0] = __builtin_amdgcn_mfma_f32_16x16x32_bf16(wb[cur][1][ks], b0, acc[1][0], 0, 0, 0);
            acc[0][1] = __builtin_amdgcn_mfma_f32_16x16x32_bf16(wb[cur][0][ks], b1, acc[0][1], 0, 0, 0);
            acc[1][1] = __builtin_amdgcn_mfma_f32_16x16x32_bf16(wb[cur][1][ks], b1, acc[1][1], 0, 0, 0);
        }
    }

    if (OUT_CF) {
        #pragma unroll
        for (int mb = 0; mb < 2; ++mb) {
            #pragma unroll
            for (int r = 0; r < 4; ++r) {
                int co = coh * 64 + mB + mb * 16 + l4 * 4 + r;
                float bv = bias[co];
                #pragma unroll
                for (int nb = 0; nb < 2; ++nb) {
                    int p = y * 64 + xh + nb * 16 + l15;
                    size_t o = ((size_t)(b * CC + co)) * SP + p;
                    outF[o] = acc[mb][nb][r] + bv + resid[o];
                }
            }
        }
    } else {
        #pragma unroll
        for (int mb = 0; mb < 2; ++mb) {
            #pragma unroll
            for (int r = 0; r < 4; ++r) {
                int col = mB + mb * 16 + l4 * 4 + r;      // block-local co
                int cog = coh * 64 + col;
                float bv = bias[cog] + (FUSE_TEMB ? temb[b * CC + cog] : 0.f);
                #pragma unroll
                for (int nb = 0; nb < 2; ++nb) {
                    int xl = xh + nb * 16 + l15;
                    Otr[xl * 72 + col] = (__bf16)(acc[mb][nb][r] + bv);
                }
            }
        }
        __syncthreads();
        #pragma unroll
        for (int it = 0; it < 2; ++it) {
            int q = it * 256 + tid;           // 512 16B chunks
            int xl = q >> 3, cc = q & 7;
            *(bf16x8*)&outT[((size_t)(b * SP + y * 64 + xl)) * CC + coh * 64 + cc * 8] =
                *(const bf16x8*)&Otr[xl * 72 + cc * 8];
        }
    }
}

// ---------------- 1x1 conv -> cmT [b][p][co] bf16 (x 1/sqrt(128)) + cm2 [b][co][p] bf16 ----------------
__global__ __launch_bounds__(256) void conv1x1_kernel(
    const float* __restrict__ in, const float* __restrict__ wgt,
    const float* __restrict__ bias, __bf16* __restrict__ cmT,
    __bf16* __restrict__ cm2)
{
    const int p0 = blockIdx.x * 256;
    const int p = p0 + threadIdx.x;
    const int cog = blockIdx.y, b = blockIdx.z;
    __shared__ float wl[128 * 8];
    __shared__ __bf16 tr[8][272];
    for (int i = threadIdx.x; i < 1024; i += 256) {
        int j = i & 7, ci = i >> 3;
        wl[i] = wgt[(size_t)(cog * 8 + j) * 128 + ci];
    }
    __syncthreads();
    float acc[8];
    #pragma unroll
    for (int j = 0; j < 8; ++j) acc[j] = bias[cog * 8 + j];
    const float* inb = in + (size_t)b * CC * SP + p;
    for (int ci = 0; ci < 128; ++ci) {
        float v = inb[ci * SP];
        const float4* wk4 = (const float4*)(wl + ci * 8);
        float4 wa = wk4[0], wb = wk4[1];
        acc[0] += v * wa.x; acc[1] += v * wa.y;
        acc[2] += v * wa.z; acc[3] += v * wa.w;
        acc[4] += v * wb.x; acc[5] += v * wb.y;
        acc[6] += v * wb.z; acc[7] += v * wb.w;
    }
    const float scl = 0.088388347648318447f;  // 1/sqrt(128)
    bf16x8 v8s;
    #pragma unroll
    for (int j = 0; j < 8; ++j) {
        v8s[j] = (__bf16)(acc[j] * scl);
        tr[j][threadIdx.x] = (__bf16)acc[j];
    }
    *(bf16x8*)&cmT[((size_t)(b * SP + p)) * CC + cog * 8] = v8s;
    __syncthreads();
    {
        int j = threadIdx.x >> 5, t32 = threadIdx.x & 31;
        *(bf16x8*)&cm2[((size_t)(b * CC + cog * 8 + j)) * SP + p0 + t32 * 8] =
            *(const bf16x8*)&tr[j][t32 * 8];
    }
}

// ---------------- fused cross-attention v4: 4-way uv split for TLP ----------------
#define PBS 72    // Pb row stride (bf16)

__global__ __launch_bounds__(256) void attn_kernel(
    const __bf16* __restrict__ h1T, const __bf16* __restrict__ cmT,
    const __bf16* __restrict__ cm2, __bf16* __restrict__ parts)
{
    const int w = blockIdx.x;
    const int b = blockIdx.y;
    const int s = blockIdx.z;          // uv quarter
    const int tid = threadIdx.x;
    const int wl = tid >> 6;           // wave 0..3
    const int l = tid & 63, l15 = l & 15, l4 = l >> 4;
    const int hB = (wl & 1) * 32;      // mm2: wave h base
    const int cB = (wl >> 1) * 64;     // mm2: wave c base

    __shared__ __align__(16) __bf16 Pb[2 * 64 * PBS];   // ping-pong [h][t]
    __bf16* Otr = Pb;                                    // epilogue alias [h][c] stride 136

    const __bf16* h1Tb = h1T + (size_t)b * SP * CC;
    const __bf16* cmTb = cmT + (size_t)b * SP * CC;
    const __bf16* cm2b = cm2 + (size_t)b * CC * SP;

    // hoist mm1 B-frags from global: B[n=h][k=c]
    bf16x8 hfr[4][4];
    #pragma unroll
    for (int nt = 0; nt < 4; ++nt)
        #pragma unroll
        for (int ks = 0; ks < 4; ++ks)
            hfr[nt][ks] = *(const bf16x8*)&h1Tb[((size_t)((nt * 16 + l15) * WW + w)) * CC + ks * 32 + l4 * 8];

    f32x4 acc2[2][4];   // [mb over h][nt over c]
    #pragma unroll
    for (int mb = 0; mb < 2; ++mb)
        #pragma unroll
        for (int nt = 0; nt < 4; ++nt) acc2[mb][nt] = (f32x4){0.f, 0.f, 0.f, 0.f};

    bf16x8 bfr[2][4][2];  // [buf][nt over c][ks2 over t]

    // prologue: load tile 0 operands, produce Pb[0]
    {
        const int uv0 = s * TT;
        #pragma unroll
        for (int nt = 0; nt < 4; ++nt)
            #pragma unroll
            for (int ks = 0; ks < 2; ++ks)
                bfr[0][nt][ks] = *(const bf16x8*)&cm2b[(size_t)(cB + nt * 16 + l15) * SP + uv0 + ks * 32 + l4 * 8];
        const __bf16* arow = cmTb + (size_t)(uv0 + 16 * wl + l15) * CC;
        bf16x8 afr[4];
        #pragma unroll
        for (int ks = 0; ks < 4; ++ks) afr[ks] = *(const bf16x8*)&arow[ks * 32 + l4 * 8];
        f32x4 s1[4];
        #pragma unroll
        for (int nt = 0; nt < 4; ++nt) {
            s1[nt] = (f32x4){0.f, 0.f, 0.f, 0.f};
            #pragma unroll
            for (int ks = 0; ks < 4; ++ks)
                s1[nt] = __builtin_amdgcn_mfma_f32_16x16x32_bf16(afr[ks], hfr[nt][ks], s1[nt], 0, 0, 0);
        }
        #pragma unroll
        for (int r = 0; r < 4; ++r) {
            float e0 = __expf(s1[0][r]), e1 = __expf(s1[1][r]);
            float e2 = __expf(s1[2][r]), e3 = __expf(s1[3][r]);
            float sm = e0 + e1 + e2 + e3;
            sm += __shfl_xor(sm, 1, 64);
            sm += __shfl_xor(sm, 2, 64);
            sm += __shfl_xor(sm, 4, 64);
            sm += __shfl_xor(sm, 8, 64);
            float ri = 1.f / sm;
            s1[0][r] = e0 * ri; s1[1][r] = e1 * ri;
            s1[2][r] = e2 * ri; s1[3][r] = e3 * ri;
        }
        #pragma unroll
        for (int nt = 0; nt < 4; ++nt) {
            bf16x4 pk;
            pk[0] = (__bf16)s1[nt][0]; pk[1] = (__bf16)s1[nt][1];
            pk[2] = (__bf16)s1[nt][2]; pk[3] = (__bf16)s1[nt][3];
            *(bf16x4*)&Pb[(nt * 16 + l15) * PBS + 16 * wl + l4 * 4] = pk;
        }
    }

    #pragma unroll 2
    for (int i = 0; i < SP / TT / NS; ++i) {
        const int cur = i & 1;
        __syncthreads();
        // prefetch tile i+1 operands (global) before consuming tile i
        bf16x8 afr[4];
        if (i < SP / TT / NS - 1) {
            const int uv0n = ((i + 1) * NS + s) * TT;
            #pragma unroll
            for (int nt = 0; nt < 4; ++nt)
                #pragma unroll
                for (int ks = 0; ks < 2; ++ks)
                    bfr[cur ^ 1][nt][ks] = *(const bf16x8*)&cm2b[(size_t)(cB + nt * 16 + l15) * SP + uv0n + ks * 32 + l4 * 8];
            const __bf16* arow = cmTb + (size_t)(uv0n + 16 * wl + l15) * CC;
            #pragma unroll
            for (int ks = 0; ks < 4; ++ks) afr[ks] = *(const bf16x8*)&arow[ks * 32 + l4 * 8];
        }
        // consume tile i
        {
            const __bf16* PbR = Pb + cur * (64 * PBS);
            bf16x8 pfr[2][2];
            #pragma unroll
            for (int mb = 0; mb < 2; ++mb)
                #pragma unroll
                for (int ks = 0; ks < 2; ++ks)
                    pfr[mb][ks] = *(const bf16x8*)&PbR[(hB + mb * 16 + l15) * PBS + ks * 32 + l4 * 8];
            #pragma unroll
            for (int mb = 0; mb < 2; ++mb)
                #pragma unroll
                for (int nt = 0; nt < 4; ++nt)
                    #pragma unroll
                    for (int ks = 0; ks < 2; ++ks)
                        acc2[mb][nt] = __builtin_amdgcn_mfma_f32_16x16x32_bf16(
                            pfr[mb][ks], bfr[cur][nt][ks], acc2[mb][nt], 0, 0, 0);
        }
        // produce tile i+1
        if (i < SP / TT / NS - 1) {
            f32x4 s1[4];
            #pragma unroll
            for (int nt = 0; nt < 4; ++nt) {
                s1[nt] = (f32x4){0.f, 0.f, 0.f, 0.f};
                #pragma unroll
                for (int ks = 0; ks < 4; ++ks)
                    s1[nt] = __builtin_amdgcn_mfma_f32_16x16x32_bf16(afr[ks], hfr[nt][ks], s1[nt], 0, 0, 0);
            }
            #pragma unroll
            for (int r = 0; r < 4; ++r) {
                float e0 = __expf(s1[0][r]), e1 = __expf(s1[1][r]);
                float e2 = __expf(s1[2][r]), e3 = __expf(s1[3][r]);
                float sm = e0 + e1 + e2 + e3;
                sm += __shfl_xor(sm, 1, 64);
                sm += __shfl_xor(sm, 2, 64);
                sm += __shfl_xor(sm, 4, 64);
                sm += __shfl_xor(sm, 8, 64);
                float ri = 1.f / sm;
                s1[0][r] = e0 * ri; s1[1][r] = e1 * ri;
                s1[2][r] = e2 * ri; s1[3][r] = e3 * ri;
            }
            __bf16* PbW = Pb + (cur ^ 1) * (64 * PBS);
            #pragma unroll
            for (int nt = 0; nt < 4; ++nt) {
                bf16x4 pk;
                pk[0] = (__bf16)s1[nt][0]; pk[1] = (__bf16)s1[nt][1];
                pk[2] = (__bf16)s1[nt][2]; pk[3] = (__bf16)s1[nt][3];
                *(bf16x4*)&PbW[(nt * 16 + l15) * PBS + 16 * wl + l4 * 4] = pk;
            }
        }
    }

    // epilogue: transpose via LDS (alias over Pb), write bf16 partial
    __syncthreads();
    #pragma unroll
    for (int mb = 0; mb < 2; ++mb)
        #pragma unroll
        for (int nt = 0; nt < 4; ++nt)
            #pragma unroll
            for (int r = 0; r < 4; ++r)
                Otr[(hB + mb * 16 + l4 * 4 + r) * 136 + cB + nt * 16 + l15] =
                    (__bf16)acc2[mb][nt][r];
    __syncthreads();
    __bf16* pO = parts + (size_t)s * PSZ;
    #pragma unroll
    for (int it = 0; it < 4; ++it) {
        int q = it * 256 + tid;              // 1024 16B chunks
        int h = q >> 4, cc = q & 15;
        *(bf16x8*)&pO[((size_t)(b * SP + h * WW + w)) * CC + cc * 8] =
            *(const bf16x8*)&Otr[h * 136 + cc * 8];
    }
}

// ---------------- GN2 stats partials: h2 = h1T + sum(parts) + emb ----------------
__global__ __launch_bounds__(256) void gn2_stats_kernel(
    const __bf16* __restrict__ h1T, const __bf16* __restrict__ parts,
    const int* __restrict__ aim, const float* __restrict__ emb,
    float* __restrict__ pstat)
{
    const int pb = blockIdx.x, b = blockIdx.y;   // pb over 64 blocks of 64 rows
    const int tid = threadIdx.x;
    const int c4 = tid & 31;
    const float4 ev = *(const float4*)&emb[aim[b] * CC + c4 * 4];
    float s = 0.f, s2 = 0.f;
    for (int it = 0; it < 8; ++it) {
        int prow = it * 8 + (tid >> 5);
        size_t base = ((size_t)(b * SP + pb * 64 + prow)) * CC + c4 * 4;
        bf16x4 hv = *(const bf16x4*)&h1T[base];
        float v0 = (float)hv[0] + ev.x;
        float v1 = (float)hv[1] + ev.y;
        float v2 = (float)hv[2] + ev.z;
        float v3 = (float)hv[3] + ev.w;
        #pragma unroll
        for (int k = 0; k < NS; ++k) {
            bf16x4 a = *(const bf16x4*)&parts[(size_t)k * PSZ + base];
            v0 += (float)a[0]; v1 += (float)a[1];
            v2 += (float)a[2]; v3 += (float)a[3];
        }
        s += v0 + v1 + v2 + v3;
        s2 += v0 * v0 + v1 * v1 + v2 * v2 + v3 * v3;
    }
    s  += __shfl_down(s,  32, 64);
    s2 += __shfl_down(s2, 32, 64);
    __shared__ float ls[4][32][2];
    const int wv = tid >> 6, ll = tid & 63;
    if (ll < 32) { ls[wv][ll][0] = s; ls[wv][ll][1] = s2; }
    __syncthreads();
    if (tid < 32) {
        float S = ls[0][tid][0] + ls[1][tid][0] + ls[2][tid][0] + ls[3][tid][0];
        float S2 = ls[0][tid][1] + ls[1][tid][1] + ls[2][tid][1] + ls[3][tid][1];
        int g = tid;
        pstat[(((size_t)b * NG + g) * 64 + pb) * 2]     = S;
        pstat[(((size_t)b * NG + g) * 64 + pb) * 2 + 1] = S2;
    }
}

// ---------------- GN2 apply (inline finalize) + SiLU -> aT bf16 channels-last ----------------
__global__ __launch_bounds__(256) void gn2_apply_kernel(
    const __bf16* __restrict__ h1T, const __bf16* __restrict__ parts,
    const int* __restrict__ aim, const float* __restrict__ emb,
    const float* __restrict__ pstat, const float* __restrict__ scale,
    const float* __restrict__ bias, __bf16* __restrict__ outT)
{
    const int pb = blockIdx.x, b = blockIdx.y;
    const int tid = threadIdx.x;
    const int c4 = tid & 31;
    const int g = c4;
    __shared__ float st[32][2];
    if (tid < 32) {
        float S = 0.f, S2 = 0.f;
        const float* ps = pstat + ((size_t)b * NG + tid) * 128;
        for (int k = 0; k < 64; ++k) { S += ps[k * 2]; S2 += ps[k * 2 + 1]; }
        float mm = S * (1.f / 16384.f);
        float var = S2 * (1.f / 16384.f) - mm * mm;
        st[tid][0] = mm;
        st[tid][1] = rsqrtf(var + 1e-5f);
    }
    __syncthreads();
    const float4 ev = *(const float4*)&emb[aim[b] * CC + c4 * 4];
    const float4 sc = *(const float4*)&scale[c4 * 4];
    const float4 bi = *(const float4*)&bias[c4 * 4];
    const float m = st[g][0], inv = st[g][1];
    for (int it = 0; it < 8; ++it) {
        int prow = it * 8 + (tid >> 5);
        size_t base = ((size_t)(b * SP + pb * 64 + prow)) * CC + c4 * 4;
        bf16x4 hv = *(const bf16x4*)&h1T[base];
        float v0 = (float)hv[0] + ev.x;
        float v1 = (float)hv[1] + ev.y;
        float v2 = (float)hv[2] + ev.z;
        float v3 = (float)hv[3] + ev.w;
        #pragma unroll
        for (int k = 0; k < NS; ++k) {
            bf16x4 a = *(const bf16x4*)&parts[(size_t)k * PSZ + base];
            v0 += (float)a[0]; v1 += (float)a[1];
            v2 += (float)a[2]; v3 += (float)a[3];
        }
        bf16x4 o;
        o[0] = (__bf16)silu_f((v0 - m) * inv * sc.x + bi.x);
        o[1] = (__bf16)silu_f((v1 - m) * inv * sc.y + bi.y);
        o[2] = (__bf16)silu_f((v2 - m) * inv * sc.z + bi.z);
        o[3] = (__bf16)silu_f((v3 - m) * inv * sc.w + bi.w);
        *(bf16x4*)&outT[base] = o;
    }
}

extern "C" void kernel_launch(void* const* d_in, const int* in_sizes, int n_in,
                              void* d_out, int out_size, void* d_ws, size_t ws_size,
                              hipStream_t stream)
{
    const float* x     = (const float*)d_in[0];
    const float* t     = (const float*)d_in[1];
    const int*   aim   = (const int*)  d_in[2];
    const float* cond  = (const float*)d_in[3];
    const float* gn1s  = (const float*)d_in[4];
    const float* gn1b  = (const float*)d_in[5];
    const float* c1w   = (const float*)d_in[6];
    const float* c1b   = (const float*)d_in[7];
    const float* mlpw  = (const float*)d_in[8];
    const float* mlpb  = (const float*)d_in[9];
    const float* cw    = (const float*)d_in[10];
    const float* cb    = (const float*)d_in[11];
    const float* gn2s  = (const float*)d_in[12];
    const float* gn2b  = (const float*)d_in[13];
    const float* c2w   = (const float*)d_in[14];
    const float* c2b   = (const float*)d_in[15];
    const float* emb   = (const float*)d_in[16];
    float* out = (float*)d_out;
    float* ws = (float*)d_ws;

    // float-offset workspace map
    __bf16* aT    = (__bf16*)ws;                  // [0, 1048576)
    __bf16* h1T   = (__bf16*)(ws + 1048576);      // [1048576, 2097152)
    __bf16* cmT   = (__bf16*)(ws + 2097152);      // [2097152, 3145728)
    __bf16* cm2   = (__bf16*)(ws + 3145728);      // [3145728, 4194304)
    __bf16* parts = (__bf16*)(ws + 4194304);      // 4 x 1,048,576 fl = [4194304, 8388608)
    __bf16* wt    = (__bf16*)(ws + 8388608);      // 294,912 bf16 = 147,456 fl
    float*  tembw = ws + 8536064;                 // 512
    float*  pstat = ws + 8536576;                 // 16384

    gn1_fused_kernel<<<dim3(BB * NG), dim3(256), 0, stream>>>(x, gn1s, gn1b, aT);
    wt_kernel<<<dim3(18), dim3(256), 0, stream>>>(c1w, c2w, wt);
    temb_kernel<<<dim3(8), dim3(256), 0, stream>>>(t, mlpw, mlpb, tembw);
    conv1x1_kernel<<<dim3(16, 16, BB), dim3(256), 0, stream>>>(cond, cw, cb, cmT, cm2);
    conv_mfma_kernel<true, false><<<dim3(128, BB), dim3(256), 0, stream>>>(
        aT, wt, c1b, tembw, nullptr, h1T, nullptr);
    attn_kernel<<<dim3(WW, BB, NS), dim3(256), 0, stream>>>(h1T, cmT, cm2, parts);
    gn2_stats_kernel<<<dim3(64, BB), dim3(256), 0, stream>>>(h1T, parts, aim, emb, pstat);
    gn2_apply_kernel<<<dim3(64, BB), dim3(256), 0, stream>>>(
        h1T, parts, aim, emb, pstat, gn2s, gn2b, aT);
    conv_mfma_kernel<false, true><<<dim3(128, BB), dim3(256), 0, stream>>>(
        aT, wt + (size_t)9 * 16384, c2b, nullptr, x, nullptr, out);
}

// Round 10
// 251.829 us; speedup vs baseline: 6.8336x; 1.1682x over previous
//
#include <hip/hip_runtime.h>
#include <cmath>

#define BB 4
#define CC 128
#define HH 64
#define WW 64
#define SP 4096   // H*W
#define NG 32     // groups
#define TT 64     // attention uv-tile width
#define NS 2      // attention uv split factor
#define PSZ ((size_t)BB * SP * CC)   // partial tensor elements

typedef __bf16 bf16x8 __attribute__((ext_vector_type(8)));
typedef __bf16 bf16x4 __attribute__((ext_vector_type(4)));
typedef float  f32x4  __attribute__((ext_vector_type(4)));

__device__ __forceinline__ float silu_f(float v) {
    return v / (1.f + __expf(-v));
}

// ---------------- GN1 fused stats+apply+SiLU -> channels-last bf16 ----------------
__global__ __launch_bounds__(256) void gn1_fused_kernel(
    const float* __restrict__ in, const float* __restrict__ scale,
    const float* __restrict__ bias, __bf16* __restrict__ outT)
{
    const int bg = blockIdx.x;
    const int b = bg >> 5, g = bg & 31;
    const int tid = threadIdx.x;
    __shared__ float X[16384];
    __shared__ float rs[4], rs2[4];
    __shared__ float mean_s, inv_s;

    const float* p = in + (size_t)bg * 16384;
    float s = 0.f, s2 = 0.f;
    for (int it = 0; it < 16; ++it) {
        int q = it * 256 + tid;
        float4 v = *(const float4*)&p[q * 4];
        *(float4*)&X[q * 4] = v;
        s += v.x + v.y + v.z + v.w;
        s2 += v.x * v.x + v.y * v.y + v.z * v.z + v.w * v.w;
    }
    #pragma unroll
    for (int off = 32; off >= 1; off >>= 1) {
        s  += __shfl_down(s,  off, 64);
        s2 += __shfl_down(s2, off, 64);
    }
    const int wid = tid >> 6;
    if ((tid & 63) == 0) { rs[wid] = s; rs2[wid] = s2; }
    __syncthreads();
    if (tid == 0) {
        float S = rs[0] + rs[1] + rs[2] + rs[3];
        float S2 = rs2[0] + rs2[1] + rs2[2] + rs2[3];
        float m = S * (1.f / 16384.f);
        float var = S2 * (1.f / 16384.f) - m * m;
        mean_s = m;
        inv_s = rsqrtf(var + 1e-5f);
    }
    __syncthreads();
    const float m = mean_s, inv = inv_s;
    float sc[4], bi[4];
    #pragma unroll
    for (int j = 0; j < 4; ++j) { sc[j] = scale[g * 4 + j]; bi[j] = bias[g * 4 + j]; }
    for (int it = 0; it < 16; ++it) {
        int pp = it * 256 + tid;
        bf16x4 o;
        #pragma unroll
        for (int j = 0; j < 4; ++j)
            o[j] = (__bf16)silu_f((X[j * 4096 + pp] - m) * inv * sc[j] + bi[j]);
        *(bf16x4*)&outT[((size_t)(b * SP + pp)) * CC + g * 4] = o;
    }
}

// ---------------- weight transpose ----------------
__global__ __launch_bounds__(256) void wt_kernel(
    const float* __restrict__ w1, const float* __restrict__ w2,
    __bf16* __restrict__ wt)   // [2][9][128][128]
{
    const int blk = blockIdx.x;        // 0..17
    const int wsel = blk / 9, tap = blk % 9;
    const float* src = wsel ? w2 : w1;
    __bf16* dst = wt + (size_t)wsel * 9 * 16384 + (size_t)tap * 16384;
    for (int it = 0; it < 64; ++it) {
        int q = it * 256 + threadIdx.x;   // q = co*128+ci
        dst[q] = (__bf16)src[(size_t)q * 9 + tap];
    }
}

// ---------------- time-embedding MLP ----------------
__global__ __launch_bounds__(256) void temb_kernel(
    const float* __restrict__ t, const float* __restrict__ w,
    const float* __restrict__ bias, float* __restrict__ temb)
{
    const int cog = blockIdx.x;
    const int tid = threadIdx.x;
    __shared__ float st[4][512];
    __shared__ float wr[16][512];
    for (int it = 0; it < 8; ++it) {
        int q = it * 256 + tid;
        st[q >> 9][q & 511] = silu_f(t[q]);
    }
    for (int it = 0; it < 8; ++it) {
        int q = it * 256 + tid;
        int row = q >> 7, col4 = q & 127;
        *(float4*)&wr[row][col4 * 4] =
            *(const float4*)&w[(size_t)(cog * 16 + row) * 512 + col4 * 4];
    }
    __syncthreads();
    const int col = tid >> 4, seg = tid & 15;
    float acc[4] = {0.f, 0.f, 0.f, 0.f};
    for (int k = seg * 32; k < seg * 32 + 32; ++k) {
        float wv = wr[col][k];
        acc[0] += st[0][k] * wv;
        acc[1] += st[1][k] * wv;
        acc[2] += st[2][k] * wv;
        acc[3] += st[3][k] * wv;
    }
    #pragma unroll
    for (int o = 1; o < 16; o <<= 1) {
        #pragma unroll
        for (int b4 = 0; b4 < 4; ++b4)
            acc[b4] += __shfl_xor(acc[b4], o, 64);
    }
    if (seg == 0) {
        float bv = bias[cog * 16 + col];
        #pragma unroll
        for (int b4 = 0; b4 < 4; ++b4)
            temb[b4 * 128 + cog * 16 + col] = acc[b4] + bv;
    }
}

// ---------------- 3x3 conv v4: LDS input, direct stores, 3 blocks/CU ----------------
template<bool FUSE_TEMB, bool OUT_CF>
__global__ __launch_bounds__(256, 3) void conv_mfma_kernel(
    const __bf16* __restrict__ inT, const __bf16* __restrict__ wt,
    const float* __restrict__ bias, const float* __restrict__ temb,
    const float* __restrict__ resid, __bf16* __restrict__ outT,
    float* __restrict__ outF)
{
    const int y   = blockIdx.x >> 1;
    const int coh = blockIdx.x & 1;
    const int b   = blockIdx.y;
    const int tid = threadIdx.x;
    const int l = tid & 63, wv = tid >> 6;
    const int l15 = l & 15, l4 = l >> 4;
    const int mB = (wv & 1) * 32;         // wave co base (block-local)
    const int xh = (wv >> 1) * 32;        // wave x base

    __shared__ __bf16 inS[3 * 66 * 136];  // [row 3][xs 66][c], 53.9 KB

    const __bf16* inTb = inT + (size_t)b * SP * CC;
    for (int q = tid; q < 3 * 66 * 16; q += 256) {
        int cc = q & 15;
        int xs = (q >> 4) % 66;
        int r  = (q >> 4) / 66;
        int yy = y + r - 1;
        int xg = xs - 1;
        bf16x8 v;
        if (((unsigned)yy < 64u) && ((unsigned)xg < 64u)) {
            v = *(const bf16x8*)&inTb[((size_t)(yy * 64 + xg)) * CC + cc * 8];
        } else {
            #pragma unroll
            for (int j = 0; j < 8; ++j) v[j] = (__bf16)0.f;
        }
        *(bf16x8*)&inS[(r * 66 + xs) * 136 + cc * 8] = v;
    }
    __syncthreads();

    f32x4 acc[2][2];
    #pragma unroll
    for (int mb = 0; mb < 2; ++mb)
        #pragma unroll
        for (int nb = 0; nb < 2; ++nb) acc[mb][nb] = (f32x4){0.f, 0.f, 0.f, 0.f};

    const __bf16* wp0 = wt + (size_t)(coh * 64 + mB + l15) * 128 + l4 * 8;
    const __bf16* wp1 = wt + (size_t)(coh * 64 + mB + 16 + l15) * 128 + l4 * 8;

    bf16x8 wb[2][2][4];   // [buf][mb][ks]
    #pragma unroll
    for (int ks = 0; ks < 4; ++ks) {
        wb[0][0][ks] = *(const bf16x8*)(wp0 + ks * 32);
        wb[0][1][ks] = *(const bf16x8*)(wp1 + ks * 32);
    }

    #pragma unroll
    for (int tap = 0; tap < 9; ++tap) {
        const int cur = tap & 1, nxt = cur ^ 1;
        if (tap < 8) {
            #pragma unroll
            for (int ks = 0; ks < 4; ++ks) {
                wb[nxt][0][ks] = *(const bf16x8*)(wp0 + (tap + 1) * 16384 + ks * 32);
                wb[nxt][1][ks] = *(const bf16x8*)(wp1 + (tap + 1) * 16384 + ks * 32);
            }
        }
        const __bf16* rb = &inS[((tap / 3) * 66 + xh + (tap % 3)) * 136];
        #pragma unroll
        for (int ks = 0; ks < 4; ++ks) {
            bf16x8 b0 = *(const bf16x8*)&rb[(l15) * 136 + ks * 32 + l4 * 8];
            bf16x8 b1 = *(const bf16x8*)&rb[(16 + l15) * 136 + ks * 32 + l4 * 8];
            acc[0][0] = __builtin_amdgcn_mfma_f32_16x16x32_bf16(wb[cur][0][ks], b0, acc[0][0], 0, 0, 0);
            acc[1][0] = __builtin_amdgcn_mfma_f32_16x16x32_bf16(wb[cur][1][ks], b0, acc[1][0], 0, 0, 0);
            acc[0][1] = __builtin_amdgcn_mfma_f32_16x16x32_bf16(wb[cur][0][ks], b1, acc[0][1], 0, 0, 0);
            acc[1][1] = __builtin_amdgcn_mfma_f32_16x16x32_bf16(wb[cur][1][ks], b1, acc[1][1], 0, 0, 0);
        }
    }

    if (OUT_CF) {
        // channels-first fp32 + residual
        #pragma unroll
        for (int mb = 0; mb < 2; ++mb) {
            #pragma unroll
            for (int r = 0; r < 4; ++r) {
                int co = coh * 64 + mB + mb * 16 + l4 * 4 + r;
                float bv = bias[co];
                #pragma unroll
                for (int nb = 0; nb < 2; ++nb) {
                    int p = y * 64 + xh + nb * 16 + l15;
                    size_t o = ((size_t)(b * CC + co)) * SP + p;
                    outF[o] = acc[mb][nb][r] + bv + resid[o];
                }
            }
        }
    } else {
        // channels-last bf16 direct packed stores (8 B per lane per mb/nb)
        #pragma unroll
        for (int mb = 0; mb < 2; ++mb) {
            int co0 = coh * 64 + mB + mb * 16 + l4 * 4;
            float bv[4];
            #pragma unroll
            for (int r = 0; r < 4; ++r)
                bv[r] = bias[co0 + r] + (FUSE_TEMB ? temb[b * CC + co0 + r] : 0.f);
            #pragma unroll
            for (int nb = 0; nb < 2; ++nb) {
                int p = y * 64 + xh + nb * 16 + l15;
                bf16x4 o;
                #pragma unroll
                for (int r = 0; r < 4; ++r)
                    o[r] = (__bf16)(acc[mb][nb][r] + bv[r]);
                *(bf16x4*)&outT[((size_t)(b * SP + p)) * CC + co0] = o;
            }
        }
    }
}

// ---------------- 1x1 conv -> cmT [b][p][co] bf16 (x 1/sqrt(128)) + cm2 [b][co][p] bf16 ----------------
__global__ __launch_bounds__(256) void conv1x1_kernel(
    const float* __restrict__ in, const float* __restrict__ wgt,
    const float* __restrict__ bias, __bf16* __restrict__ cmT,
    __bf16* __restrict__ cm2)
{
    const int p0 = blockIdx.x * 256;
    const int p = p0 + threadIdx.x;
    const int cog = blockIdx.y, b = blockIdx.z;
    __shared__ float wl[128 * 8];
    __shared__ __bf16 tr[8][272];
    for (int i = threadIdx.x; i < 1024; i += 256) {
        int j = i & 7, ci = i >> 3;
        wl[i] = wgt[(size_t)(cog * 8 + j) * 128 + ci];
    }
    __syncthreads();
    float acc[8];
    #pragma unroll
    for (int j = 0; j < 8; ++j) acc[j] = bias[cog * 8 + j];
    const float* inb = in + (size_t)b * CC * SP + p;
    for (int ci = 0; ci < 128; ++ci) {
        float v = inb[ci * SP];
        const float4* wk4 = (const float4*)(wl + ci * 8);
        float4 wa = wk4[0], wb = wk4[1];
        acc[0] += v * wa.x; acc[1] += v * wa.y;
        acc[2] += v * wa.z; acc[3] += v * wa.w;
        acc[4] += v * wb.x; acc[5] += v * wb.y;
        acc[6] += v * wb.z; acc[7] += v * wb.w;
    }
    const float scl = 0.088388347648318447f;  // 1/sqrt(128)
    bf16x8 v8s;
    #pragma unroll
    for (int j = 0; j < 8; ++j) {
        v8s[j] = (__bf16)(acc[j] * scl);
        tr[j][threadIdx.x] = (__bf16)acc[j];
    }
    *(bf16x8*)&cmT[((size_t)(b * SP + p)) * CC + cog * 8] = v8s;
    __syncthreads();
    {
        int j = threadIdx.x >> 5, t32 = threadIdx.x & 31;
        *(bf16x8*)&cm2[((size_t)(b * CC + cog * 8 + j)) * SP + p0 + t32 * 8] =
            *(const bf16x8*)&tr[j][t32 * 8];
    }
}

// ---------------- fused cross-attention v5: ct2 LDS dbuf + Pb single, 3 blocks/CU ----------------
#define CT2 72    // ct2 row stride (bf16)
#define PBS 72    // Pb row stride (bf16)

// LDS pool: ct2[2] 2x128x72x2 = 36864 B, Pb 64x72x2 = 9216 B -> 46080 B (3 blocks/CU)
#define POOL_BYTES 46080

__global__ __launch_bounds__(256, 3) void attn_kernel(
    const __bf16* __restrict__ h1T, const __bf16* __restrict__ cmT,
    const __bf16* __restrict__ cm2, __bf16* __restrict__ parts)
{
    const int w = blockIdx.x;
    const int b = blockIdx.y;
    const int s = blockIdx.z;          // even/odd uv tiles
    const int tid = threadIdx.x;
    const int wl = tid >> 6;           // wave 0..3
    const int l = tid & 63, l15 = l & 15, l4 = l >> 4;
    const int hB = (wl & 1) * 32;      // mm2: wave h base
    const int cB = (wl >> 1) * 64;     // mm2: wave c base

    __shared__ __align__(16) char pool[POOL_BYTES];
    __bf16* ct2p = (__bf16*)pool;               // two buffers of 9216 elems
    __bf16* Pb   = (__bf16*)(pool + 36864);     // single buffer [h][t]
    __bf16* Otr  = (__bf16*)pool;               // epilogue alias [h][c] stride 136

    const __bf16* h1Tb = h1T + (size_t)b * SP * CC;
    const __bf16* cmTb = cmT + (size_t)b * SP * CC;
    const __bf16* cm2b = cm2 + (size_t)b * CC * SP;

    // hoist mm1 B-frags from global: B[n=h][k=c]
    bf16x8 hfr[4][4];
    #pragma unroll
    for (int nt = 0; nt < 4; ++nt)
        #pragma unroll
        for (int ks = 0; ks < 4; ++ks)
            hfr[nt][ks] = *(const bf16x8*)&h1Tb[((size_t)((nt * 16 + l15) * WW + w)) * CC + ks * 32 + l4 * 8];

    f32x4 acc2[2][4];   // [mb over h][nt over c]
    #pragma unroll
    for (int mb = 0; mb < 2; ++mb)
        #pragma unroll
        for (int nt = 0; nt < 4; ++nt) acc2[mb][nt] = (f32x4){0.f, 0.f, 0.f, 0.f};

    const int sc = tid >> 3;         // staging: my c row (0..31 step over 4 its)
    const int stc = tid & 7;         // staging: my t chunk

    // prologue: stage ct2[0] (tile 0), produce Pb (tile 0)
    {
        const int uv0 = s * TT;
        #pragma unroll
        for (int it = 0; it < 4; ++it) {
            int c = it * 32 + sc;
            *(bf16x8*)&ct2p[c * CT2 + stc * 8] =
                *(const bf16x8*)&cm2b[(size_t)c * SP + uv0 + stc * 8];
        }
        const __bf16* arow = cmTb + (size_t)(uv0 + 16 * wl + l15) * CC;
        bf16x8 afr[4];
        #pragma unroll
        for (int ks = 0; ks < 4; ++ks) afr[ks] = *(const bf16x8*)&arow[ks * 32 + l4 * 8];
        f32x4 s1[4];
        #pragma unroll
        for (int nt = 0; nt < 4; ++nt) {
            s1[nt] = (f32x4){0.f, 0.f, 0.f, 0.f};
            #pragma unroll
            for (int ks = 0; ks < 4; ++ks)
                s1[nt] = __builtin_amdgcn_mfma_f32_16x16x32_bf16(afr[ks], hfr[nt][ks], s1[nt], 0, 0, 0);
        }
        #pragma unroll
        for (int r = 0; r < 4; ++r) {
            float e0 = __expf(s1[0][r]), e1 = __expf(s1[1][r]);
            float e2 = __expf(s1[2][r]), e3 = __expf(s1[3][r]);
            float sm = e0 + e1 + e2 + e3;
            sm += __shfl_xor(sm, 1, 64);
            sm += __shfl_xor(sm, 2, 64);
            sm += __shfl_xor(sm, 4, 64);
            sm += __shfl_xor(sm, 8, 64);
            float ri = 1.f / sm;
            s1[0][r] = e0 * ri; s1[1][r] = e1 * ri;
            s1[2][r] = e2 * ri; s1[3][r] = e3 * ri;
        }
        #pragma unroll
        for (int nt = 0; nt < 4; ++nt) {
            bf16x4 pk;
            pk[0] = (__bf16)s1[nt][0]; pk[1] = (__bf16)s1[nt][1];
            pk[2] = (__bf16)s1[nt][2]; pk[3] = (__bf16)s1[nt][3];
            *(bf16x4*)&Pb[(nt * 16 + l15) * PBS + 16 * wl + l4 * 4] = pk;
        }
    }

    for (int i = 0; i < SP / TT / NS; ++i) {
        const int cur = i & 1;
        __syncthreads();   // A: Pb(tile i) + ct2[cur] complete
        // prefetch next tile's operands into registers
        bf16x8 st4[4];
        bf16x8 afr[4];
        if (i < SP / TT / NS - 1) {
            const int uv0n = ((i + 1) * NS + s) * TT;
            #pragma unroll
            for (int it = 0; it < 4; ++it) {
                int c = it * 32 + sc;
                st4[it] = *(const bf16x8*)&cm2b[(size_t)c * SP + uv0n + stc * 8];
            }
            const __bf16* arow = cmTb + (size_t)(uv0n + 16 * wl + l15) * CC;
            #pragma unroll
            for (int ks = 0; ks < 4; ++ks) afr[ks] = *(const bf16x8*)&arow[ks * 32 + l4 * 8];
        }
        // read my P fragments (then Pb is free to overwrite)
        bf16x8 pfr[2][2];
        #pragma unroll
        for (int mb = 0; mb < 2; ++mb)
            #pragma unroll
            for (int ks = 0; ks < 2; ++ks)
                pfr[mb][ks] = *(const bf16x8*)&Pb[(hB + mb * 16 + l15) * PBS + ks * 32 + l4 * 8];
        __syncthreads();   // B: all pfr reads done
        // mm2: O[h][c] += P[h][t] * ct2[c][t]
        {
            const __bf16* ctR = ct2p + cur * 9216;
            #pragma unroll
            for (int mb = 0; mb < 2; ++mb)
                #pragma unroll
                for (int nt = 0; nt < 4; ++nt)
                    #pragma unroll
                    for (int ks = 0; ks < 2; ++ks) {
                        bf16x8 bfr = *(const bf16x8*)&ctR[(cB + nt * 16 + l15) * CT2 + ks * 32 + l4 * 8];
                        acc2[mb][nt] = __builtin_amdgcn_mfma_f32_16x16x32_bf16(
                            pfr[mb][ks], bfr, acc2[mb][nt], 0, 0, 0);
                    }
        }
        if (i < SP / TT / NS - 1) {
            // commit staged ct2 for tile i+1
            __bf16* ctW = ct2p + (cur ^ 1) * 9216;
            #pragma unroll
            for (int it = 0; it < 4; ++it) {
                int c = it * 32 + sc;
                *(bf16x8*)&ctW[c * CT2 + stc * 8] = st4[it];
            }
            // mm1 + softmax -> Pb (tile i+1)
            f32x4 s1[4];
            #pragma unroll
            for (int nt = 0; nt < 4; ++nt) {
                s1[nt] = (f32x4){0.f, 0.f, 0.f, 0.f};
                #pragma unroll
                for (int ks = 0; ks < 4; ++ks)
                    s1[nt] = __builtin_amdgcn_mfma_f32_16x16x32_bf16(afr[ks], hfr[nt][ks], s1[nt], 0, 0, 0);
            }
            #pragma unroll
            for (int r = 0; r < 4; ++r) {
                float e0 = __expf(s1[0][r]), e1 = __expf(s1[1][r]);
                float e2 = __expf(s1[2][r]), e3 = __expf(s1[3][r]);
                float sm = e0 + e1 + e2 + e3;
                sm += __shfl_xor(sm, 1, 64);
                sm += __shfl_xor(sm, 2, 64);
                sm += __shfl_xor(sm, 4, 64);
                sm += __shfl_xor(sm, 8, 64);
                float ri = 1.f / sm;
                s1[0][r] = e0 * ri; s1[1][r] = e1 * ri;
                s1[2][r] = e2 * ri; s1[3][r] = e3 * ri;
            }
            #pragma unroll
            for (int nt = 0; nt < 4; ++nt) {
                bf16x4 pk;
                pk[0] = (__bf16)s1[nt][0]; pk[1] = (__bf16)s1[nt][1];
                pk[2] = (__bf16)s1[nt][2]; pk[3] = (__bf16)s1[nt][3];
                *(bf16x4*)&Pb[(nt * 16 + l15) * PBS + 16 * wl + l4 * 4] = pk;
            }
        }
    }

    // epilogue: transpose via LDS (alias over ct2 pool), write bf16 partial
    __syncthreads();
    #pragma unroll
    for (int mb = 0; mb < 2; ++mb)
        #pragma unroll
        for (int nt = 0; nt < 4; ++nt)
            #pragma unroll
            for (int r = 0; r < 4; ++r)
                Otr[(hB + mb * 16 + l4 * 4 + r) * 136 + cB + nt * 16 + l15] =
                    (__bf16)acc2[mb][nt][r];
    __syncthreads();
    __bf16* pO = parts + (size_t)s * PSZ;
    #pragma unroll
    for (int it = 0; it < 4; ++it) {
        int q = it * 256 + tid;              // 1024 16B chunks
        int h = q >> 4, cc = q & 15;
        *(bf16x8*)&pO[((size_t)(b * SP + h * WW + w)) * CC + cc * 8] =
            *(const bf16x8*)&Otr[h * 136 + cc * 8];
    }
}

// ---------------- GN2 stats partials: h2 = h1T + sum(parts) + emb ----------------
__global__ __launch_bounds__(256) void gn2_stats_kernel(
    const __bf16* __restrict__ h1T, const __bf16* __restrict__ parts,
    const int* __restrict__ aim, const float* __restrict__ emb,
    float* __restrict__ pstat)
{
    const int pb = blockIdx.x, b = blockIdx.y;
    const int tid = threadIdx.x;
    const int c4 = tid & 31;
    const float4 ev = *(const float4*)&emb[aim[b] * CC + c4 * 4];
    float s = 0.f, s2 = 0.f;
    for (int it = 0; it < 8; ++it) {
        int prow = it * 8 + (tid >> 5);
        size_t base = ((size_t)(b * SP + pb * 64 + prow)) * CC + c4 * 4;
        bf16x4 hv = *(const bf16x4*)&h1T[base];
        float v0 = (float)hv[0] + ev.x;
        float v1 = (float)hv[1] + ev.y;
        float v2 = (float)hv[2] + ev.z;
        float v3 = (float)hv[3] + ev.w;
        #pragma unroll
        for (int k = 0; k < NS; ++k) {
            bf16x4 a = *(const bf16x4*)&parts[(size_t)k * PSZ + base];
            v0 += (float)a[0]; v1 += (float)a[1];
            v2 += (float)a[2]; v3 += (float)a[3];
        }
        s += v0 + v1 + v2 + v3;
        s2 += v0 * v0 + v1 * v1 + v2 * v2 + v3 * v3;
    }
    s  += __shfl_down(s,  32, 64);
    s2 += __shfl_down(s2, 32, 64);
    __shared__ float ls[4][32][2];
    const int wv = tid >> 6, ll = tid & 63;
    if (ll < 32) { ls[wv][ll][0] = s; ls[wv][ll][1] = s2; }
    __syncthreads();
    if (tid < 32) {
        float S = ls[0][tid][0] + ls[1][tid][0] + ls[2][tid][0] + ls[3][tid][0];
        float S2 = ls[0][tid][1] + ls[1][tid][1] + ls[2][tid][1] + ls[3][tid][1];
        int g = tid;
        pstat[(((size_t)b * NG + g) * 64 + pb) * 2]     = S;
        pstat[(((size_t)b * NG + g) * 64 + pb) * 2 + 1] = S2;
    }
}

// ---------------- GN2 apply (inline finalize) + SiLU -> aT bf16 channels-last ----------------
__global__ __launch_bounds__(256) void gn2_apply_kernel(
    const __bf16* __restrict__ h1T, const __bf16* __restrict__ parts,
    const int* __restrict__ aim, const float* __restrict__ emb,
    const float* __restrict__ pstat, const float* __restrict__ scale,
    const float* __restrict__ bias, __bf16* __restrict__ outT)
{
    const int pb = blockIdx.x, b = blockIdx.y;
    const int tid = threadIdx.x;
    const int c4 = tid & 31;
    const int g = c4;
    __shared__ float st[32][2];
    if (tid < 32) {
        float S = 0.f, S2 = 0.f;
        const float* ps = pstat + ((size_t)b * NG + tid) * 128;
        for (int k = 0; k < 64; ++k) { S += ps[k * 2]; S2 += ps[k * 2 + 1]; }
        float mm = S * (1.f / 16384.f);
        float var = S2 * (1.f / 16384.f) - mm * mm;
        st[tid][0] = mm;
        st[tid][1] = rsqrtf(var + 1e-5f);
    }
    __syncthreads();
    const float4 ev = *(const float4*)&emb[aim[b] * CC + c4 * 4];
    const float4 sc = *(const float4*)&scale[c4 * 4];
    const float4 bi = *(const float4*)&bias[c4 * 4];
    const float m = st[g][0], inv = st[g][1];
    for (int it = 0; it < 8; ++it) {
        int prow = it * 8 + (tid >> 5);
        size_t base = ((size_t)(b * SP + pb * 64 + prow)) * CC + c4 * 4;
        bf16x4 hv = *(const bf16x4*)&h1T[base];
        float v0 = (float)hv[0] + ev.x;
        float v1 = (float)hv[1] + ev.y;
        float v2 = (float)hv[2] + ev.z;
        float v3 = (float)hv[3] + ev.w;
        #pragma unroll
        for (int k = 0; k < NS; ++k) {
            bf16x4 a = *(const bf16x4*)&parts[(size_t)k * PSZ + base];
            v0 += (float)a[0]; v1 += (float)a[1];
            v2 += (float)a[2]; v3 += (float)a[3];
        }
        bf16x4 o;
        o[0] = (__bf16)silu_f((v0 - m) * inv * sc.x + bi.x);
        o[1] = (__bf16)silu_f((v1 - m) * inv * sc.y + bi.y);
        o[2] = (__bf16)silu_f((v2 - m) * inv * sc.z + bi.z);
        o[3] = (__bf16)silu_f((v3 - m) * inv * sc.w + bi.w);
        *(bf16x4*)&outT[base] = o;
    }
}

extern "C" void kernel_launch(void* const* d_in, const int* in_sizes, int n_in,
                              void* d_out, int out_size, void* d_ws, size_t ws_size,
                              hipStream_t stream)
{
    const float* x     = (const float*)d_in[0];
    const float* t     = (const float*)d_in[1];
    const int*   aim   = (const int*)  d_in[2];
    const float* cond  = (const float*)d_in[3];
    const float* gn1s  = (const float*)d_in[4];
    const float* gn1b  = (const float*)d_in[5];
    const float* c1w   = (const float*)d_in[6];
    const float* c1b   = (const float*)d_in[7];
    const float* mlpw  = (const float*)d_in[8];
    const float* mlpb  = (const float*)d_in[9];
    const float* cw    = (const float*)d_in[10];
    const float* cb    = (const float*)d_in[11];
    const float* gn2s  = (const float*)d_in[12];
    const float* gn2b  = (const float*)d_in[13];
    const float* c2w   = (const float*)d_in[14];
    const float* c2b   = (const float*)d_in[15];
    const float* emb   = (const float*)d_in[16];
    float* out = (float*)d_out;
    float* ws = (float*)d_ws;

    // float-offset workspace map
    __bf16* aT    = (__bf16*)ws;                  // [0, 1048576)
    __bf16* h1T   = (__bf16*)(ws + 1048576);      // [1048576, 2097152)
    __bf16* cmT   = (__bf16*)(ws + 2097152);      // [2097152, 3145728)
    __bf16* cm2   = (__bf16*)(ws + 3145728);      // [3145728, 4194304)
    __bf16* parts = (__bf16*)(ws + 4194304);      // 2 x 1,048,576 fl = [4194304, 6291456)
    __bf16* wt    = (__bf16*)(ws + 6291456);      // 294,912 bf16 = 147,456 fl
    float*  tembw = ws + 6438912;                 // 512
    float*  pstat = ws + 6439424;                 // 16384

    gn1_fused_kernel<<<dim3(BB * NG), dim3(256), 0, stream>>>(x, gn1s, gn1b, aT);
    wt_kernel<<<dim3(18), dim3(256), 0, stream>>>(c1w, c2w, wt);
    temb_kernel<<<dim3(8), dim3(256), 0, stream>>>(t, mlpw, mlpb, tembw);
    conv1x1_kernel<<<dim3(16, 16, BB), dim3(256), 0, stream>>>(cond, cw, cb, cmT, cm2);
    conv_mfma_kernel<true, false><<<dim3(128, BB), dim3(256), 0, stream>>>(
        aT, wt, c1b, tembw, nullptr, h1T, nullptr);
    attn_kernel<<<dim3(WW, BB, NS), dim3(256), 0, stream>>>(h1T, cmT, cm2, parts);
    gn2_stats_kernel<<<dim3(64, BB), dim3(256), 0, stream>>>(h1T, parts, aim, emb, pstat);
    gn2_apply_kernel<<<dim3(64, BB), dim3(256), 0, stream>>>(
        h1T, parts, aim, emb, pstat, gn2s, gn2b, aT);
    conv_mfma_kernel<false, true><<<dim3(128, BB), dim3(256), 0, stream>>>(
        aT, wt + (size_t)9 * 16384, c2b, nullptr, x, nullptr, out);
}

// Round 11
// 243.343 us; speedup vs baseline: 7.0719x; 1.0349x over previous
//
#include <hip/hip_runtime.h>
#include <cmath>

#define BB 4
#define CC 128
#define HH 64
#define WW 64
#define SP 4096   // H*W
#define NG 32     // groups
#define TT 64     // attention uv-tile width
#define NS 4      // attention uv split factor
#define PSZ ((size_t)BB * SP * CC)   // partial tensor elements

typedef __bf16 bf16x8 __attribute__((ext_vector_type(8)));
typedef __bf16 bf16x4 __attribute__((ext_vector_type(4)));
typedef float  f32x4  __attribute__((ext_vector_type(4)));

__device__ __forceinline__ float silu_f(float v) {
    return v / (1.f + __expf(-v));
}

// ================= merged prep kernel =================
// blocks [0,128): GN1 fused (stats+apply+SiLU -> aT channels-last bf16)
// blocks [128,146): 3x3 weight transpose -> wt bf16
// blocks [146,154): time-embedding MLP -> tembw
// blocks [154,410): 1x1 conv MFMA -> cmT (scaled) + cm2
__global__ __launch_bounds__(256) void prep_kernel(
    const float* __restrict__ x, const float* __restrict__ gn1s,
    const float* __restrict__ gn1b, __bf16* __restrict__ aT,
    const float* __restrict__ c1w, const float* __restrict__ c2w,
    __bf16* __restrict__ wt,
    const float* __restrict__ t, const float* __restrict__ mlpw,
    const float* __restrict__ mlpb, float* __restrict__ tembw,
    const float* __restrict__ cond, const float* __restrict__ cw,
    const float* __restrict__ cb, __bf16* __restrict__ cmT,
    __bf16* __restrict__ cm2)
{
    __shared__ __align__(16) char pool[65536];
    __shared__ float rs[4], rs2[4], mean_s, inv_s;
    const int blk = blockIdx.x;
    const int tid = threadIdx.x;

    if (blk < 128) {
        // ---- GN1 fused ----
        const int b = blk >> 5, g = blk & 31;
        float* X = (float*)pool;
        const float* p = x + (size_t)blk * 16384;
        float s = 0.f, s2 = 0.f;
        for (int it = 0; it < 16; ++it) {
            int q = it * 256 + tid;
            float4 v = *(const float4*)&p[q * 4];
            *(float4*)&X[q * 4] = v;
            s += v.x + v.y + v.z + v.w;
            s2 += v.x * v.x + v.y * v.y + v.z * v.z + v.w * v.w;
        }
        #pragma unroll
        for (int off = 32; off >= 1; off >>= 1) {
            s  += __shfl_down(s,  off, 64);
            s2 += __shfl_down(s2, off, 64);
        }
        const int wid = tid >> 6;
        if ((tid & 63) == 0) { rs[wid] = s; rs2[wid] = s2; }
        __syncthreads();
        if (tid == 0) {
            float S = rs[0] + rs[1] + rs[2] + rs[3];
            float S2 = rs2[0] + rs2[1] + rs2[2] + rs2[3];
            float m = S * (1.f / 16384.f);
            float var = S2 * (1.f / 16384.f) - m * m;
            mean_s = m;
            inv_s = rsqrtf(var + 1e-5f);
        }
        __syncthreads();
        const float m = mean_s, inv = inv_s;
        float sc[4], bi[4];
        #pragma unroll
        for (int j = 0; j < 4; ++j) { sc[j] = gn1s[g * 4 + j]; bi[j] = gn1b[g * 4 + j]; }
        for (int it = 0; it < 16; ++it) {
            int pp = it * 256 + tid;
            bf16x4 o;
            #pragma unroll
            for (int j = 0; j < 4; ++j)
                o[j] = (__bf16)silu_f((X[j * 4096 + pp] - m) * inv * sc[j] + bi[j]);
            *(bf16x4*)&aT[((size_t)(b * SP + pp)) * CC + g * 4] = o;
        }
    } else if (blk < 146) {
        // ---- weight transpose ----
        const int idx = blk - 128;
        const int wsel = idx / 9, tap = idx % 9;
        const float* src = wsel ? c2w : c1w;
        __bf16* dst = wt + (size_t)wsel * 9 * 16384 + (size_t)tap * 16384;
        for (int it = 0; it < 64; ++it) {
            int q = it * 256 + tid;
            dst[q] = (__bf16)src[(size_t)q * 9 + tap];
        }
    } else if (blk < 154) {
        // ---- temb MLP ----
        const int cog = blk - 146;
        float* st = (float*)pool;            // [4][512]
        float* wr = (float*)(pool + 8192);   // [16][512]
        for (int it = 0; it < 8; ++it) {
            int q = it * 256 + tid;
            st[q] = silu_f(t[q]);
        }
        for (int it = 0; it < 8; ++it) {
            int q = it * 256 + tid;
            int row = q >> 7, col4 = q & 127;
            *(float4*)&wr[row * 512 + col4 * 4] =
                *(const float4*)&mlpw[(size_t)(cog * 16 + row) * 512 + col4 * 4];
        }
        __syncthreads();
        const int col = tid >> 4, seg = tid & 15;
        float acc[4] = {0.f, 0.f, 0.f, 0.f};
        for (int k = seg * 32; k < seg * 32 + 32; ++k) {
            float wv = wr[col * 512 + k];
            acc[0] += st[0 * 512 + k] * wv;
            acc[1] += st[1 * 512 + k] * wv;
            acc[2] += st[2 * 512 + k] * wv;
            acc[3] += st[3 * 512 + k] * wv;
        }
        #pragma unroll
        for (int o = 1; o < 16; o <<= 1) {
            #pragma unroll
            for (int b4 = 0; b4 < 4; ++b4)
                acc[b4] += __shfl_xor(acc[b4], o, 64);
        }
        if (seg == 0) {
            float bv = mlpb[cog * 16 + col];
            #pragma unroll
            for (int b4 = 0; b4 < 4; ++b4)
                tembw[b4 * 128 + cog * 16 + col] = acc[b4] + bv;
        }
    } else {
        // ---- 1x1 conv MFMA ----
        const int pblk = blk - 154;          // 0..255
        const int b = pblk >> 6;
        const int p0 = (pblk & 63) * 64;
        const int l = tid & 63, wv = tid >> 6;
        const int l15 = l & 15, l4 = l >> 4;
        const int mB = wv * 32;              // wave co base

        __bf16* XT = (__bf16*)pool;              // [p 64][ci] stride 134
        __bf16* wl = (__bf16*)(pool + 17152);    // [co 128][ci] stride 134

        for (int it = 0; it < 32; ++it) {
            int q = it * 256 + tid;              // ci = q>>6, p = q&63
            float v = cond[((size_t)(b * CC + (q >> 6))) * SP + p0 + (q & 63)];
            XT[(q & 63) * 134 + (q >> 6)] = (__bf16)v;
        }
        for (int it = 0; it < 64; ++it) {
            int q = it * 256 + tid;              // co = q>>7, ci = q&127
            wl[(q >> 7) * 134 + (q & 127)] = (__bf16)cw[q];
        }
        __syncthreads();

        f32x4 acc[2][4];
        #pragma unroll
        for (int mb = 0; mb < 2; ++mb)
            #pragma unroll
            for (int nt = 0; nt < 4; ++nt) acc[mb][nt] = (f32x4){0.f, 0.f, 0.f, 0.f};

        #pragma unroll
        for (int ks = 0; ks < 4; ++ks) {
            bf16x8 bfr[4];
            #pragma unroll
            for (int nt = 0; nt < 4; ++nt)
                bfr[nt] = *(const bf16x8*)&XT[(nt * 16 + l15) * 134 + ks * 32 + l4 * 8];
            #pragma unroll
            for (int mb = 0; mb < 2; ++mb) {
                bf16x8 afr = *(const bf16x8*)&wl[(mB + mb * 16 + l15) * 134 + ks * 32 + l4 * 8];
                #pragma unroll
                for (int nt = 0; nt < 4; ++nt)
                    acc[mb][nt] = __builtin_amdgcn_mfma_f32_16x16x32_bf16(afr, bfr[nt], acc[mb][nt], 0, 0, 0);
            }
        }

        const float scl = 0.088388347648318447f;  // 1/sqrt(128)
        // cmT [p][co] direct stores (+bias, scaled)
        #pragma unroll
        for (int mb = 0; mb < 2; ++mb) {
            int co0 = mB + mb * 16 + l4 * 4;
            float bv[4];
            #pragma unroll
            for (int r = 0; r < 4; ++r) bv[r] = cb[co0 + r];
            #pragma unroll
            for (int nt = 0; nt < 4; ++nt) {
                int p = p0 + nt * 16 + l15;
                bf16x4 o;
                #pragma unroll
                for (int r = 0; r < 4; ++r)
                    o[r] = (__bf16)((acc[mb][nt][r] + bv[r]) * scl);
                *(bf16x4*)&cmT[((size_t)(b * SP + p)) * CC + co0] = o;
            }
        }
        __syncthreads();
        // cm2 [co][p] via LDS transpose (reuse wl region)
        __bf16* O2 = wl;   // [co 128][p 64] stride 72
        #pragma unroll
        for (int mb = 0; mb < 2; ++mb) {
            int co0 = mB + mb * 16 + l4 * 4;
            #pragma unroll
            for (int r = 0; r < 4; ++r) {
                float bv = cb[co0 + r];
                #pragma unroll
                for (int nt = 0; nt < 4; ++nt)
                    O2[(co0 + r) * 72 + nt * 16 + l15] = (__bf16)(acc[mb][nt][r] + bv);
            }
        }
        __syncthreads();
        #pragma unroll
        for (int it = 0; it < 4; ++it) {
            int q = it * 256 + tid;              // co = q>>3, pc = q&7
            int co = q >> 3, pc = q & 7;
            *(bf16x8*)&cm2[((size_t)(b * CC + co)) * SP + p0 + pc * 8] =
                *(const bf16x8*)&O2[co * 72 + pc * 8];
        }
    }
}

// ---------------- 3x3 conv v4: LDS input, direct stores ----------------
template<bool FUSE_TEMB, bool OUT_CF>
__global__ __launch_bounds__(256, 3) void conv_mfma_kernel(
    const __bf16* __restrict__ inT, const __bf16* __restrict__ wt,
    const float* __restrict__ bias, const float* __restrict__ temb,
    const float* __restrict__ resid, __bf16* __restrict__ outT,
    float* __restrict__ outF)
{
    const int y   = blockIdx.x >> 1;
    const int coh = blockIdx.x & 1;
    const int b   = blockIdx.y;
    const int tid = threadIdx.x;
    const int l = tid & 63, wv = tid >> 6;
    const int l15 = l & 15, l4 = l >> 4;
    const int mB = (wv & 1) * 32;
    const int xh = (wv >> 1) * 32;

    __shared__ __bf16 inS[3 * 66 * 136];

    const __bf16* inTb = inT + (size_t)b * SP * CC;
    for (int q = tid; q < 3 * 66 * 16; q += 256) {
        int cc = q & 15;
        int xs = (q >> 4) % 66;
        int r  = (q >> 4) / 66;
        int yy = y + r - 1;
        int xg = xs - 1;
        bf16x8 v;
        if (((unsigned)yy < 64u) && ((unsigned)xg < 64u)) {
            v = *(const bf16x8*)&inTb[((size_t)(yy * 64 + xg)) * CC + cc * 8];
        } else {
            #pragma unroll
            for (int j = 0; j < 8; ++j) v[j] = (__bf16)0.f;
        }
        *(bf16x8*)&inS[(r * 66 + xs) * 136 + cc * 8] = v;
    }
    __syncthreads();

    f32x4 acc[2][2];
    #pragma unroll
    for (int mb = 0; mb < 2; ++mb)
        #pragma unroll
        for (int nb = 0; nb < 2; ++nb) acc[mb][nb] = (f32x4){0.f, 0.f, 0.f, 0.f};

    const __bf16* wp0 = wt + (size_t)(coh * 64 + mB + l15) * 128 + l4 * 8;
    const __bf16* wp1 = wt + (size_t)(coh * 64 + mB + 16 + l15) * 128 + l4 * 8;

    bf16x8 wb[2][2][4];
    #pragma unroll
    for (int ks = 0; ks < 4; ++ks) {
        wb[0][0][ks] = *(const bf16x8*)(wp0 + ks * 32);
        wb[0][1][ks] = *(const bf16x8*)(wp1 + ks * 32);
    }

    #pragma unroll
    for (int tap = 0; tap < 9; ++tap) {
        const int cur = tap & 1, nxt = cur ^ 1;
        if (tap < 8) {
            #pragma unroll
            for (int ks = 0; ks < 4; ++ks) {
                wb[nxt][0][ks] = *(const bf16x8*)(wp0 + (tap + 1) * 16384 + ks * 32);
                wb[nxt][1][ks] = *(const bf16x8*)(wp1 + (tap + 1) * 16384 + ks * 32);
            }
        }
        const __bf16* rb = &inS[((tap / 3) * 66 + xh + (tap % 3)) * 136];
        #pragma unroll
        for (int ks = 0; ks < 4; ++ks) {
            bf16x8 b0 = *(const bf16x8*)&rb[(l15) * 136 + ks * 32 + l4 * 8];
            bf16x8 b1 = *(const bf16x8*)&rb[(16 + l15) * 136 + ks * 32 + l4 * 8];
            acc[0][0] = __builtin_amdgcn_mfma_f32_16x16x32_bf16(wb[cur][0][ks], b0, acc[0][0], 0, 0, 0);
            acc[1][0] = __builtin_amdgcn_mfma_f32_16x16x32_bf16(wb[cur][1][ks], b0, acc[1][0], 0, 0, 0);
            acc[0][1] = __builtin_amdgcn_mfma_f32_16x16x32_bf16(wb[cur][0][ks], b1, acc[0][1], 0, 0, 0);
            acc[1][1] = __builtin_amdgcn_mfma_f32_16x16x32_bf16(wb[cur][1][ks], b1, acc[1][1], 0, 0, 0);
        }
    }

    if (OUT_CF) {
        #pragma unroll
        for (int mb = 0; mb < 2; ++mb) {
            #pragma unroll
            for (int r = 0; r < 4; ++r) {
                int co = coh * 64 + mB + mb * 16 + l4 * 4 + r;
                float bv = bias[co];
                #pragma unroll
                for (int nb = 0; nb < 2; ++nb) {
                    int p = y * 64 + xh + nb * 16 + l15;
                    size_t o = ((size_t)(b * CC + co)) * SP + p;
                    outF[o] = acc[mb][nb][r] + bv + resid[o];
                }
            }
        }
    } else {
        #pragma unroll
        for (int mb = 0; mb < 2; ++mb) {
            int co0 = coh * 64 + mB + mb * 16 + l4 * 4;
            float bv[4];
            #pragma unroll
            for (int r = 0; r < 4; ++r)
                bv[r] = bias[co0 + r] + (FUSE_TEMB ? temb[b * CC + co0 + r] : 0.f);
            #pragma unroll
            for (int nb = 0; nb < 2; ++nb) {
                int p = y * 64 + xh + nb * 16 + l15;
                bf16x4 o;
                #pragma unroll
                for (int r = 0; r < 4; ++r)
                    o[r] = (__bf16)(acc[mb][nb][r] + bv[r]);
                *(bf16x4*)&outT[((size_t)(b * SP + p)) * CC + co0] = o;
            }
        }
    }
}

// ---------------- fused cross-attention v5: ct2 LDS dbuf + Pb single ----------------
#define CT2 72    // ct2 row stride (bf16)
#define PBS 72    // Pb row stride (bf16)
#define POOL_BYTES 46080

__global__ __launch_bounds__(256, 3) void attn_kernel(
    const __bf16* __restrict__ h1T, const __bf16* __restrict__ cmT,
    const __bf16* __restrict__ cm2, __bf16* __restrict__ parts)
{
    const int w = blockIdx.x;
    const int b = blockIdx.y;
    const int s = blockIdx.z;          // uv quarter
    const int tid = threadIdx.x;
    const int wl = tid >> 6;
    const int l = tid & 63, l15 = l & 15, l4 = l >> 4;
    const int hB = (wl & 1) * 32;
    const int cB = (wl >> 1) * 64;

    __shared__ __align__(16) char pool[POOL_BYTES];
    __bf16* ct2p = (__bf16*)pool;
    __bf16* Pb   = (__bf16*)(pool + 36864);
    __bf16* Otr  = (__bf16*)pool;

    const __bf16* h1Tb = h1T + (size_t)b * SP * CC;
    const __bf16* cmTb = cmT + (size_t)b * SP * CC;
    const __bf16* cm2b = cm2 + (size_t)b * CC * SP;

    bf16x8 hfr[4][4];
    #pragma unroll
    for (int nt = 0; nt < 4; ++nt)
        #pragma unroll
        for (int ks = 0; ks < 4; ++ks)
            hfr[nt][ks] = *(const bf16x8*)&h1Tb[((size_t)((nt * 16 + l15) * WW + w)) * CC + ks * 32 + l4 * 8];

    f32x4 acc2[2][4];
    #pragma unroll
    for (int mb = 0; mb < 2; ++mb)
        #pragma unroll
        for (int nt = 0; nt < 4; ++nt) acc2[mb][nt] = (f32x4){0.f, 0.f, 0.f, 0.f};

    const int sc = tid >> 3;
    const int stc = tid & 7;

    {
        const int uv0 = s * TT;
        #pragma unroll
        for (int it = 0; it < 4; ++it) {
            int c = it * 32 + sc;
            *(bf16x8*)&ct2p[c * CT2 + stc * 8] =
                *(const bf16x8*)&cm2b[(size_t)c * SP + uv0 + stc * 8];
        }
        const __bf16* arow = cmTb + (size_t)(uv0 + 16 * wl + l15) * CC;
        bf16x8 afr[4];
        #pragma unroll
        for (int ks = 0; ks < 4; ++ks) afr[ks] = *(const bf16x8*)&arow[ks * 32 + l4 * 8];
        f32x4 s1[4];
        #pragma unroll
        for (int nt = 0; nt < 4; ++nt) {
            s1[nt] = (f32x4){0.f, 0.f, 0.f, 0.f};
            #pragma unroll
            for (int ks = 0; ks < 4; ++ks)
                s1[nt] = __builtin_amdgcn_mfma_f32_16x16x32_bf16(afr[ks], hfr[nt][ks], s1[nt], 0, 0, 0);
        }
        #pragma unroll
        for (int r = 0; r < 4; ++r) {
            float e0 = __expf(s1[0][r]), e1 = __expf(s1[1][r]);
            float e2 = __expf(s1[2][r]), e3 = __expf(s1[3][r]);
            float sm = e0 + e1 + e2 + e3;
            sm += __shfl_xor(sm, 1, 64);
            sm += __shfl_xor(sm, 2, 64);
            sm += __shfl_xor(sm, 4, 64);
            sm += __shfl_xor(sm, 8, 64);
            float ri = 1.f / sm;
            s1[0][r] = e0 * ri; s1[1][r] = e1 * ri;
            s1[2][r] = e2 * ri; s1[3][r] = e3 * ri;
        }
        #pragma unroll
        for (int nt = 0; nt < 4; ++nt) {
            bf16x4 pk;
            pk[0] = (__bf16)s1[nt][0]; pk[1] = (__bf16)s1[nt][1];
            pk[2] = (__bf16)s1[nt][2]; pk[3] = (__bf16)s1[nt][3];
            *(bf16x4*)&Pb[(nt * 16 + l15) * PBS + 16 * wl + l4 * 4] = pk;
        }
    }

    for (int i = 0; i < SP / TT / NS; ++i) {
        const int cur = i & 1;
        __syncthreads();
        bf16x8 st4[4];
        bf16x8 afr[4];
        if (i < SP / TT / NS - 1) {
            const int uv0n = ((i + 1) * NS + s) * TT;
            #pragma unroll
            for (int it = 0; it < 4; ++it) {
                int c = it * 32 + sc;
                st4[it] = *(const bf16x8*)&cm2b[(size_t)c * SP + uv0n + stc * 8];
            }
            const __bf16* arow = cmTb + (size_t)(uv0n + 16 * wl + l15) * CC;
            #pragma unroll
            for (int ks = 0; ks < 4; ++ks) afr[ks] = *(const bf16x8*)&arow[ks * 32 + l4 * 8];
        }
        bf16x8 pfr[2][2];
        #pragma unroll
        for (int mb = 0; mb < 2; ++mb)
            #pragma unroll
            for (int ks = 0; ks < 2; ++ks)
                pfr[mb][ks] = *(const bf16x8*)&Pb[(hB + mb * 16 + l15) * PBS + ks * 32 + l4 * 8];
        __syncthreads();
        {
            const __bf16* ctR = ct2p + cur * 9216;
            #pragma unroll
            for (int mb = 0; mb < 2; ++mb)
                #pragma unroll
                for (int nt = 0; nt < 4; ++nt)
                    #pragma unroll
                    for (int ks = 0; ks < 2; ++ks) {
                        bf16x8 bfr = *(const bf16x8*)&ctR[(cB + nt * 16 + l15) * CT2 + ks * 32 + l4 * 8];
                        acc2[mb][nt] = __builtin_amdgcn_mfma_f32_16x16x32_bf16(
                            pfr[mb][ks], bfr, acc2[mb][nt], 0, 0, 0);
                    }
        }
        if (i < SP / TT / NS - 1) {
            __bf16* ctW = ct2p + (cur ^ 1) * 9216;
            #pragma unroll
            for (int it = 0; it < 4; ++it) {
                int c = it * 32 + sc;
                *(bf16x8*)&ctW[c * CT2 + stc * 8] = st4[it];
            }
            f32x4 s1[4];
            #pragma unroll
            for (int nt = 0; nt < 4; ++nt) {
                s1[nt] = (f32x4){0.f, 0.f, 0.f, 0.f};
                #pragma unroll
                for (int ks = 0; ks < 4; ++ks)
                    s1[nt] = __builtin_amdgcn_mfma_f32_16x16x32_bf16(afr[ks], hfr[nt][ks], s1[nt], 0, 0, 0);
            }
            #pragma unroll
            for (int r = 0; r < 4; ++r) {
                float e0 = __expf(s1[0][r]), e1 = __expf(s1[1][r]);
                float e2 = __expf(s1[2][r]), e3 = __expf(s1[3][r]);
                float sm = e0 + e1 + e2 + e3;
                sm += __shfl_xor(sm, 1, 64);
                sm += __shfl_xor(sm, 2, 64);
                sm += __shfl_xor(sm, 4, 64);
                sm += __shfl_xor(sm, 8, 64);
                float ri = 1.f / sm;
                s1[0][r] = e0 * ri; s1[1][r] = e1 * ri;
                s1[2][r] = e2 * ri; s1[3][r] = e3 * ri;
            }
            #pragma unroll
            for (int nt = 0; nt < 4; ++nt) {
                bf16x4 pk;
                pk[0] = (__bf16)s1[nt][0]; pk[1] = (__bf16)s1[nt][1];
                pk[2] = (__bf16)s1[nt][2]; pk[3] = (__bf16)s1[nt][3];
                *(bf16x4*)&Pb[(nt * 16 + l15) * PBS + 16 * wl + l4 * 4] = pk;
            }
        }
    }

    __syncthreads();
    #pragma unroll
    for (int mb = 0; mb < 2; ++mb)
        #pragma unroll
        for (int nt = 0; nt < 4; ++nt)
            #pragma unroll
            for (int r = 0; r < 4; ++r)
                Otr[(hB + mb * 16 + l4 * 4 + r) * 136 + cB + nt * 16 + l15] =
                    (__bf16)acc2[mb][nt][r];
    __syncthreads();
    __bf16* pO = parts + (size_t)s * PSZ;
    #pragma unroll
    for (int it = 0; it < 4; ++it) {
        int q = it * 256 + tid;
        int h = q >> 4, cc = q & 15;
        *(bf16x8*)&pO[((size_t)(b * SP + h * WW + w)) * CC + cc * 8] =
            *(const bf16x8*)&Otr[h * 136 + cc * 8];
    }
}

// ---------------- GN2 stats partials: h2 = h1T + sum(parts) + emb ----------------
__global__ __launch_bounds__(256) void gn2_stats_kernel(
    const __bf16* __restrict__ h1T, const __bf16* __restrict__ parts,
    const int* __restrict__ aim, const float* __restrict__ emb,
    float* __restrict__ pstat)
{
    const int pb = blockIdx.x, b = blockIdx.y;
    const int tid = threadIdx.x;
    const int c4 = tid & 31;
    const float4 ev = *(const float4*)&emb[aim[b] * CC + c4 * 4];
    float s = 0.f, s2 = 0.f;
    for (int it = 0; it < 8; ++it) {
        int prow = it * 8 + (tid >> 5);
        size_t base = ((size_t)(b * SP + pb * 64 + prow)) * CC + c4 * 4;
        bf16x4 hv = *(const bf16x4*)&h1T[base];
        float v0 = (float)hv[0] + ev.x;
        float v1 = (float)hv[1] + ev.y;
        float v2 = (float)hv[2] + ev.z;
        float v3 = (float)hv[3] + ev.w;
        #pragma unroll
        for (int k = 0; k < NS; ++k) {
            bf16x4 a = *(const bf16x4*)&parts[(size_t)k * PSZ + base];
            v0 += (float)a[0]; v1 += (float)a[1];
            v2 += (float)a[2]; v3 += (float)a[3];
        }
        s += v0 + v1 + v2 + v3;
        s2 += v0 * v0 + v1 * v1 + v2 * v2 + v3 * v3;
    }
    s  += __shfl_down(s,  32, 64);
    s2 += __shfl_down(s2, 32, 64);
    __shared__ float ls[4][32][2];
    const int wv = tid >> 6, ll = tid & 63;
    if (ll < 32) { ls[wv][ll][0] = s; ls[wv][ll][1] = s2; }
    __syncthreads();
    if (tid < 32) {
        float S = ls[0][tid][0] + ls[1][tid][0] + ls[2][tid][0] + ls[3][tid][0];
        float S2 = ls[0][tid][1] + ls[1][tid][1] + ls[2][tid][1] + ls[3][tid][1];
        int g = tid;
        pstat[(((size_t)b * NG + g) * 64 + pb) * 2]     = S;
        pstat[(((size_t)b * NG + g) * 64 + pb) * 2 + 1] = S2;
    }
}

// ---------------- GN2 apply (inline finalize) + SiLU -> aT bf16 channels-last ----------------
__global__ __launch_bounds__(256) void gn2_apply_kernel(
    const __bf16* __restrict__ h1T, const __bf16* __restrict__ parts,
    const int* __restrict__ aim, const float* __restrict__ emb,
    const float* __restrict__ pstat, const float* __restrict__ scale,
    const float* __restrict__ bias, __bf16* __restrict__ outT)
{
    const int pb = blockIdx.x, b = blockIdx.y;
    const int tid = threadIdx.x;
    const int c4 = tid & 31;
    const int g = c4;
    __shared__ float st[32][2];
    if (tid < 32) {
        float S = 0.f, S2 = 0.f;
        const float* ps = pstat + ((size_t)b * NG + tid) * 128;
        for (int k = 0; k < 64; ++k) { S += ps[k * 2]; S2 += ps[k * 2 + 1]; }
        float mm = S * (1.f / 16384.f);
        float var = S2 * (1.f / 16384.f) - mm * mm;
        st[tid][0] = mm;
        st[tid][1] = rsqrtf(var + 1e-5f);
    }
    __syncthreads();
    const float4 ev = *(const float4*)&emb[aim[b] * CC + c4 * 4];
    const float4 sc = *(const float4*)&scale[c4 * 4];
    const float4 bi = *(const float4*)&bias[c4 * 4];
    const float m = st[g][0], inv = st[g][1];
    for (int it = 0; it < 8; ++it) {
        int prow = it * 8 + (tid >> 5);
        size_t base = ((size_t)(b * SP + pb * 64 + prow)) * CC + c4 * 4;
        bf16x4 hv = *(const bf16x4*)&h1T[base];
        float v0 = (float)hv[0] + ev.x;
        float v1 = (float)hv[1] + ev.y;
        float v2 = (float)hv[2] + ev.z;
        float v3 = (float)hv[3] + ev.w;
        #pragma unroll
        for (int k = 0; k < NS; ++k) {
            bf16x4 a = *(const bf16x4*)&parts[(size_t)k * PSZ + base];
            v0 += (float)a[0]; v1 += (float)a[1];
            v2 += (float)a[2]; v3 += (float)a[3];
        }
        bf16x4 o;
        o[0] = (__bf16)silu_f((v0 - m) * inv * sc.x + bi.x);
        o[1] = (__bf16)silu_f((v1 - m) * inv * sc.y + bi.y);
        o[2] = (__bf16)silu_f((v2 - m) * inv * sc.z + bi.z);
        o[3] = (__bf16)silu_f((v3 - m) * inv * sc.w + bi.w);
        *(bf16x4*)&outT[base] = o;
    }
}

extern "C" void kernel_launch(void* const* d_in, const int* in_sizes, int n_in,
                              void* d_out, int out_size, void* d_ws, size_t ws_size,
                              hipStream_t stream)
{
    const float* x     = (const float*)d_in[0];
    const float* t     = (const float*)d_in[1];
    const int*   aim   = (const int*)  d_in[2];
    const float* cond  = (const float*)d_in[3];
    const float* gn1s  = (const float*)d_in[4];
    const float* gn1b  = (const float*)d_in[5];
    const float* c1w   = (const float*)d_in[6];
    const float* c1b   = (const float*)d_in[7];
    const float* mlpw  = (const float*)d_in[8];
    const float* mlpb  = (const float*)d_in[9];
    const float* cw    = (const float*)d_in[10];
    const float* cb    = (const float*)d_in[11];
    const float* gn2s  = (const float*)d_in[12];
    const float* gn2b  = (const float*)d_in[13];
    const float* c2w   = (const float*)d_in[14];
    const float* c2b   = (const float*)d_in[15];
    const float* emb   = (const float*)d_in[16];
    float* out = (float*)d_out;
    float* ws = (float*)d_ws;

    // float-offset workspace map
    __bf16* aT    = (__bf16*)ws;                  // [0, 1048576)
    __bf16* h1T   = (__bf16*)(ws + 1048576);      // [1048576, 2097152)
    __bf16* cmT   = (__bf16*)(ws + 2097152);      // [2097152, 3145728)
    __bf16* cm2   = (__bf16*)(ws + 3145728);      // [3145728, 4194304)
    __bf16* parts = (__bf16*)(ws + 4194304);      // 4 x 1,048,576 fl = [4194304, 8388608)
    __bf16* wt    = (__bf16*)(ws + 8388608);      // 294,912 bf16 = 147,456 fl
    float*  tembw = ws + 8536064;                 // 512
    float*  pstat = ws + 8536576;                 // 16384

    prep_kernel<<<dim3(410), dim3(256), 0, stream>>>(
        x, gn1s, gn1b, aT, c1w, c2w, wt, t, mlpw, mlpb, tembw,
        cond, cw, cb, cmT, cm2);
    conv_mfma_kernel<true, false><<<dim3(128, BB), dim3(256), 0, stream>>>(
        aT, wt, c1b, tembw, nullptr, h1T, nullptr);
    attn_kernel<<<dim3(WW, BB, NS), dim3(256), 0, stream>>>(h1T, cmT, cm2, parts);
    gn2_stats_kernel<<<dim3(64, BB), dim3(256), 0, stream>>>(h1T, parts, aim, emb, pstat);
    gn2_apply_kernel<<<dim3(64, BB), dim3(256), 0, stream>>>(
        h1T, parts, aim, emb, pstat, gn2s, gn2b, aT);
    conv_mfma_kernel<false, true><<<dim3(128, BB), dim3(256), 0, stream>>>(
        aT, wt + (size_t)9 * 16384, c2b, nullptr, x, nullptr, out);
}

// Round 12
// 229.838 us; speedup vs baseline: 7.4874x; 1.0588x over previous
//
#include <hip/hip_runtime.h>
#include <cmath>

#define BB 4
#define CC 128
#define HH 64
#define WW 64
#define SP 4096   // H*W
#define NG 32     // groups
#define TT 64     // attention uv-tile width
#define NS 2      // attention uv split factor
#define PSZ ((size_t)BB * SP * CC)   // partial tensor elements

typedef __bf16 bf16x8 __attribute__((ext_vector_type(8)));
typedef __bf16 bf16x4 __attribute__((ext_vector_type(4)));
typedef float  f32x4  __attribute__((ext_vector_type(4)));

__device__ __forceinline__ float silu_f(float v) {
    return v / (1.f + __expf(-v));
}

// ================= merged prep kernel (slim LDS: 18.5 KB pool) =================
// blocks [0,128): GN1 two-pass -> aT channels-last bf16
// blocks [128,146): 3x3 weight transpose -> wt bf16
// blocks [146,154): time-embedding MLP -> tembw
// blocks [154,410): 1x1 conv MFMA -> cmT (scaled) + cm2
__global__ __launch_bounds__(256) void prep_kernel(
    const float* __restrict__ x, const float* __restrict__ gn1s,
    const float* __restrict__ gn1b, __bf16* __restrict__ aT,
    const float* __restrict__ c1w, const float* __restrict__ c2w,
    __bf16* __restrict__ wt,
    const float* __restrict__ t, const float* __restrict__ mlpw,
    const float* __restrict__ mlpb, float* __restrict__ tembw,
    const float* __restrict__ cond, const float* __restrict__ cw,
    const float* __restrict__ cb, __bf16* __restrict__ cmT,
    __bf16* __restrict__ cm2)
{
    __shared__ __align__(16) char pool[18432];
    __shared__ float rs[4], rs2[4], mean_s, inv_s;
    const int blk = blockIdx.x;
    const int tid = threadIdx.x;

    if (blk < 128) {
        // ---- GN1 two-pass (no big LDS) ----
        const int b = blk >> 5, g = blk & 31;
        const float* p = x + (size_t)blk * 16384;
        float s = 0.f, s2 = 0.f;
        for (int it = 0; it < 16; ++it) {
            int q = it * 256 + tid;
            float4 v = *(const float4*)&p[q * 4];
            s += v.x + v.y + v.z + v.w;
            s2 += v.x * v.x + v.y * v.y + v.z * v.z + v.w * v.w;
        }
        #pragma unroll
        for (int off = 32; off >= 1; off >>= 1) {
            s  += __shfl_down(s,  off, 64);
            s2 += __shfl_down(s2, off, 64);
        }
        const int wid = tid >> 6;
        if ((tid & 63) == 0) { rs[wid] = s; rs2[wid] = s2; }
        __syncthreads();
        if (tid == 0) {
            float S = rs[0] + rs[1] + rs[2] + rs[3];
            float S2 = rs2[0] + rs2[1] + rs2[2] + rs2[3];
            float m = S * (1.f / 16384.f);
            float var = S2 * (1.f / 16384.f) - m * m;
            mean_s = m;
            inv_s = rsqrtf(var + 1e-5f);
        }
        __syncthreads();
        const float m = mean_s, inv = inv_s;
        float sc[4], bi[4];
        #pragma unroll
        for (int j = 0; j < 4; ++j) { sc[j] = gn1s[g * 4 + j]; bi[j] = gn1b[g * 4 + j]; }
        for (int it = 0; it < 16; ++it) {
            int pp = it * 256 + tid;
            bf16x4 o;
            #pragma unroll
            for (int j = 0; j < 4; ++j)
                o[j] = (__bf16)silu_f((p[j * 4096 + pp] - m) * inv * sc[j] + bi[j]);
            *(bf16x4*)&aT[((size_t)(b * SP + pp)) * CC + g * 4] = o;
        }
    } else if (blk < 146) {
        // ---- weight transpose ----
        const int idx = blk - 128;
        const int wsel = idx / 9, tap = idx % 9;
        const float* src = wsel ? c2w : c1w;
        __bf16* dst = wt + (size_t)wsel * 9 * 16384 + (size_t)tap * 16384;
        for (int it = 0; it < 64; ++it) {
            int q = it * 256 + tid;
            dst[q] = (__bf16)src[(size_t)q * 9 + tap];
        }
    } else if (blk < 154) {
        // ---- temb MLP (weights direct from global) ----
        const int cog = blk - 146;
        float* st = (float*)pool;            // [4][512] = 8 KB
        for (int it = 0; it < 8; ++it) {
            int q = it * 256 + tid;
            st[q] = silu_f(t[q]);
        }
        __syncthreads();
        const int col = tid >> 4, seg = tid & 15;
        const float* wr = mlpw + (size_t)(cog * 16 + col) * 512 + seg * 32;
        float acc[4] = {0.f, 0.f, 0.f, 0.f};
        #pragma unroll
        for (int k8 = 0; k8 < 8; ++k8) {
            float4 wv = *(const float4*)&wr[k8 * 4];
            #pragma unroll
            for (int j = 0; j < 4; ++j) {
                int k = seg * 32 + k8 * 4 + j;
                float w4 = (&wv.x)[j];
                acc[0] += st[0 * 512 + k] * w4;
                acc[1] += st[1 * 512 + k] * w4;
                acc[2] += st[2 * 512 + k] * w4;
                acc[3] += st[3 * 512 + k] * w4;
            }
        }
        #pragma unroll
        for (int o = 1; o < 16; o <<= 1) {
            #pragma unroll
            for (int b4 = 0; b4 < 4; ++b4)
                acc[b4] += __shfl_xor(acc[b4], o, 64);
        }
        if (seg == 0) {
            float bv = mlpb[cog * 16 + col];
            #pragma unroll
            for (int b4 = 0; b4 < 4; ++b4)
                tembw[b4 * 128 + cog * 16 + col] = acc[b4] + bv;
        }
    } else {
        // ---- 1x1 conv MFMA (weights converted in-register) ----
        const int pblk = blk - 154;          // 0..255
        const int b = pblk >> 6;
        const int p0 = (pblk & 63) * 64;
        const int l = tid & 63, wv = tid >> 6;
        const int l15 = l & 15, l4 = l >> 4;
        const int mB = wv * 32;              // wave co base

        __bf16* XT = (__bf16*)pool;          // [p 64][ci] stride 136 = 17408 B

        for (int it = 0; it < 32; ++it) {
            int q = it * 256 + tid;          // ci = q>>6, p = q&63
            float v = cond[((size_t)(b * CC + (q >> 6))) * SP + p0 + (q & 63)];
            XT[(q & 63) * 136 + (q >> 6)] = (__bf16)v;
        }
        __syncthreads();

        f32x4 acc[2][4];
        #pragma unroll
        for (int mb = 0; mb < 2; ++mb)
            #pragma unroll
            for (int nt = 0; nt < 4; ++nt) acc[mb][nt] = (f32x4){0.f, 0.f, 0.f, 0.f};

        #pragma unroll
        for (int ks = 0; ks < 4; ++ks) {
            bf16x8 bfr[4];
            #pragma unroll
            for (int nt = 0; nt < 4; ++nt)
                bfr[nt] = *(const bf16x8*)&XT[(nt * 16 + l15) * 136 + ks * 32 + l4 * 8];
            #pragma unroll
            for (int mb = 0; mb < 2; ++mb) {
                const float* wrow = cw + (size_t)(mB + mb * 16 + l15) * 128 + ks * 32 + l4 * 8;
                float4 wa = *(const float4*)wrow;
                float4 wb4 = *(const float4*)(wrow + 4);
                bf16x8 afr;
                afr[0] = (__bf16)wa.x; afr[1] = (__bf16)wa.y;
                afr[2] = (__bf16)wa.z; afr[3] = (__bf16)wa.w;
                afr[4] = (__bf16)wb4.x; afr[5] = (__bf16)wb4.y;
                afr[6] = (__bf16)wb4.z; afr[7] = (__bf16)wb4.w;
                #pragma unroll
                for (int nt = 0; nt < 4; ++nt)
                    acc[mb][nt] = __builtin_amdgcn_mfma_f32_16x16x32_bf16(afr, bfr[nt], acc[mb][nt], 0, 0, 0);
            }
        }

        const float scl = 0.088388347648318447f;  // 1/sqrt(128)
        // cmT [p][co] direct stores (+bias, scaled)
        #pragma unroll
        for (int mb = 0; mb < 2; ++mb) {
            int co0 = mB + mb * 16 + l4 * 4;
            float bv[4];
            #pragma unroll
            for (int r = 0; r < 4; ++r) bv[r] = cb[co0 + r];
            #pragma unroll
            for (int nt = 0; nt < 4; ++nt) {
                int p = p0 + nt * 16 + l15;
                bf16x4 o;
                #pragma unroll
                for (int r = 0; r < 4; ++r)
                    o[r] = (__bf16)((acc[mb][nt][r] + bv[r]) * scl);
                *(bf16x4*)&cmT[((size_t)(b * SP + p)) * CC + co0] = o;
            }
        }
        __syncthreads();
        // cm2 [co][p] via LDS transpose (reuse pool)
        __bf16* O2 = (__bf16*)pool;   // [co 128][p 64] stride 72 = 18432 B
        #pragma unroll
        for (int mb = 0; mb < 2; ++mb) {
            int co0 = mB + mb * 16 + l4 * 4;
            #pragma unroll
            for (int r = 0; r < 4; ++r) {
                float bv = cb[co0 + r];
                #pragma unroll
                for (int nt = 0; nt < 4; ++nt)
                    O2[(co0 + r) * 72 + nt * 16 + l15] = (__bf16)(acc[mb][nt][r] + bv);
            }
        }
        __syncthreads();
        #pragma unroll
        for (int it = 0; it < 4; ++it) {
            int q = it * 256 + tid;
            int co = q >> 3, pc = q & 7;
            *(bf16x8*)&cm2[((size_t)(b * CC + co)) * SP + p0 + pc * 8] =
                *(const bf16x8*)&O2[co * 72 + pc * 8];
        }
    }
}

// ---------------- 3x3 conv v5: 32-x blocks, 26 KB LDS, 4 blocks/CU ----------------
// grid (256, BB): bx = y*4 + xh2*2 + coh. Wave wv: co = coh*64 + wv*16, x = x0..x0+31.
template<bool FUSE_TEMB, bool OUT_CF>
__global__ __launch_bounds__(256, 4) void conv_mfma_kernel(
    const __bf16* __restrict__ inT, const __bf16* __restrict__ wt,
    const float* __restrict__ bias, const float* __restrict__ temb,
    const float* __restrict__ resid, __bf16* __restrict__ outT,
    float* __restrict__ outF)
{
    const int y   = blockIdx.x >> 2;
    const int xh2 = (blockIdx.x >> 1) & 1;
    const int coh = blockIdx.x & 1;
    const int x0  = xh2 * 32;
    const int b   = blockIdx.y;
    const int tid = threadIdx.x;
    const int l = tid & 63, wv = tid >> 6;
    const int l15 = l & 15, l4 = l >> 4;
    const int co_w = coh * 64 + wv * 16;   // wave co base (global)

    // LDS [r 3][cc 16][xs 34][8] = 13056 elems = 26112 B
    __shared__ __bf16 inS[3 * 16 * 34 * 8];

    const __bf16* inTb = inT + (size_t)b * SP * CC;
    for (int q = tid; q < 3 * 34 * 16; q += 256) {
        int cc = q & 15;
        int t2 = q >> 4;
        int xs = t2 % 34;
        int r  = t2 / 34;
        int yy = y + r - 1;
        int xg = x0 + xs - 1;
        bf16x8 v;
        if (((unsigned)yy < 64u) && ((unsigned)xg < 64u)) {
            v = *(const bf16x8*)&inTb[((size_t)(yy * 64 + xg)) * CC + cc * 8];
        } else {
            #pragma unroll
            for (int j = 0; j < 8; ++j) v[j] = (__bf16)0.f;
        }
        *(bf16x8*)&inS[((r * 16 + cc) * 34 + xs) * 8] = v;
    }
    __syncthreads();

    f32x4 acc[2];   // [nb over x]
    acc[0] = (f32x4){0.f, 0.f, 0.f, 0.f};
    acc[1] = (f32x4){0.f, 0.f, 0.f, 0.f};

    const __bf16* wp = wt + (size_t)(co_w + l15) * 128 + l4 * 8;
    bf16x8 wb[2][4];   // [buf][ks]
    #pragma unroll
    for (int ks = 0; ks < 4; ++ks)
        wb[0][ks] = *(const bf16x8*)(wp + ks * 32);

    #pragma unroll
    for (int tap = 0; tap < 9; ++tap) {
        const int cur = tap & 1, nxt = cur ^ 1;
        if (tap < 8) {
            #pragma unroll
            for (int ks = 0; ks < 4; ++ks)
                wb[nxt][ks] = *(const bf16x8*)(wp + (tap + 1) * 16384 + ks * 32);
        }
        const int rr = tap / 3, dx = tap % 3;
        #pragma unroll
        for (int ks = 0; ks < 4; ++ks) {
            const __bf16* rb = &inS[((rr * 16 + ks * 4 + l4) * 34) * 8];
            bf16x8 b0 = *(const bf16x8*)&rb[(dx + l15) * 8];
            bf16x8 b1 = *(const bf16x8*)&rb[(16 + dx + l15) * 8];
            acc[0] = __builtin_amdgcn_mfma_f32_16x16x32_bf16(wb[cur][ks], b0, acc[0], 0, 0, 0);
            acc[1] = __builtin_amdgcn_mfma_f32_16x16x32_bf16(wb[cur][ks], b1, acc[1], 0, 0, 0);
        }
    }

    if (OUT_CF) {
        #pragma unroll
        for (int r = 0; r < 4; ++r) {
            int co = co_w + l4 * 4 + r;
            float bv = bias[co];
            #pragma unroll
            for (int nb = 0; nb < 2; ++nb) {
                int p = y * 64 + x0 + nb * 16 + l15;
                size_t o = ((size_t)(b * CC + co)) * SP + p;
                outF[o] = acc[nb][r] + bv + resid[o];
            }
        }
    } else {
        int co0 = co_w + l4 * 4;
        float bv[4];
        #pragma unroll
        for (int r = 0; r < 4; ++r)
            bv[r] = bias[co0 + r] + (FUSE_TEMB ? temb[b * CC + co0 + r] : 0.f);
        #pragma unroll
        for (int nb = 0; nb < 2; ++nb) {
            int p = y * 64 + x0 + nb * 16 + l15;
            bf16x4 o;
            #pragma unroll
            for (int r = 0; r < 4; ++r)
                o[r] = (__bf16)(acc[nb][r] + bv[r]);
            *(bf16x4*)&outT[((size_t)(b * SP + p)) * CC + co0] = o;
        }
    }
}

// ---------------- fused cross-attention v5: ct2 LDS dbuf + Pb single (NS=2) ----------------
#define CT2 72    // ct2 row stride (bf16)
#define PBS 72    // Pb row stride (bf16)
#define POOL_BYTES 46080

__global__ __launch_bounds__(256, 3) void attn_kernel(
    const __bf16* __restrict__ h1T, const __bf16* __restrict__ cmT,
    const __bf16* __restrict__ cm2, __bf16* __restrict__ parts)
{
    const int w = blockIdx.x;
    const int b = blockIdx.y;
    const int s = blockIdx.z;          // even/odd uv tiles
    const int tid = threadIdx.x;
    const int wl = tid >> 6;
    const int l = tid & 63, l15 = l & 15, l4 = l >> 4;
    const int hB = (wl & 1) * 32;
    const int cB = (wl >> 1) * 64;

    __shared__ __align__(16) char pool[POOL_BYTES];
    __bf16* ct2p = (__bf16*)pool;
    __bf16* Pb   = (__bf16*)(pool + 36864);
    __bf16* Otr  = (__bf16*)pool;

    const __bf16* h1Tb = h1T + (size_t)b * SP * CC;
    const __bf16* cmTb = cmT + (size_t)b * SP * CC;
    const __bf16* cm2b = cm2 + (size_t)b * CC * SP;

    bf16x8 hfr[4][4];
    #pragma unroll
    for (int nt = 0; nt < 4; ++nt)
        #pragma unroll
        for (int ks = 0; ks < 4; ++ks)
            hfr[nt][ks] = *(const bf16x8*)&h1Tb[((size_t)((nt * 16 + l15) * WW + w)) * CC + ks * 32 + l4 * 8];

    f32x4 acc2[2][4];
    #pragma unroll
    for (int mb = 0; mb < 2; ++mb)
        #pragma unroll
        for (int nt = 0; nt < 4; ++nt) acc2[mb][nt] = (f32x4){0.f, 0.f, 0.f, 0.f};

    const int sc = tid >> 3;
    const int stc = tid & 7;

    {
        const int uv0 = s * TT;
        #pragma unroll
        for (int it = 0; it < 4; ++it) {
            int c = it * 32 + sc;
            *(bf16x8*)&ct2p[c * CT2 + stc * 8] =
                *(const bf16x8*)&cm2b[(size_t)c * SP + uv0 + stc * 8];
        }
        const __bf16* arow = cmTb + (size_t)(uv0 + 16 * wl + l15) * CC;
        bf16x8 afr[4];
        #pragma unroll
        for (int ks = 0; ks < 4; ++ks) afr[ks] = *(const bf16x8*)&arow[ks * 32 + l4 * 8];
        f32x4 s1[4];
        #pragma unroll
        for (int nt = 0; nt < 4; ++nt) {
            s1[nt] = (f32x4){0.f, 0.f, 0.f, 0.f};
            #pragma unroll
            for (int ks = 0; ks < 4; ++ks)
                s1[nt] = __builtin_amdgcn_mfma_f32_16x16x32_bf16(afr[ks], hfr[nt][ks], s1[nt], 0, 0, 0);
        }
        #pragma unroll
        for (int r = 0; r < 4; ++r) {
            float e0 = __expf(s1[0][r]), e1 = __expf(s1[1][r]);
            float e2 = __expf(s1[2][r]), e3 = __expf(s1[3][r]);
            float sm = e0 + e1 + e2 + e3;
            sm += __shfl_xor(sm, 1, 64);
            sm += __shfl_xor(sm, 2, 64);
            sm += __shfl_xor(sm, 4, 64);
            sm += __shfl_xor(sm, 8, 64);
            float ri = 1.f / sm;
            s1[0][r] = e0 * ri; s1[1][r] = e1 * ri;
            s1[2][r] = e2 * ri; s1[3][r] = e3 * ri;
        }
        #pragma unroll
        for (int nt = 0; nt < 4; ++nt) {
            bf16x4 pk;
            pk[0] = (__bf16)s1[nt][0]; pk[1] = (__bf16)s1[nt][1];
            pk[2] = (__bf16)s1[nt][2]; pk[3] = (__bf16)s1[nt][3];
            *(bf16x4*)&Pb[(nt * 16 + l15) * PBS + 16 * wl + l4 * 4] = pk;
        }
    }

    for (int i = 0; i < SP / TT / NS; ++i) {
        const int cur = i & 1;
        __syncthreads();
        bf16x8 st4[4];
        bf16x8 afr[4];
        if (i < SP / TT / NS - 1) {
            const int uv0n = ((i + 1) * NS + s) * TT;
            #pragma unroll
            for (int it = 0; it < 4; ++it) {
                int c = it * 32 + sc;
                st4[it] = *(const bf16x8*)&cm2b[(size_t)c * SP + uv0n + stc * 8];
            }
            const __bf16* arow = cmTb + (size_t)(uv0n + 16 * wl + l15) * CC;
            #pragma unroll
            for (int ks = 0; ks < 4; ++ks) afr[ks] = *(const bf16x8*)&arow[ks * 32 + l4 * 8];
        }
        bf16x8 pfr[2][2];
        #pragma unroll
        for (int mb = 0; mb < 2; ++mb)
            #pragma unroll
            for (int ks = 0; ks < 2; ++ks)
                pfr[mb][ks] = *(const bf16x8*)&Pb[(hB + mb * 16 + l15) * PBS + ks * 32 + l4 * 8];
        __syncthreads();
        {
            const __bf16* ctR = ct2p + cur * 9216;
            #pragma unroll
            for (int mb = 0; mb < 2; ++mb)
                #pragma unroll
                for (int nt = 0; nt < 4; ++nt)
                    #pragma unroll
                    for (int ks = 0; ks < 2; ++ks) {
                        bf16x8 bfr = *(const bf16x8*)&ctR[(cB + nt * 16 + l15) * CT2 + ks * 32 + l4 * 8];
                        acc2[mb][nt] = __builtin_amdgcn_mfma_f32_16x16x32_bf16(
                            pfr[mb][ks], bfr, acc2[mb][nt], 0, 0, 0);
                    }
        }
        if (i < SP / TT / NS - 1) {
            __bf16* ctW = ct2p + (cur ^ 1) * 9216;
            #pragma unroll
            for (int it = 0; it < 4; ++it) {
                int c = it * 32 + sc;
                *(bf16x8*)&ctW[c * CT2 + stc * 8] = st4[it];
            }
            f32x4 s1[4];
            #pragma unroll
            for (int nt = 0; nt < 4; ++nt) {
                s1[nt] = (f32x4){0.f, 0.f, 0.f, 0.f};
                #pragma unroll
                for (int ks = 0; ks < 4; ++ks)
                    s1[nt] = __builtin_amdgcn_mfma_f32_16x16x32_bf16(afr[ks], hfr[nt][ks], s1[nt], 0, 0, 0);
            }
            #pragma unroll
            for (int r = 0; r < 4; ++r) {
                float e0 = __expf(s1[0][r]), e1 = __expf(s1[1][r]);
                float e2 = __expf(s1[2][r]), e3 = __expf(s1[3][r]);
                float sm = e0 + e1 + e2 + e3;
                sm += __shfl_xor(sm, 1, 64);
                sm += __shfl_xor(sm, 2, 64);
                sm += __shfl_xor(sm, 4, 64);
                sm += __shfl_xor(sm, 8, 64);
                float ri = 1.f / sm;
                s1[0][r] = e0 * ri; s1[1][r] = e1 * ri;
                s1[2][r] = e2 * ri; s1[3][r] = e3 * ri;
            }
            #pragma unroll
            for (int nt = 0; nt < 4; ++nt) {
                bf16x4 pk;
                pk[0] = (__bf16)s1[nt][0]; pk[1] = (__bf16)s1[nt][1];
                pk[2] = (__bf16)s1[nt][2]; pk[3] = (__bf16)s1[nt][3];
                *(bf16x4*)&Pb[(nt * 16 + l15) * PBS + 16 * wl + l4 * 4] = pk;
            }
        }
    }

    __syncthreads();
    #pragma unroll
    for (int mb = 0; mb < 2; ++mb)
        #pragma unroll
        for (int nt = 0; nt < 4; ++nt)
            #pragma unroll
            for (int r = 0; r < 4; ++r)
                Otr[(hB + mb * 16 + l4 * 4 + r) * 136 + cB + nt * 16 + l15] =
                    (__bf16)acc2[mb][nt][r];
    __syncthreads();
    __bf16* pO = parts + (size_t)s * PSZ;
    #pragma unroll
    for (int it = 0; it < 4; ++it) {
        int q = it * 256 + tid;
        int h = q >> 4, cc = q & 15;
        *(bf16x8*)&pO[((size_t)(b * SP + h * WW + w)) * CC + cc * 8] =
            *(const bf16x8*)&Otr[h * 136 + cc * 8];
    }
}

// ---------------- GN2 stats: h2 = h1T + sum(parts) + emb -> h2T bf16 + partial stats ----------------
__global__ __launch_bounds__(256) void gn2_stats_kernel(
    const __bf16* __restrict__ h1T, const __bf16* __restrict__ parts,
    const int* __restrict__ aim, const float* __restrict__ emb,
    __bf16* __restrict__ h2T, float* __restrict__ pstat)
{
    const int pb = blockIdx.x, b = blockIdx.y;
    const int tid = threadIdx.x;
    const int c4 = tid & 31;
    const float4 ev = *(const float4*)&emb[aim[b] * CC + c4 * 4];
    float s = 0.f, s2 = 0.f;
    for (int it = 0; it < 8; ++it) {
        int prow = it * 8 + (tid >> 5);
        size_t base = ((size_t)(b * SP + pb * 64 + prow)) * CC + c4 * 4;
        bf16x4 hv = *(const bf16x4*)&h1T[base];
        float v0 = (float)hv[0] + ev.x;
        float v1 = (float)hv[1] + ev.y;
        float v2 = (float)hv[2] + ev.z;
        float v3 = (float)hv[3] + ev.w;
        #pragma unroll
        for (int k = 0; k < NS; ++k) {
            bf16x4 a = *(const bf16x4*)&parts[(size_t)k * PSZ + base];
            v0 += (float)a[0]; v1 += (float)a[1];
            v2 += (float)a[2]; v3 += (float)a[3];
        }
        bf16x4 o;
        o[0] = (__bf16)v0; o[1] = (__bf16)v1;
        o[2] = (__bf16)v2; o[3] = (__bf16)v3;
        *(bf16x4*)&h2T[base] = o;
        s += v0 + v1 + v2 + v3;
        s2 += v0 * v0 + v1 * v1 + v2 * v2 + v3 * v3;
    }
    s  += __shfl_down(s,  32, 64);
    s2 += __shfl_down(s2, 32, 64);
    __shared__ float ls[4][32][2];
    const int wv = tid >> 6, ll = tid & 63;
    if (ll < 32) { ls[wv][ll][0] = s; ls[wv][ll][1] = s2; }
    __syncthreads();
    if (tid < 32) {
        float S = ls[0][tid][0] + ls[1][tid][0] + ls[2][tid][0] + ls[3][tid][0];
        float S2 = ls[0][tid][1] + ls[1][tid][1] + ls[2][tid][1] + ls[3][tid][1];
        int g = tid;
        pstat[(((size_t)b * NG + g) * 64 + pb) * 2]     = S;
        pstat[(((size_t)b * NG + g) * 64 + pb) * 2 + 1] = S2;
    }
}

// ---------------- GN2 apply (inline finalize) + SiLU: h2T -> aT bf16 ----------------
__global__ __launch_bounds__(256) void gn2_apply_kernel(
    const __bf16* __restrict__ h2T, const float* __restrict__ pstat,
    const float* __restrict__ scale, const float* __restrict__ bias,
    __bf16* __restrict__ outT)
{
    const int pb = blockIdx.x, b = blockIdx.y;
    const int tid = threadIdx.x;
    const int c4 = tid & 31;
    const int g = c4;
    __shared__ float st[32][2];
    if (tid < 32) {
        float S = 0.f, S2 = 0.f;
        const float* ps = pstat + ((size_t)b * NG + tid) * 128;
        for (int k = 0; k < 64; ++k) { S += ps[k * 2]; S2 += ps[k * 2 + 1]; }
        float mm = S * (1.f / 16384.f);
        float var = S2 * (1.f / 16384.f) - mm * mm;
        st[tid][0] = mm;
        st[tid][1] = rsqrtf(var + 1e-5f);
    }
    __syncthreads();
    const float4 sc = *(const float4*)&scale[c4 * 4];
    const float4 bi = *(const float4*)&bias[c4 * 4];
    const float m = st[g][0], inv = st[g][1];
    for (int it = 0; it < 8; ++it) {
        int prow = it * 8 + (tid >> 5);
        size_t base = ((size_t)(b * SP + pb * 64 + prow)) * CC + c4 * 4;
        bf16x4 hv = *(const bf16x4*)&h2T[base];
        bf16x4 o;
        o[0] = (__bf16)silu_f(((float)hv[0] - m) * inv * sc.x + bi.x);
        o[1] = (__bf16)silu_f(((float)hv[1] - m) * inv * sc.y + bi.y);
        o[2] = (__bf16)silu_f(((float)hv[2] - m) * inv * sc.z + bi.z);
        o[3] = (__bf16)silu_f(((float)hv[3] - m) * inv * sc.w + bi.w);
        *(bf16x4*)&outT[base] = o;
    }
}

extern "C" void kernel_launch(void* const* d_in, const int* in_sizes, int n_in,
                              void* d_out, int out_size, void* d_ws, size_t ws_size,
                              hipStream_t stream)
{
    const float* x     = (const float*)d_in[0];
    const float* t     = (const float*)d_in[1];
    const int*   aim   = (const int*)  d_in[2];
    const float* cond  = (const float*)d_in[3];
    const float* gn1s  = (const float*)d_in[4];
    const float* gn1b  = (const float*)d_in[5];
    const float* c1w   = (const float*)d_in[6];
    const float* c1b   = (const float*)d_in[7];
    const float* mlpw  = (const float*)d_in[8];
    const float* mlpb  = (const float*)d_in[9];
    const float* cw    = (const float*)d_in[10];
    const float* cb    = (const float*)d_in[11];
    const float* gn2s  = (const float*)d_in[12];
    const float* gn2b  = (const float*)d_in[13];
    const float* c2w   = (const float*)d_in[14];
    const float* c2b   = (const float*)d_in[15];
    const float* emb   = (const float*)d_in[16];
    float* out = (float*)d_out;
    float* ws = (float*)d_ws;

    // float-offset workspace map
    __bf16* aT    = (__bf16*)ws;                  // [0, 1048576)
    __bf16* h1T   = (__bf16*)(ws + 1048576);      // [1048576, 2097152)
    __bf16* cmT   = (__bf16*)(ws + 2097152);      // [2097152, 3145728)  (h2T after attn)
    __bf16* cm2   = (__bf16*)(ws + 3145728);      // [3145728, 4194304)
    __bf16* parts = (__bf16*)(ws + 4194304);      // 2 x 1,048,576 fl = [4194304, 6291456)
    __bf16* wt    = (__bf16*)(ws + 6291456);      // 294,912 bf16 = 147,456 fl
    float*  tembw = ws + 6438912;                 // 512
    float*  pstat = ws + 6439424;                 // 16384
    __bf16* h2T   = cmT;                          // reuse dead cmT space

    prep_kernel<<<dim3(410), dim3(256), 0, stream>>>(
        x, gn1s, gn1b, aT, c1w, c2w, wt, t, mlpw, mlpb, tembw,
        cond, cw, cb, cmT, cm2);
    conv_mfma_kernel<true, false><<<dim3(256, BB), dim3(256), 0, stream>>>(
        aT, wt, c1b, tembw, nullptr, h1T, nullptr);
    attn_kernel<<<dim3(WW, BB, NS), dim3(256), 0, stream>>>(h1T, cmT, cm2, parts);
    gn2_stats_kernel<<<dim3(64, BB), dim3(256), 0, stream>>>(h1T, parts, aim, emb, h2T, pstat);
    gn2_apply_kernel<<<dim3(64, BB), dim3(256), 0, stream>>>(h2T, pstat, gn2s, gn2b, aT);
    conv_mfma_kernel<false, true><<<dim3(256, BB), dim3(256), 0, stream>>>(
        aT, wt + (size_t)9 * 16384, c2b, nullptr, x, nullptr, out);
}

// Round 13
// 225.534 us; speedup vs baseline: 7.6303x; 1.0191x over previous
//
#include <hip/hip_runtime.h>
#include <cmath>

#define BB 4
#define CC 128
#define HH 64
#define WW 64
#define SP 4096   // H*W
#define NG 32     // groups
#define TT 64     // attention uv-tile width
#define NS 2      // attention uv split factor
#define PSZ ((size_t)BB * SP * CC)   // partial tensor elements

typedef __bf16 bf16x8 __attribute__((ext_vector_type(8)));
typedef __bf16 bf16x4 __attribute__((ext_vector_type(4)));
typedef float  f32x4  __attribute__((ext_vector_type(4)));

__device__ __forceinline__ float silu_f(float v) {
    return v / (1.f + __expf(-v));
}

// ================= merged prep kernel (slim LDS) =================
__global__ __launch_bounds__(256) void prep_kernel(
    const float* __restrict__ x, const float* __restrict__ gn1s,
    const float* __restrict__ gn1b, __bf16* __restrict__ aT,
    const float* __restrict__ c1w, const float* __restrict__ c2w,
    __bf16* __restrict__ wt,
    const float* __restrict__ t, const float* __restrict__ mlpw,
    const float* __restrict__ mlpb, float* __restrict__ tembw,
    const float* __restrict__ cond, const float* __restrict__ cw,
    const float* __restrict__ cb, __bf16* __restrict__ cmT,
    __bf16* __restrict__ cm2)
{
    __shared__ __align__(16) char pool[18432];
    __shared__ float rs[4], rs2[4], mean_s, inv_s;
    const int blk = blockIdx.x;
    const int tid = threadIdx.x;

    if (blk < 128) {
        // ---- GN1 two-pass ----
        const int b = blk >> 5, g = blk & 31;
        const float* p = x + (size_t)blk * 16384;
        float s = 0.f, s2 = 0.f;
        for (int it = 0; it < 16; ++it) {
            int q = it * 256 + tid;
            float4 v = *(const float4*)&p[q * 4];
            s += v.x + v.y + v.z + v.w;
            s2 += v.x * v.x + v.y * v.y + v.z * v.z + v.w * v.w;
        }
        #pragma unroll
        for (int off = 32; off >= 1; off >>= 1) {
            s  += __shfl_down(s,  off, 64);
            s2 += __shfl_down(s2, off, 64);
        }
        const int wid = tid >> 6;
        if ((tid & 63) == 0) { rs[wid] = s; rs2[wid] = s2; }
        __syncthreads();
        if (tid == 0) {
            float S = rs[0] + rs[1] + rs[2] + rs[3];
            float S2 = rs2[0] + rs2[1] + rs2[2] + rs2[3];
            float m = S * (1.f / 16384.f);
            float var = S2 * (1.f / 16384.f) - m * m;
            mean_s = m;
            inv_s = rsqrtf(var + 1e-5f);
        }
        __syncthreads();
        const float m = mean_s, inv = inv_s;
        float sc[4], bi[4];
        #pragma unroll
        for (int j = 0; j < 4; ++j) { sc[j] = gn1s[g * 4 + j]; bi[j] = gn1b[g * 4 + j]; }
        for (int it = 0; it < 16; ++it) {
            int pp = it * 256 + tid;
            bf16x4 o;
            #pragma unroll
            for (int j = 0; j < 4; ++j)
                o[j] = (__bf16)silu_f((p[j * 4096 + pp] - m) * inv * sc[j] + bi[j]);
            *(bf16x4*)&aT[((size_t)(b * SP + pp)) * CC + g * 4] = o;
        }
    } else if (blk < 146) {
        // ---- weight transpose ----
        const int idx = blk - 128;
        const int wsel = idx / 9, tap = idx % 9;
        const float* src = wsel ? c2w : c1w;
        __bf16* dst = wt + (size_t)wsel * 9 * 16384 + (size_t)tap * 16384;
        for (int it = 0; it < 64; ++it) {
            int q = it * 256 + tid;
            dst[q] = (__bf16)src[(size_t)q * 9 + tap];
        }
    } else if (blk < 154) {
        // ---- temb MLP ----
        const int cog = blk - 146;
        float* st = (float*)pool;
        for (int it = 0; it < 8; ++it) {
            int q = it * 256 + tid;
            st[q] = silu_f(t[q]);
        }
        __syncthreads();
        const int col = tid >> 4, seg = tid & 15;
        const float* wr = mlpw + (size_t)(cog * 16 + col) * 512 + seg * 32;
        float acc[4] = {0.f, 0.f, 0.f, 0.f};
        #pragma unroll
        for (int k8 = 0; k8 < 8; ++k8) {
            float4 wv = *(const float4*)&wr[k8 * 4];
            #pragma unroll
            for (int j = 0; j < 4; ++j) {
                int k = seg * 32 + k8 * 4 + j;
                float w4 = (&wv.x)[j];
                acc[0] += st[0 * 512 + k] * w4;
                acc[1] += st[1 * 512 + k] * w4;
                acc[2] += st[2 * 512 + k] * w4;
                acc[3] += st[3 * 512 + k] * w4;
            }
        }
        #pragma unroll
        for (int o = 1; o < 16; o <<= 1) {
            #pragma unroll
            for (int b4 = 0; b4 < 4; ++b4)
                acc[b4] += __shfl_xor(acc[b4], o, 64);
        }
        if (seg == 0) {
            float bv = mlpb[cog * 16 + col];
            #pragma unroll
            for (int b4 = 0; b4 < 4; ++b4)
                tembw[b4 * 128 + cog * 16 + col] = acc[b4] + bv;
        }
    } else {
        // ---- 1x1 conv MFMA ----
        const int pblk = blk - 154;
        const int b = pblk >> 6;
        const int p0 = (pblk & 63) * 64;
        const int l = tid & 63, wv = tid >> 6;
        const int l15 = l & 15, l4 = l >> 4;
        const int mB = wv * 32;

        __bf16* XT = (__bf16*)pool;

        for (int it = 0; it < 32; ++it) {
            int q = it * 256 + tid;
            float v = cond[((size_t)(b * CC + (q >> 6))) * SP + p0 + (q & 63)];
            XT[(q & 63) * 136 + (q >> 6)] = (__bf16)v;
        }
        __syncthreads();

        f32x4 acc[2][4];
        #pragma unroll
        for (int mb = 0; mb < 2; ++mb)
            #pragma unroll
            for (int nt = 0; nt < 4; ++nt) acc[mb][nt] = (f32x4){0.f, 0.f, 0.f, 0.f};

        #pragma unroll
        for (int ks = 0; ks < 4; ++ks) {
            bf16x8 bfr[4];
            #pragma unroll
            for (int nt = 0; nt < 4; ++nt)
                bfr[nt] = *(const bf16x8*)&XT[(nt * 16 + l15) * 136 + ks * 32 + l4 * 8];
            #pragma unroll
            for (int mb = 0; mb < 2; ++mb) {
                const float* wrow = cw + (size_t)(mB + mb * 16 + l15) * 128 + ks * 32 + l4 * 8;
                float4 wa = *(const float4*)wrow;
                float4 wb4 = *(const float4*)(wrow + 4);
                bf16x8 afr;
                afr[0] = (__bf16)wa.x; afr[1] = (__bf16)wa.y;
                afr[2] = (__bf16)wa.z; afr[3] = (__bf16)wa.w;
                afr[4] = (__bf16)wb4.x; afr[5] = (__bf16)wb4.y;
                afr[6] = (__bf16)wb4.z; afr[7] = (__bf16)wb4.w;
                #pragma unroll
                for (int nt = 0; nt < 4; ++nt)
                    acc[mb][nt] = __builtin_amdgcn_mfma_f32_16x16x32_bf16(afr, bfr[nt], acc[mb][nt], 0, 0, 0);
            }
        }

        const float scl = 0.088388347648318447f;
        #pragma unroll
        for (int mb = 0; mb < 2; ++mb) {
            int co0 = mB + mb * 16 + l4 * 4;
            float bv[4];
            #pragma unroll
            for (int r = 0; r < 4; ++r) bv[r] = cb[co0 + r];
            #pragma unroll
            for (int nt = 0; nt < 4; ++nt) {
                int p = p0 + nt * 16 + l15;
                bf16x4 o;
                #pragma unroll
                for (int r = 0; r < 4; ++r)
                    o[r] = (__bf16)((acc[mb][nt][r] + bv[r]) * scl);
                *(bf16x4*)&cmT[((size_t)(b * SP + p)) * CC + co0] = o;
            }
        }
        __syncthreads();
        __bf16* O2 = (__bf16*)pool;
        #pragma unroll
        for (int mb = 0; mb < 2; ++mb) {
            int co0 = mB + mb * 16 + l4 * 4;
            #pragma unroll
            for (int r = 0; r < 4; ++r) {
                float bv = cb[co0 + r];
                #pragma unroll
                for (int nt = 0; nt < 4; ++nt)
                    O2[(co0 + r) * 72 + nt * 16 + l15] = (__bf16)(acc[mb][nt][r] + bv);
            }
        }
        __syncthreads();
        #pragma unroll
        for (int it = 0; it < 4; ++it) {
            int q = it * 256 + tid;
            int co = q >> 3, pc = q & 7;
            *(bf16x8*)&cm2[((size_t)(b * CC + co)) * SP + p0 + pc * 8] =
                *(const bf16x8*)&O2[co * 72 + pc * 8];
        }
    }
}

// ---------------- 3x3 conv: optional fused GN+SiLU on staging ----------------
template<bool FUSE_TEMB, bool OUT_CF, bool FUSE_GN>
__global__ __launch_bounds__(256, 4) void conv_mfma_kernel(
    const __bf16* __restrict__ inT, const __bf16* __restrict__ wt,
    const float* __restrict__ bias, const float* __restrict__ temb,
    const float* __restrict__ resid, __bf16* __restrict__ outT,
    float* __restrict__ outF, const float* __restrict__ gstat,
    const float* __restrict__ gn_s, const float* __restrict__ gn_b)
{
    const int y   = blockIdx.x >> 2;
    const int xh2 = (blockIdx.x >> 1) & 1;
    const int coh = blockIdx.x & 1;
    const int x0  = xh2 * 32;
    const int b   = blockIdx.y;
    const int tid = threadIdx.x;
    const int l = tid & 63, wv = tid >> 6;
    const int l15 = l & 15, l4 = l >> 4;
    const int co_w = coh * 64 + wv * 16;

    __shared__ __bf16 inS[3 * 16 * 34 * 8];   // 26 KB
    __shared__ float af[128], bfp[128];

    if (FUSE_GN) {
        if (tid < 128) {
            int g = tid >> 2;
            float S = gstat[(b * NG + g) * 2], S2 = gstat[(b * NG + g) * 2 + 1];
            float m = S * (1.f / 16384.f);
            float var = S2 * (1.f / 16384.f) - m * m;
            float inv = rsqrtf(var + 1e-5f);
            float a = inv * gn_s[tid];
            af[tid] = a;
            bfp[tid] = gn_b[tid] - m * a;
        }
        __syncthreads();
    }

    const __bf16* inTb = inT + (size_t)b * SP * CC;
    for (int q = tid; q < 3 * 34 * 16; q += 256) {
        int cc = q & 15;
        int t2 = q >> 4;
        int xs = t2 % 34;
        int r  = t2 / 34;
        int yy = y + r - 1;
        int xg = x0 + xs - 1;
        bf16x8 v;
        if (((unsigned)yy < 64u) && ((unsigned)xg < 64u)) {
            bf16x8 raw = *(const bf16x8*)&inTb[((size_t)(yy * 64 + xg)) * CC + cc * 8];
            if (FUSE_GN) {
                #pragma unroll
                for (int j = 0; j < 8; ++j) {
                    int c = cc * 8 + j;
                    v[j] = (__bf16)silu_f((float)raw[j] * af[c] + bfp[c]);
                }
            } else {
                v = raw;
            }
        } else {
            #pragma unroll
            for (int j = 0; j < 8; ++j) v[j] = (__bf16)0.f;
        }
        *(bf16x8*)&inS[((r * 16 + cc) * 34 + xs) * 8] = v;
    }
    __syncthreads();

    f32x4 acc[2];
    acc[0] = (f32x4){0.f, 0.f, 0.f, 0.f};
    acc[1] = (f32x4){0.f, 0.f, 0.f, 0.f};

    const __bf16* wp = wt + (size_t)(co_w + l15) * 128 + l4 * 8;
    bf16x8 wb[2][4];
    #pragma unroll
    for (int ks = 0; ks < 4; ++ks)
        wb[0][ks] = *(const bf16x8*)(wp + ks * 32);

    #pragma unroll
    for (int tap = 0; tap < 9; ++tap) {
        const int cur = tap & 1, nxt = cur ^ 1;
        if (tap < 8) {
            #pragma unroll
            for (int ks = 0; ks < 4; ++ks)
                wb[nxt][ks] = *(const bf16x8*)(wp + (tap + 1) * 16384 + ks * 32);
        }
        const int rr = tap / 3, dx = tap % 3;
        #pragma unroll
        for (int ks = 0; ks < 4; ++ks) {
            const __bf16* rb = &inS[((rr * 16 + ks * 4 + l4) * 34) * 8];
            bf16x8 b0 = *(const bf16x8*)&rb[(dx + l15) * 8];
            bf16x8 b1 = *(const bf16x8*)&rb[(16 + dx + l15) * 8];
            acc[0] = __builtin_amdgcn_mfma_f32_16x16x32_bf16(wb[cur][ks], b0, acc[0], 0, 0, 0);
            acc[1] = __builtin_amdgcn_mfma_f32_16x16x32_bf16(wb[cur][ks], b1, acc[1], 0, 0, 0);
        }
    }

    if (OUT_CF) {
        #pragma unroll
        for (int r = 0; r < 4; ++r) {
            int co = co_w + l4 * 4 + r;
            float bv = bias[co];
            #pragma unroll
            for (int nb = 0; nb < 2; ++nb) {
                int p = y * 64 + x0 + nb * 16 + l15;
                size_t o = ((size_t)(b * CC + co)) * SP + p;
                outF[o] = acc[nb][r] + bv + resid[o];
            }
        }
    } else {
        int co0 = co_w + l4 * 4;
        float bv[4];
        #pragma unroll
        for (int r = 0; r < 4; ++r)
            bv[r] = bias[co0 + r] + (FUSE_TEMB ? temb[b * CC + co0 + r] : 0.f);
        #pragma unroll
        for (int nb = 0; nb < 2; ++nb) {
            int p = y * 64 + x0 + nb * 16 + l15;
            bf16x4 o;
            #pragma unroll
            for (int r = 0; r < 4; ++r)
                o[r] = (__bf16)(acc[nb][r] + bv[r]);
            *(bf16x4*)&outT[((size_t)(b * SP + p)) * CC + co0] = o;
        }
    }
}

// ---------------- fused cross-attention v6: double ping-pong, ONE barrier/tile ----------------
#define CT2 72    // ct2 row stride (bf16)
#define PBS 72    // Pb row stride (bf16)
// pool: ct2[2] 2x18432 B = 36864, Pb[2] 2x9216 B = 18432 -> 55296 B
#define POOL_BYTES 55296

__global__ __launch_bounds__(256, 2) void attn_kernel(
    const __bf16* __restrict__ h1T, const __bf16* __restrict__ cmT,
    const __bf16* __restrict__ cm2, __bf16* __restrict__ parts)
{
    const int w = blockIdx.x;
    const int b = blockIdx.y;
    const int s = blockIdx.z;
    const int tid = threadIdx.x;
    const int wl = tid >> 6;
    const int l = tid & 63, l15 = l & 15, l4 = l >> 4;
    const int hB = (wl & 1) * 32;
    const int cB = (wl >> 1) * 64;

    __shared__ __align__(16) char pool[POOL_BYTES];
    __bf16* ct2p = (__bf16*)pool;               // 2 buffers of 9216 elems
    __bf16* Pbp  = (__bf16*)(pool + 36864);     // 2 buffers of 4608 elems
    __bf16* Otr  = (__bf16*)pool;               // epilogue alias

    const __bf16* h1Tb = h1T + (size_t)b * SP * CC;
    const __bf16* cmTb = cmT + (size_t)b * SP * CC;
    const __bf16* cm2b = cm2 + (size_t)b * CC * SP;

    bf16x8 hfr[4][4];
    #pragma unroll
    for (int nt = 0; nt < 4; ++nt)
        #pragma unroll
        for (int ks = 0; ks < 4; ++ks)
            hfr[nt][ks] = *(const bf16x8*)&h1Tb[((size_t)((nt * 16 + l15) * WW + w)) * CC + ks * 32 + l4 * 8];

    f32x4 acc2[2][4];
    #pragma unroll
    for (int mb = 0; mb < 2; ++mb)
        #pragma unroll
        for (int nt = 0; nt < 4; ++nt) acc2[mb][nt] = (f32x4){0.f, 0.f, 0.f, 0.f};

    const int sc = tid >> 3;
    const int stc = tid & 7;

    // prologue: stage ct2[0], produce Pb[0] (tile 0)
    {
        const int uv0 = s * TT;
        #pragma unroll
        for (int it = 0; it < 4; ++it) {
            int c = it * 32 + sc;
            *(bf16x8*)&ct2p[c * CT2 + stc * 8] =
                *(const bf16x8*)&cm2b[(size_t)c * SP + uv0 + stc * 8];
        }
        const __bf16* arow = cmTb + (size_t)(uv0 + 16 * wl + l15) * CC;
        bf16x8 afr[4];
        #pragma unroll
        for (int ks = 0; ks < 4; ++ks) afr[ks] = *(const bf16x8*)&arow[ks * 32 + l4 * 8];
        f32x4 s1[4];
        #pragma unroll
        for (int nt = 0; nt < 4; ++nt) {
            s1[nt] = (f32x4){0.f, 0.f, 0.f, 0.f};
            #pragma unroll
            for (int ks = 0; ks < 4; ++ks)
                s1[nt] = __builtin_amdgcn_mfma_f32_16x16x32_bf16(afr[ks], hfr[nt][ks], s1[nt], 0, 0, 0);
        }
        #pragma unroll
        for (int r = 0; r < 4; ++r) {
            float e0 = __expf(s1[0][r]), e1 = __expf(s1[1][r]);
            float e2 = __expf(s1[2][r]), e3 = __expf(s1[3][r]);
            float sm = e0 + e1 + e2 + e3;
            sm += __shfl_xor(sm, 1, 64);
            sm += __shfl_xor(sm, 2, 64);
            sm += __shfl_xor(sm, 4, 64);
            sm += __shfl_xor(sm, 8, 64);
            float ri = 1.f / sm;
            s1[0][r] = e0 * ri; s1[1][r] = e1 * ri;
            s1[2][r] = e2 * ri; s1[3][r] = e3 * ri;
        }
        #pragma unroll
        for (int nt = 0; nt < 4; ++nt) {
            bf16x4 pk;
            pk[0] = (__bf16)s1[nt][0]; pk[1] = (__bf16)s1[nt][1];
            pk[2] = (__bf16)s1[nt][2]; pk[3] = (__bf16)s1[nt][3];
            *(bf16x4*)&Pbp[(nt * 16 + l15) * PBS + 16 * wl + l4 * 4] = pk;
        }
    }

    for (int i = 0; i < SP / TT / NS; ++i) {
        const int cur = i & 1;
        __syncthreads();   // Pb[cur] + ct2[cur] complete (written last iter / prologue)
        // prefetch tile i+1 operands into registers
        bf16x8 st4[4];
        bf16x8 afr[4];
        if (i < SP / TT / NS - 1) {
            const int uv0n = ((i + 1) * NS + s) * TT;
            #pragma unroll
            for (int it = 0; it < 4; ++it) {
                int c = it * 32 + sc;
                st4[it] = *(const bf16x8*)&cm2b[(size_t)c * SP + uv0n + stc * 8];
            }
            const __bf16* arow = cmTb + (size_t)(uv0n + 16 * wl + l15) * CC;
            #pragma unroll
            for (int ks = 0; ks < 4; ++ks) afr[ks] = *(const bf16x8*)&arow[ks * 32 + l4 * 8];
        }
        // consume tile i: mm2 from Pb[cur], ct2[cur]
        {
            const __bf16* PbR = Pbp + cur * 4608;
            const __bf16* ctR = ct2p + cur * 9216;
            bf16x8 pfr[2][2];
            #pragma unroll
            for (int mb = 0; mb < 2; ++mb)
                #pragma unroll
                for (int ks = 0; ks < 2; ++ks)
                    pfr[mb][ks] = *(const bf16x8*)&PbR[(hB + mb * 16 + l15) * PBS + ks * 32 + l4 * 8];
            #pragma unroll
            for (int mb = 0; mb < 2; ++mb)
                #pragma unroll
                for (int nt = 0; nt < 4; ++nt)
                    #pragma unroll
                    for (int ks = 0; ks < 2; ++ks) {
                        bf16x8 bfr = *(const bf16x8*)&ctR[(cB + nt * 16 + l15) * CT2 + ks * 32 + l4 * 8];
                        acc2[mb][nt] = __builtin_amdgcn_mfma_f32_16x16x32_bf16(
                            pfr[mb][ks], bfr, acc2[mb][nt], 0, 0, 0);
                    }
        }
        // produce tile i+1 into the other buffers
        if (i < SP / TT / NS - 1) {
            __bf16* ctW = ct2p + (cur ^ 1) * 9216;
            #pragma unroll
            for (int it = 0; it < 4; ++it) {
                int c = it * 32 + sc;
                *(bf16x8*)&ctW[c * CT2 + stc * 8] = st4[it];
            }
            f32x4 s1[4];
            #pragma unroll
            for (int nt = 0; nt < 4; ++nt) {
                s1[nt] = (f32x4){0.f, 0.f, 0.f, 0.f};
                #pragma unroll
                for (int ks = 0; ks < 4; ++ks)
                    s1[nt] = __builtin_amdgcn_mfma_f32_16x16x32_bf16(afr[ks], hfr[nt][ks], s1[nt], 0, 0, 0);
            }
            #pragma unroll
            for (int r = 0; r < 4; ++r) {
                float e0 = __expf(s1[0][r]), e1 = __expf(s1[1][r]);
                float e2 = __expf(s1[2][r]), e3 = __expf(s1[3][r]);
                float sm = e0 + e1 + e2 + e3;
                sm += __shfl_xor(sm, 1, 64);
                sm += __shfl_xor(sm, 2, 64);
                sm += __shfl_xor(sm, 4, 64);
                sm += __shfl_xor(sm, 8, 64);
                float ri = 1.f / sm;
                s1[0][r] = e0 * ri; s1[1][r] = e1 * ri;
                s1[2][r] = e2 * ri; s1[3][r] = e3 * ri;
            }
            __bf16* PbW = Pbp + (cur ^ 1) * 4608;
            #pragma unroll
            for (int nt = 0; nt < 4; ++nt) {
                bf16x4 pk;
                pk[0] = (__bf16)s1[nt][0]; pk[1] = (__bf16)s1[nt][1];
                pk[2] = (__bf16)s1[nt][2]; pk[3] = (__bf16)s1[nt][3];
                *(bf16x4*)&PbW[(nt * 16 + l15) * PBS + 16 * wl + l4 * 4] = pk;
            }
        }
    }

    __syncthreads();
    #pragma unroll
    for (int mb = 0; mb < 2; ++mb)
        #pragma unroll
        for (int nt = 0; nt < 4; ++nt)
            #pragma unroll
            for (int r = 0; r < 4; ++r)
                Otr[(hB + mb * 16 + l4 * 4 + r) * 136 + cB + nt * 16 + l15] =
                    (__bf16)acc2[mb][nt][r];
    __syncthreads();
    __bf16* pO = parts + (size_t)s * PSZ;
    #pragma unroll
    for (int it = 0; it < 4; ++it) {
        int q = it * 256 + tid;
        int h = q >> 4, cc = q & 15;
        *(bf16x8*)&pO[((size_t)(b * SP + h * WW + w)) * CC + cc * 8] =
            *(const bf16x8*)&Otr[h * 136 + cc * 8];
    }
}

// ---------------- GN2 stats: h2 -> h2T bf16 + atomic group sums ----------------
__global__ __launch_bounds__(256) void gn2_stats_kernel(
    const __bf16* __restrict__ h1T, const __bf16* __restrict__ parts,
    const int* __restrict__ aim, const float* __restrict__ emb,
    __bf16* __restrict__ h2T, float* __restrict__ gstat)
{
    const int pb = blockIdx.x, b = blockIdx.y;
    const int tid = threadIdx.x;
    const int c4 = tid & 31;
    const float4 ev = *(const float4*)&emb[aim[b] * CC + c4 * 4];
    float s = 0.f, s2 = 0.f;
    for (int it = 0; it < 8; ++it) {
        int prow = it * 8 + (tid >> 5);
        size_t base = ((size_t)(b * SP + pb * 64 + prow)) * CC + c4 * 4;
        bf16x4 hv = *(const bf16x4*)&h1T[base];
        float v0 = (float)hv[0] + ev.x;
        float v1 = (float)hv[1] + ev.y;
        float v2 = (float)hv[2] + ev.z;
        float v3 = (float)hv[3] + ev.w;
        #pragma unroll
        for (int k = 0; k < NS; ++k) {
            bf16x4 a = *(const bf16x4*)&parts[(size_t)k * PSZ + base];
            v0 += (float)a[0]; v1 += (float)a[1];
            v2 += (float)a[2]; v3 += (float)a[3];
        }
        bf16x4 o;
        o[0] = (__bf16)v0; o[1] = (__bf16)v1;
        o[2] = (__bf16)v2; o[3] = (__bf16)v3;
        *(bf16x4*)&h2T[base] = o;
        s += v0 + v1 + v2 + v3;
        s2 += v0 * v0 + v1 * v1 + v2 * v2 + v3 * v3;
    }
    s  += __shfl_down(s,  32, 64);
    s2 += __shfl_down(s2, 32, 64);
    __shared__ float ls[4][32][2];
    const int wv = tid >> 6, ll = tid & 63;
    if (ll < 32) { ls[wv][ll][0] = s; ls[wv][ll][1] = s2; }
    __syncthreads();
    if (tid < 32) {
        float S = ls[0][tid][0] + ls[1][tid][0] + ls[2][tid][0] + ls[3][tid][0];
        float S2 = ls[0][tid][1] + ls[1][tid][1] + ls[2][tid][1] + ls[3][tid][1];
        atomicAdd(&gstat[(b * NG + tid) * 2], S);
        atomicAdd(&gstat[(b * NG + tid) * 2 + 1], S2);
    }
}

extern "C" void kernel_launch(void* const* d_in, const int* in_sizes, int n_in,
                              void* d_out, int out_size, void* d_ws, size_t ws_size,
                              hipStream_t stream)
{
    const float* x     = (const float*)d_in[0];
    const float* t     = (const float*)d_in[1];
    const int*   aim   = (const int*)  d_in[2];
    const float* cond  = (const float*)d_in[3];
    const float* gn1s  = (const float*)d_in[4];
    const float* gn1b  = (const float*)d_in[5];
    const float* c1w   = (const float*)d_in[6];
    const float* c1b   = (const float*)d_in[7];
    const float* mlpw  = (const float*)d_in[8];
    const float* mlpb  = (const float*)d_in[9];
    const float* cw    = (const float*)d_in[10];
    const float* cb    = (const float*)d_in[11];
    const float* gn2s  = (const float*)d_in[12];
    const float* gn2b  = (const float*)d_in[13];
    const float* c2w   = (const float*)d_in[14];
    const float* c2b   = (const float*)d_in[15];
    const float* emb   = (const float*)d_in[16];
    float* out = (float*)d_out;
    float* ws = (float*)d_ws;

    // float-offset workspace map
    __bf16* aT    = (__bf16*)ws;                  // [0, 1048576)
    __bf16* h1T   = (__bf16*)(ws + 1048576);
    __bf16* cmT   = (__bf16*)(ws + 2097152);      // h2T after attn
    __bf16* cm2   = (__bf16*)(ws + 3145728);
    __bf16* parts = (__bf16*)(ws + 4194304);      // 2 partials
    __bf16* wt    = (__bf16*)(ws + 6291456);
    float*  tembw = ws + 6438912;
    float*  gstat = ws + 6439424;                 // 256 floats
    __bf16* h2T   = cmT;

    prep_kernel<<<dim3(410), dim3(256), 0, stream>>>(
        x, gn1s, gn1b, aT, c1w, c2w, wt, t, mlpw, mlpb, tembw,
        cond, cw, cb, cmT, cm2);
    hipMemsetAsync(gstat, 0, 256 * sizeof(float), stream);
    conv_mfma_kernel<true, false, false><<<dim3(256, BB), dim3(256), 0, stream>>>(
        aT, wt, c1b, tembw, nullptr, h1T, nullptr, nullptr, nullptr, nullptr);
    attn_kernel<<<dim3(WW, BB, NS), dim3(256), 0, stream>>>(h1T, cmT, cm2, parts);
    gn2_stats_kernel<<<dim3(64, BB), dim3(256), 0, stream>>>(h1T, parts, aim, emb, h2T, gstat);
    conv_mfma_kernel<false, true, true><<<dim3(256, BB), dim3(256), 0, stream>>>(
        h2T, wt + (size_t)9 * 16384, c2b, nullptr, x, nullptr, out, gstat, gn2s, gn2b);
}